// Round 5
// baseline (786.093 us; speedup 1.0000x reference)
//
#include <hip/hip_runtime.h>
#include <hip/hip_fp16.h>
#include <stdint.h>
#include <math.h>

// MoE MLP block: router top-2 + 8 experts SiLU-GLU, fp16 MFMA.
// v5: T3+T4 pipeline — raw s_barrier + counted s_waitcnt vmcnt(N) (never 0 in
// steady state), 2-deep B register prefetch, 1-deep A DMA prefetch, setprio
// around MFMA. Wait arithmetic documented inline. XCD-chunked grid kept.

typedef _Float16 f16;
typedef _Float16 f16x8 __attribute__((ext_vector_type(8)));
typedef float f32x4 __attribute__((ext_vector_type(4)));

#define T_TOK 2048
#define DDIM 2880
#define NEXP 8
#define IDIM 2880

#define BM 256
#define BK 64
#define NKT 45    // 2880/64
#define BN1 96
#define NNT1 30   // 2880/96
#define BN2 192
#define NNT2 15   // 2880/192
#define MAXMT 24  // 4096/256 + 8
#define NB1 (NNT1*MAXMT)  // 720 (div by 8)
#define NB2 (NNT2*MAXMT)  // 360 (div by 8)
#define SLOT_CAP 6144

// ---- workspace layout (bytes). ybuf aliases xh (xh dead before gemm2). ----
#define HBUF_OFF 0
#define HBUF_BYTES ((size_t)SLOT_CAP*IDIM*2)
#define XH_OFF   (HBUF_OFF + HBUF_BYTES)
#define XH_BYTES ((size_t)T_TOK*DDIM*2)
#define YBUF_OFF XH_OFF
#define YBUF_BYTES ((size_t)SLOT_CAP*DDIM*2)
#define META_OFF (YBUF_OFF + YBUF_BYTES)
#define M_COUNT 0
#define M_CUR 8
#define M_OFFS 16
#define M_NTILES 25
#define M_TILE_E 32
#define M_TILE_R0 96
#define M_SLOT_TOK 160
#define M_SLOT_OF (160+SLOT_CAP)
#define M_TOK_E (M_SLOT_OF + 2*T_TOK)
#define META_INTS (M_TOK_E + 2*T_TOK)
#define SLOTW_OFF (META_OFF + META_INTS*4)
#define TOKW_OFF  (SLOTW_OFF + SLOT_CAP*4)
#define WS_NEEDED ((size_t)TOKW_OFF + (size_t)T_TOK*2*4)

__device__ __forceinline__ int swz(int row) { return ((row ^ (row >> 3)) & 7) << 4; }

__device__ __forceinline__ void gload_lds16(const void* gp, void* lp) {
  __builtin_amdgcn_global_load_lds(
      (const __attribute__((address_space(1))) uint32_t*)gp,
      (__attribute__((address_space(3))) uint32_t*)lp,
      16, 0, 0);
}

__device__ __forceinline__ void ldB8(const float* bs, size_t stride, float4 (&v)[8]) {
#pragma unroll
  for (int j = 0; j < 8; j++) v[j] = *(const float4*)(bs + j * stride);
}

__device__ __forceinline__ void cvtB(const float4 (&v)[8], char* base, int bn0, int bk0) {
#pragma unroll
  for (int c = 0; c < 4; c++) {
    f16x8 p;
#pragma unroll
    for (int j = 0; j < 8; j++) {
      float fc = (c==0) ? v[j].x : (c==1) ? v[j].y : (c==2) ? v[j].z : v[j].w;
      p[j] = (f16)fc;
    }
    *(f16x8*)(base + (bn0 + c) * 128 + ((bk0 * 2) ^ swz(bn0 + c))) = p;
  }
}

// ---------------- router: f64 logits, top-2, pairwise softmax ----------------
__global__ __launch_bounds__(256) void k_router(
    const float* __restrict__ x, const float* __restrict__ wr,
    int* __restrict__ meta, float* __restrict__ tok_w) {
  const int lane = threadIdx.x & 63;
  const int t = blockIdx.x * 4 + (threadIdx.x >> 6);
  double acc[NEXP];
#pragma unroll
  for (int e = 0; e < NEXP; e++) acc[e] = 0.0;
  for (int d = lane; d < DDIM; d += 64) {
    float xv = x[(size_t)t * DDIM + d];
    float4 w0 = *(const float4*)(wr + (size_t)d * NEXP);
    float4 w1 = *(const float4*)(wr + (size_t)d * NEXP + 4);
    acc[0] += (double)xv * (double)w0.x;
    acc[1] += (double)xv * (double)w0.y;
    acc[2] += (double)xv * (double)w0.z;
    acc[3] += (double)xv * (double)w0.w;
    acc[4] += (double)xv * (double)w1.x;
    acc[5] += (double)xv * (double)w1.y;
    acc[6] += (double)xv * (double)w1.z;
    acc[7] += (double)xv * (double)w1.w;
  }
#pragma unroll
  for (int m = 32; m >= 1; m >>= 1) {
#pragma unroll
    for (int e = 0; e < NEXP; e++) acc[e] += __shfl_xor(acc[e], m, 64);
  }
  if (lane == 0) {
    int e0 = 0;
#pragma unroll
    for (int e = 1; e < NEXP; e++) if (acc[e] > acc[e0]) e0 = e;
    int e1 = (e0 == 0) ? 1 : 0;
#pragma unroll
    for (int e = 0; e < NEXP; e++) if (e != e0 && acc[e] > acc[e1]) e1 = e;
    double w0 = 1.0 / (1.0 + exp(acc[e1] - acc[e0]));
    meta[M_TOK_E + 2*t]     = e0;
    meta[M_TOK_E + 2*t + 1] = e1;
    tok_w[2*t]     = (float)w0;
    tok_w[2*t + 1] = (float)(1.0 - w0);
    atomicAdd(&meta[M_COUNT + e0], 1);
    atomicAdd(&meta[M_COUNT + e1], 1);
  }
}

// ---------------- x f32 -> f16 ----------------
__global__ __launch_bounds__(256) void k_xcvt(const float* __restrict__ x, f16* __restrict__ xh) {
  size_t i = ((size_t)blockIdx.x * 256 + threadIdx.x) * 8;
  float4 a = *(const float4*)(x + i);
  float4 b = *(const float4*)(x + i + 4);
  f16x8 v;
  v[0]=(f16)a.x; v[1]=(f16)a.y; v[2]=(f16)a.z; v[3]=(f16)a.w;
  v[4]=(f16)b.x; v[5]=(f16)b.y; v[6]=(f16)b.z; v[7]=(f16)b.w;
  *(f16x8*)(xh + i) = v;
}

// ---------------- scan ----------------
__global__ __launch_bounds__(64) void k_scan(int* __restrict__ meta, float* __restrict__ slot_w) {
  __shared__ int s_off[NEXP], s_cnt[NEXP], s_pc[NEXP];
  if (threadIdx.x == 0) {
    int run = 0, nt = 0;
    for (int e = 0; e < NEXP; e++) {
      int c = meta[M_COUNT + e];
      int mt = (c + BM - 1) / BM;
      meta[M_OFFS + e] = run;
      s_off[e] = run; s_cnt[e] = c; s_pc[e] = mt * BM;
      for (int j = 0; j < mt; j++) { meta[M_TILE_E + nt] = e; meta[M_TILE_R0 + nt] = run + j * BM; nt++; }
      run += mt * BM;
      meta[M_CUR + e] = 0;
    }
    meta[M_OFFS + NEXP] = run;
    meta[M_NTILES] = nt;
  }
  __syncthreads();
  for (int e = 0; e < NEXP; e++) {
    for (int i = s_cnt[e] + (int)threadIdx.x; i < s_pc[e]; i += 64) {
      meta[M_SLOT_TOK + s_off[e] + i] = 0;
      slot_w[s_off[e] + i] = 0.0f;
    }
  }
}

// ---------------- scatter ----------------
__global__ __launch_bounds__(256) void k_scatter(int* __restrict__ meta,
    float* __restrict__ slot_w, const float* __restrict__ tok_w) {
  int t = blockIdx.x * 256 + threadIdx.x;
  if (t >= T_TOK) return;
#pragma unroll
  for (int k = 0; k < 2; k++) {
    int e = meta[M_TOK_E + 2*t + k];
    int pos = atomicAdd(&meta[M_CUR + e], 1);
    int slot = meta[M_OFFS + e] + pos;
    meta[M_SLOT_TOK + slot] = t;
    slot_w[slot] = tok_w[2*t + k];
    meta[M_SLOT_OF + 2*t + k] = slot;
  }
}

// ---------------- GEMM1: h = silu(x@Wg)*(x@Wu); 8 waves = 4m x {gate,up} ----------------
__global__ __launch_bounds__(512, 2) void k_gemm1(
    const f16* __restrict__ xh, const float* __restrict__ wg, const float* __restrict__ wu,
    f16* __restrict__ hbuf, const int* __restrict__ meta) {
  const int id = blockIdx.x;
  const int sid = (id & 7) * (NB1 / 8) + (id >> 3);
  const int mt = sid % MAXMT;
  const int nb = sid / MAXMT;
  if (mt >= meta[M_NTILES]) return;
  const int e  = meta[M_TILE_E + mt];
  const int r0 = meta[M_TILE_R0 + mt];
  const int n0 = nb * BN1;

  __shared__ ushort sA[2][BM * BK];       // 64KB dbuf, DMA target
  __shared__ ushort sB[2][2][BN1 * BK];   // [buf][gate/up] 48KB

  const int tid  = threadIdx.x;
  const int lane = tid & 63;
  const int w    = tid >> 6;
  const int wm   = w >> 1;
  const int gu   = w & 1;

  const char* a_gbase[4];
  int a_loff[4];
#pragma unroll
  for (int i = 0; i < 4; i++) {
    int seg = w * 4 + i;
    int row = seg * 8 + (lane >> 3);
    int colb = ((lane & 7) * 16) ^ swz(row);
    int tok = meta[M_SLOT_TOK + r0 + row];
    a_gbase[i] = (const char*)(xh + (size_t)tok * DDIM) + colb;
    a_loff[i] = seg * 1024;
  }

  const int bm_ = tid / 192;            // 0=gate, 1=up (for tid<384)
  const int tt  = tid % 192;
  const int bn0 = (tt % 24) * 4;
  const int bk0 = (tt / 24) * 8;
  const bool bact = tid < 384;          // waves 0..5: B-staging role
  const float* bsrc = (bm_ ? wu : wg) + ((size_t)e * DDIM + bk0) * IDIM + n0 + bn0;

  float4 vB0[8], vB1[8];                // 2-deep B register prefetch; B(j) in set j&1
  f32x4 acc[4][6];
#pragma unroll
  for (int i = 0; i < 4; i++)
#pragma unroll
    for (int j = 0; j < 6; j++) acc[i][j] = {0.f,0.f,0.f,0.f};

  // ---- prologue: A-DMA(0); B(0) load+convert; B(1) in flight across barrier ----
#pragma unroll
  for (int i = 0; i < 4; i++) gload_lds16(a_gbase[i], (char*)sA[0] + a_loff[i]);
  if (bact) {
    ldB8(bsrc, IDIM, vB0);
    asm volatile("s_waitcnt vmcnt(0)" ::: "memory");          // B(0)+DMA(0) done
    cvtB(vB0, (char*)sB[0][bm_], bn0, bk0);
    ldB8(bsrc + (size_t)BK * IDIM, IDIM, vB1);                // B(1) flies
    asm volatile("s_waitcnt vmcnt(8) lgkmcnt(0)\n\ts_barrier" ::: "memory");
  } else {
    asm volatile("s_waitcnt vmcnt(0) lgkmcnt(0)\n\ts_barrier" ::: "memory");
  }

  // ---- main loop ----
  for (int kt = 0; kt < NKT; kt++) {
    const int cur = kt & 1;
    const bool nx1 = (kt + 1 < NKT), nx2 = (kt + 2 < NKT);
    if (nx1) {
#pragma unroll
      for (int i = 0; i < 4; i++)
        gload_lds16(a_gbase[i] + (kt + 1) * 128, (char*)sA[cur ^ 1] + a_loff[i]);
    }
    if (nx2 && bact) {                  // issue B(kt+2) into set (kt+2)&1 == cur
      const float* bs = bsrc + (size_t)(kt + 2) * BK * IDIM;
      if (cur == 0) ldB8(bs, IDIM, vB0); else ldB8(bs, IDIM, vB1);
    }
    // MFMA on sA[cur], sB[cur][gu]
    __builtin_amdgcn_s_setprio(1);
#pragma unroll
    for (int kk = 0; kk < 2; kk++) {
      const int gb = kk * 64 + ((lane >> 4) * 16);
      f16x8 af[4], bf[6];
#pragma unroll
      for (int fm = 0; fm < 4; fm++) {
        int row = wm * 64 + fm * 16 + (lane & 15);
        af[fm] = *(const f16x8*)((const char*)sA[cur] + row * 128 + (gb ^ swz(row)));
      }
#pragma unroll
      for (int fn = 0; fn < 6; fn++) {
        int row = fn * 16 + (lane & 15);
        bf[fn] = *(const f16x8*)((const char*)sB[cur][gu] + row * 128 + (gb ^ swz(row)));
      }
#pragma unroll
      for (int fm = 0; fm < 4; fm++)
#pragma unroll
        for (int fn = 0; fn < 6; fn++)
          acc[fm][fn] = __builtin_amdgcn_mfma_f32_16x16x32_f16(af[fm], bf[fn], acc[fm][fn], 0, 0, 0);
    }
    __builtin_amdgcn_s_setprio(0);
    // convert B(kt+1) (set cur^1) -> sB[cur^1]; newer in-flight: 4 DMA + (nx2?8:0)
    if (nx1 && bact) {
      if (nx2) asm volatile("s_waitcnt vmcnt(12)" ::: "memory");
      else     asm volatile("s_waitcnt vmcnt(4)" ::: "memory");
      if (cur == 0) cvtB(vB1, (char*)sB[1][bm_], bn0, bk0);
      else          cvtB(vB0, (char*)sB[0][bm_], bn0, bk0);
    }
    // end-of-iter: prove own DMAs retired (keep B(kt+2) flying), publish LDS
    if (nx1) {
      if (bact && nx2) asm volatile("s_waitcnt vmcnt(8) lgkmcnt(0)\n\ts_barrier" ::: "memory");
      else             asm volatile("s_waitcnt vmcnt(0) lgkmcnt(0)\n\ts_barrier" ::: "memory");
    }
  }

  // epilogue: up-waves pass U via LDS (f32, stride 100), 2 rounds of 32 rows
  float* u_lds = (float*)&sA[0][0];
  const int rl4 = (lane >> 4) * 4;
  const int cl  = lane & 15;
#pragma unroll
  for (int r = 0; r < 2; r++) {
    __syncthreads();
    if (gu == 1) {
#pragma unroll
      for (int fi = 0; fi < 2; fi++)
#pragma unroll
        for (int fn = 0; fn < 6; fn++)
#pragma unroll
          for (int j = 0; j < 4; j++)
            u_lds[wm * 3200 + (fi * 16 + rl4 + j) * 100 + fn * 16 + cl] = acc[2*r + fi][fn][j];
    }
    __syncthreads();
    if (gu == 0) {
#pragma unroll
      for (int fi = 0; fi < 2; fi++) {
        int fm = 2*r + fi;
#pragma unroll
        for (int fn = 0; fn < 6; fn++)
#pragma unroll
          for (int j = 0; j < 4; j++) {
            float u = u_lds[wm * 3200 + (fi * 16 + rl4 + j) * 100 + fn * 16 + cl];
            float g = acc[fm][fn][j];
            float h = g * u / (1.0f + __expf(-g));
            hbuf[(size_t)(r0 + wm * 64 + fm * 16 + rl4 + j) * IDIM + n0 + fn * 16 + cl] = (f16)h;
          }
      }
    }
  }
}

// ---------------- GEMM2: y = (h @ Wd) * slot_w; 8 waves = 4m x 2n ----------------
__global__ __launch_bounds__(512, 2) void k_gemm2(
    const f16* __restrict__ hbuf, const float* __restrict__ wd,
    f16* __restrict__ ybuf, const int* __restrict__ meta, const float* __restrict__ slot_w) {
  const int id = blockIdx.x;
  const int sid = (id & 7) * (NB2 / 8) + (id >> 3);
  const int mt = sid % MAXMT;
  const int nb = sid / MAXMT;
  if (mt >= meta[M_NTILES]) return;
  const int e  = meta[M_TILE_E + mt];
  const int r0 = meta[M_TILE_R0 + mt];
  const int n0 = nb * BN2;

  __shared__ ushort sA[2][BM * BK];     // 64KB
  __shared__ ushort sB1[2][BN2 * BK];   // 48KB

  const int tid  = threadIdx.x;
  const int lane = tid & 63;
  const int w    = tid >> 6;
  const int wm   = w >> 1;
  const int wn   = w & 1;

  const char* a_gbase[4];
  int a_loff[4];
#pragma unroll
  for (int i = 0; i < 4; i++) {
    int seg = w * 4 + i;
    int row = seg * 8 + (lane >> 3);
    int colb = ((lane & 7) * 16) ^ swz(row);
    a_gbase[i] = (const char*)(hbuf + (size_t)(r0 + row) * IDIM) + colb;
    a_loff[i] = seg * 1024;
  }

  const int half = tid / 192;
  const int tt   = tid % 192;
  const int bn0  = half * 96 + (tt % 24) * 4;
  const int bk0  = (tt / 24) * 8;
  const bool bact = tid < 384;
  const float* bsrc = wd + ((size_t)e * IDIM + bk0) * DDIM + n0 + bn0;

  float4 vB0[8], vB1[8];
  f32x4 acc[4][6];
#pragma unroll
  for (int i = 0; i < 4; i++)
#pragma unroll
    for (int j = 0; j < 6; j++) acc[i][j] = {0.f,0.f,0.f,0.f};

  // ---- prologue ----
#pragma unroll
  for (int i = 0; i < 4; i++) gload_lds16(a_gbase[i], (char*)sA[0] + a_loff[i]);
  if (bact) {
    ldB8(bsrc, DDIM, vB0);
    asm volatile("s_waitcnt vmcnt(0)" ::: "memory");
    cvtB(vB0, (char*)sB1[0], bn0, bk0);
    ldB8(bsrc + (size_t)BK * DDIM, DDIM, vB1);
    asm volatile("s_waitcnt vmcnt(8) lgkmcnt(0)\n\ts_barrier" ::: "memory");
  } else {
    asm volatile("s_waitcnt vmcnt(0) lgkmcnt(0)\n\ts_barrier" ::: "memory");
  }

  // ---- main loop ----
  for (int kt = 0; kt < NKT; kt++) {
    const int cur = kt & 1;
    const bool nx1 = (kt + 1 < NKT), nx2 = (kt + 2 < NKT);
    if (nx1) {
#pragma unroll
      for (int i = 0; i < 4; i++)
        gload_lds16(a_gbase[i] + (kt + 1) * 128, (char*)sA[cur ^ 1] + a_loff[i]);
    }
    if (nx2 && bact) {
      const float* bs = bsrc + (size_t)(kt + 2) * BK * DDIM;
      if (cur == 0) ldB8(bs, DDIM, vB0); else ldB8(bs, DDIM, vB1);
    }
    __builtin_amdgcn_s_setprio(1);
#pragma unroll
    for (int kk = 0; kk < 2; kk++) {
      const int gb = kk * 64 + ((lane >> 4) * 16);
      f16x8 af[4], bf[6];
#pragma unroll
      for (int fm = 0; fm < 4; fm++) {
        int row = wm * 64 + fm * 16 + (lane & 15);
        af[fm] = *(const f16x8*)((const char*)sA[cur] + row * 128 + (gb ^ swz(row)));
      }
#pragma unroll
      for (int fn = 0; fn < 6; fn++) {
        int row = wn * 96 + fn * 16 + (lane & 15);
        bf[fn] = *(const f16x8*)((const char*)sB1[cur] + row * 128 + (gb ^ swz(row)));
      }
#pragma unroll
      for (int fm = 0; fm < 4; fm++)
#pragma unroll
        for (int fn = 0; fn < 6; fn++)
          acc[fm][fn] = __builtin_amdgcn_mfma_f32_16x16x32_f16(af[fm], bf[fn], acc[fm][fn], 0, 0, 0);
    }
    __builtin_amdgcn_s_setprio(0);
    if (nx1 && bact) {
      if (nx2) asm volatile("s_waitcnt vmcnt(12)" ::: "memory");
      else     asm volatile("s_waitcnt vmcnt(4)" ::: "memory");
      if (cur == 0) cvtB(vB1, (char*)sB1[1], bn0, bk0);
      else          cvtB(vB0, (char*)sB1[0], bn0, bk0);
    }
    if (nx1) {
      if (bact && nx2) asm volatile("s_waitcnt vmcnt(8) lgkmcnt(0)\n\ts_barrier" ::: "memory");
      else             asm volatile("s_waitcnt vmcnt(0) lgkmcnt(0)\n\ts_barrier" ::: "memory");
    }
  }

  const int rl4 = (lane >> 4) * 4;
  const int cl  = lane & 15;
#pragma unroll
  for (int fm = 0; fm < 4; fm++)
#pragma unroll
    for (int j = 0; j < 4; j++) {
      int row = wm * 64 + fm * 16 + rl4 + j;
      int slot = r0 + row;
      float wv = slot_w[slot];
#pragma unroll
      for (int fn = 0; fn < 6; fn++) {
        int col = n0 + wn * 96 + fn * 16 + cl;
        ybuf[(size_t)slot * DDIM + col] = (f16)(acc[fm][fn][j] * wv);
      }
    }
}

// ---------------- combine ----------------
__global__ __launch_bounds__(256) void k_combine(const f16* __restrict__ ybuf,
    const int* __restrict__ meta, float* __restrict__ out) {
  size_t idx = (size_t)blockIdx.x * 256 + threadIdx.x;
  int t = (int)(idx / (DDIM/8));
  int c = (int)(idx % (DDIM/8));
  int s0 = meta[M_SLOT_OF + 2*t];
  int s1 = meta[M_SLOT_OF + 2*t + 1];
  f16x8 a = *(const f16x8*)(ybuf + (size_t)s0 * DDIM + c*8);
  f16x8 b = *(const f16x8*)(ybuf + (size_t)s1 * DDIM + c*8);
  float4 o0, o1;
  o0.x = (float)a[0] + (float)b[0];
  o0.y = (float)a[1] + (float)b[1];
  o0.z = (float)a[2] + (float)b[2];
  o0.w = (float)a[3] + (float)b[3];
  o1.x = (float)a[4] + (float)b[4];
  o1.y = (float)a[5] + (float)b[5];
  o1.z = (float)a[6] + (float)b[6];
  o1.w = (float)a[7] + (float)b[7];
  float* op = out + (size_t)t * DDIM + c*8;
  *(float4*)op = o0;
  *(float4*)(op + 4) = o1;
}

extern "C" void kernel_launch(void* const* d_in, const int* in_sizes, int n_in,
                              void* d_out, int out_size, void* d_ws, size_t ws_size,
                              hipStream_t stream) {
  const float* x  = (const float*)d_in[0];
  const float* wr = (const float*)d_in[1];
  const float* wg = (const float*)d_in[2];
  const float* wu = (const float*)d_in[3];
  const float* wd = (const float*)d_in[4];
  float* out = (float*)d_out;
  char* ws = (char*)d_ws;
  if (ws_size < WS_NEEDED) return;

  f16* hbuf  = (f16*)(ws + HBUF_OFF);
  f16* xh    = (f16*)(ws + XH_OFF);
  f16* ybuf  = (f16*)(ws + YBUF_OFF);
  int* meta  = (int*)(ws + META_OFF);
  float* slot_w = (float*)(ws + SLOTW_OFF);
  float* tok_w  = (float*)(ws + TOKW_OFF);

  hipMemsetAsync(meta + M_COUNT, 0, NEXP * sizeof(int), stream);
  k_router<<<T_TOK/4, 256, 0, stream>>>(x, wr, meta, tok_w);
  k_xcvt<<<(T_TOK*DDIM/8 + 255)/256, 256, 0, stream>>>(x, xh);
  k_scan<<<1, 64, 0, stream>>>(meta, slot_w);
  k_scatter<<<(T_TOK + 255)/256, 256, 0, stream>>>(meta, slot_w, tok_w);
  k_gemm1<<<NB1, 512, 0, stream>>>(xh, wg, wu, hbuf, meta);
  k_gemm2<<<NB2, 512, 0, stream>>>(hbuf, wd, ybuf, meta, slot_w);
  k_combine<<<(T_TOK*DDIM/8 + 255)/256, 256, 0, stream>>>(ybuf, meta, out);
}

// Round 6
// 691.262 us; speedup vs baseline: 1.1372x; 1.1372x over previous
//
#include <hip/hip_runtime.h>
#include <hip/hip_fp16.h>
#include <stdint.h>
#include <math.h>

// MoE MLP block: router top-2 + 8 experts SiLU-GLU, fp16 MFMA.
// v6: pre-transpose+convert weights to f16 [E][N][K] (k_cvt_w), then both
// GEMMs are pure m97-template kernels: global_load_lds-only staging (A and B),
// no in-loop conversion, single-buffered 2-barrier k-loop, 3 blocks/CU.
// Host-side fallback to v4 fused path if ws_size too small.

typedef _Float16 f16;
typedef _Float16 f16x8 __attribute__((ext_vector_type(8)));
typedef float f32x4 __attribute__((ext_vector_type(4)));

#define T_TOK 2048
#define DDIM 2880
#define NEXP 8
#define IDIM 2880
#define BK 64
#define NKT 45

// ---- path A (preconverted) params ----
#define BM_A 128
#define BN1_A 96
#define BN2_A 192
#define MAXMT_A 40
#define NB1_A (30*MAXMT_A)   // 1200, div 8
#define NB2_A (15*MAXMT_A)   // 600, div 8
// ---- path B (fallback, v4) params ----
#define BM_B 256
#define BN1_B 96
#define BN2_B 192
#define MAXMT_B 24
#define NB1_B (30*MAXMT_B)   // 720
#define NB2_B (15*MAXMT_B)   // 360

#define SLOT_CAP 6144

// ---- shared meta (int32 indices) ----
#define M_COUNT 0
#define M_CUR 8
#define M_OFFS 16
#define M_NTILES 25
#define M_TILE_E 32
#define M_TILE_R0 96
#define M_SLOT_TOK 160
#define M_SLOT_OF (160+SLOT_CAP)
#define M_TOK_E (M_SLOT_OF + 2*T_TOK)
#define META_INTS (M_TOK_E + 2*T_TOK)

// ---- path A workspace layout (bytes) ----
#define WT_B   ((size_t)NEXP*DDIM*IDIM*2)          // 132.7MB per weight tensor
#define A_WGT  ((size_t)0)
#define A_WUT  (A_WGT + WT_B)
#define A_WDT  A_WGT                                // alias: wgT dead after gemm1
#define A_HBUF (A_WUT + WT_B)
#define A_YBUF (A_HBUF + (size_t)5120*IDIM*2)
#define A_XH   (A_YBUF + (size_t)5120*DDIM*2)
#define A_META (A_XH + (size_t)T_TOK*DDIM*2)
#define A_SLOTW (A_META + (size_t)META_INTS*4)
#define A_TOKW  (A_SLOTW + (size_t)SLOT_CAP*4)
#define A_NEED  (A_TOKW + (size_t)T_TOK*2*4)

// ---- path B workspace layout (bytes) ----
#define B_HBUF ((size_t)0)
#define B_XH   (B_HBUF + (size_t)SLOT_CAP*IDIM*2)
#define B_YBUF B_XH
#define B_META (B_YBUF + (size_t)SLOT_CAP*DDIM*2)
#define B_SLOTW (B_META + (size_t)META_INTS*4)
#define B_TOKW  (B_SLOTW + (size_t)SLOT_CAP*4)
#define B_NEED  (B_TOKW + (size_t)T_TOK*2*4)

__device__ __forceinline__ int swz(int row) { return ((row ^ (row >> 3)) & 7) << 4; }

__device__ __forceinline__ void gload_lds16(const void* gp, void* lp) {
  __builtin_amdgcn_global_load_lds(
      (const __attribute__((address_space(1))) uint32_t*)gp,
      (__attribute__((address_space(3))) uint32_t*)lp,
      16, 0, 0);
}

// ---------------- router: f64 logits, top-2, pairwise softmax ----------------
__global__ __launch_bounds__(256) void k_router(
    const float* __restrict__ x, const float* __restrict__ wr,
    int* __restrict__ meta, float* __restrict__ tok_w) {
  const int lane = threadIdx.x & 63;
  const int t = blockIdx.x * 4 + (threadIdx.x >> 6);
  double acc[NEXP];
#pragma unroll
  for (int e = 0; e < NEXP; e++) acc[e] = 0.0;
  for (int d = lane; d < DDIM; d += 64) {
    float xv = x[(size_t)t * DDIM + d];
    float4 w0 = *(const float4*)(wr + (size_t)d * NEXP);
    float4 w1 = *(const float4*)(wr + (size_t)d * NEXP + 4);
    acc[0] += (double)xv * (double)w0.x;
    acc[1] += (double)xv * (double)w0.y;
    acc[2] += (double)xv * (double)w0.z;
    acc[3] += (double)xv * (double)w0.w;
    acc[4] += (double)xv * (double)w1.x;
    acc[5] += (double)xv * (double)w1.y;
    acc[6] += (double)xv * (double)w1.z;
    acc[7] += (double)xv * (double)w1.w;
  }
#pragma unroll
  for (int m = 32; m >= 1; m >>= 1) {
#pragma unroll
    for (int e = 0; e < NEXP; e++) acc[e] += __shfl_xor(acc[e], m, 64);
  }
  if (lane == 0) {
    int e0 = 0;
#pragma unroll
    for (int e = 1; e < NEXP; e++) if (acc[e] > acc[e0]) e0 = e;
    int e1 = (e0 == 0) ? 1 : 0;
#pragma unroll
    for (int e = 0; e < NEXP; e++) if (e != e0 && acc[e] > acc[e1]) e1 = e;
    double w0 = 1.0 / (1.0 + exp(acc[e1] - acc[e0]));
    meta[M_TOK_E + 2*t]     = e0;
    meta[M_TOK_E + 2*t + 1] = e1;
    tok_w[2*t]     = (float)w0;
    tok_w[2*t + 1] = (float)(1.0 - w0);
    atomicAdd(&meta[M_COUNT + e0], 1);
    atomicAdd(&meta[M_COUNT + e1], 1);
  }
}

// ---------------- x f32 -> f16 ----------------
__global__ __launch_bounds__(256) void k_xcvt(const float* __restrict__ x, f16* __restrict__ xh) {
  size_t i = ((size_t)blockIdx.x * 256 + threadIdx.x) * 8;
  float4 a = *(const float4*)(x + i);
  float4 b = *(const float4*)(x + i + 4);
  f16x8 v;
  v[0]=(f16)a.x; v[1]=(f16)a.y; v[2]=(f16)a.z; v[3]=(f16)a.w;
  v[4]=(f16)b.x; v[5]=(f16)b.y; v[6]=(f16)b.z; v[7]=(f16)b.w;
  *(f16x8*)(xh + i) = v;
}

// ---------------- weight transpose-convert: f32 [2880][2880] -> f16 [2880][2880]^T ----------------
__global__ __launch_bounds__(256) void k_cvt_w(const float* __restrict__ src, f16* __restrict__ dst) {
  __shared__ f16 t[64][72];    // 9.2KB; row stride 144B (16B-aligned)
  const int tile = blockIdx.x;         // 45*45
  const int e = blockIdx.y;
  const int k0 = (tile / 45) * 64;
  const int i0 = (tile % 45) * 64;
  const int tid = threadIdx.x;
  const float* sp = src + ((size_t)e * DDIM + k0) * IDIM + i0;
#pragma unroll
  for (int p = 0; p < 4; p++) {
    int kr = p * 16 + (tid >> 4);
    int c0 = (tid & 15) * 4;
    float4 v = *(const float4*)(sp + (size_t)kr * IDIM + c0);
    t[c0 + 0][kr] = (f16)v.x;
    t[c0 + 1][kr] = (f16)v.y;
    t[c0 + 2][kr] = (f16)v.z;
    t[c0 + 3][kr] = (f16)v.w;
  }
  __syncthreads();
#pragma unroll
  for (int p = 0; p < 2; p++) {
    int row = tid >> 2;
    int ch = (tid & 3) + p * 4;
    f16x8 o = *(const f16x8*)&t[row][ch * 8];
    *(f16x8*)(dst + ((size_t)e * IDIM + i0 + row) * DDIM + k0 + ch * 8) = o;
  }
}

// ---------------- scan: offsets, tile map, pad fill, zero cursors ----------------
__global__ __launch_bounds__(64) void k_scan(int* __restrict__ meta, float* __restrict__ slot_w, int bm) {
  __shared__ int s_off[NEXP], s_cnt[NEXP], s_pc[NEXP];
  if (threadIdx.x == 0) {
    int run = 0, nt = 0;
    for (int e = 0; e < NEXP; e++) {
      int c = meta[M_COUNT + e];
      int mt = (c + bm - 1) / bm;
      meta[M_OFFS + e] = run;
      s_off[e] = run; s_cnt[e] = c; s_pc[e] = mt * bm;
      for (int j = 0; j < mt; j++) { meta[M_TILE_E + nt] = e; meta[M_TILE_R0 + nt] = run + j * bm; nt++; }
      run += mt * bm;
      meta[M_CUR + e] = 0;
    }
    meta[M_OFFS + NEXP] = run;
    meta[M_NTILES] = nt;
  }
  __syncthreads();
  for (int e = 0; e < NEXP; e++) {
    for (int i = s_cnt[e] + (int)threadIdx.x; i < s_pc[e]; i += 64) {
      meta[M_SLOT_TOK + s_off[e] + i] = 0;
      slot_w[s_off[e] + i] = 0.0f;
    }
  }
}

// ---------------- scatter ----------------
__global__ __launch_bounds__(256) void k_scatter(int* __restrict__ meta,
    float* __restrict__ slot_w, const float* __restrict__ tok_w) {
  int t = blockIdx.x * 256 + threadIdx.x;
  if (t >= T_TOK) return;
#pragma unroll
  for (int k = 0; k < 2; k++) {
    int e = meta[M_TOK_E + 2*t + k];
    int pos = atomicAdd(&meta[M_CUR + e], 1);
    int slot = meta[M_OFFS + e] + pos;
    meta[M_SLOT_TOK + slot] = t;
    slot_w[slot] = tok_w[2*t + k];
    meta[M_SLOT_OF + 2*t + k] = slot;
  }
}

// ================= PATH A: m97-template GEMMs (all-f16, DMA-only staging) =================

// GEMM1: h = silu(x@Wg)*(x@Wu); 128x96 tile, 4 waves (2m x 2n), gate+up per wave
__global__ __launch_bounds__(256, 3) void kg1(
    const f16* __restrict__ xh, const f16* __restrict__ wgT, const f16* __restrict__ wuT,
    f16* __restrict__ hbuf, const int* __restrict__ meta) {
  const int id = blockIdx.x;
  const int sid = (id & 7) * (NB1_A / 8) + (id >> 3);
  const int mt = sid % MAXMT_A;
  const int nb = sid / MAXMT_A;
  if (mt >= meta[M_NTILES]) return;
  const int e  = meta[M_TILE_E + mt];
  const int r0 = meta[M_TILE_R0 + mt];
  const int n0 = nb * BN1_A;

  __shared__ ushort sA[BM_A * BK];     // 16KB
  __shared__ ushort sBg[BN1_A * BK];   // 12KB
  __shared__ ushort sBu[BN1_A * BK];   // 12KB

  const int tid = threadIdx.x;
  const int lane = tid & 63;
  const int w = tid >> 6;
  const int wm = w >> 1, wn = w & 1;

  // A staging (gathered token rows): 16 segs x 1KB; wave w owns segs 4w..4w+3
  const char* aG[4]; int aL[4];
#pragma unroll
  for (int i = 0; i < 4; i++) {
    int seg = w * 4 + i;
    int row = seg * 8 + (lane >> 3);
    int colb = ((lane & 7) * 16) ^ swz(row);
    int tok = meta[M_SLOT_TOK + r0 + row];
    aG[i] = (const char*)(xh + (size_t)tok * DDIM) + colb;
    aL[i] = seg * 1024;
  }
  // B staging (K-major f16 weight rows): 12 segs each; wave w owns segs 3w..3w+2
  const char* gG[3]; const char* uG[3]; int bL[3];
#pragma unroll
  for (int i = 0; i < 3; i++) {
    int seg = w * 3 + i;
    int row = seg * 8 + (lane >> 3);
    int colb = ((lane & 7) * 16) ^ swz(row);
    gG[i] = (const char*)(wgT + ((size_t)e * IDIM + n0 + row) * DDIM) + colb;
    uG[i] = (const char*)(wuT + ((size_t)e * IDIM + n0 + row) * DDIM) + colb;
    bL[i] = seg * 1024;
  }

  f32x4 accG[4][3], accU[4][3];
#pragma unroll
  for (int i = 0; i < 4; i++)
#pragma unroll
    for (int j = 0; j < 3; j++) { accG[i][j] = {0.f,0.f,0.f,0.f}; accU[i][j] = {0.f,0.f,0.f,0.f}; }

  for (int kt = 0; kt < NKT; kt++) {
    __syncthreads();   // LDS free to overwrite
#pragma unroll
    for (int i = 0; i < 4; i++) gload_lds16(aG[i] + kt * 128, (char*)sA + aL[i]);
#pragma unroll
    for (int i = 0; i < 3; i++) gload_lds16(gG[i] + kt * 128, (char*)sBg + bL[i]);
#pragma unroll
    for (int i = 0; i < 3; i++) gload_lds16(uG[i] + kt * 128, (char*)sBu + bL[i]);
    __syncthreads();   // compiler drains vmcnt(0) here -> tile ready
#pragma unroll
    for (int kk = 0; kk < 2; kk++) {
      const int gb = kk * 64 + ((lane >> 4) * 16);
      f16x8 af[4], bg[3], bu[3];
#pragma unroll
      for (int fm = 0; fm < 4; fm++) {
        int row = wm * 64 + fm * 16 + (lane & 15);
        af[fm] = *(const f16x8*)((const char*)sA + row * 128 + (gb ^ swz(row)));
      }
#pragma unroll
      for (int fn = 0; fn < 3; fn++) {
        int row = wn * 48 + fn * 16 + (lane & 15);
        bg[fn] = *(const f16x8*)((const char*)sBg + row * 128 + (gb ^ swz(row)));
        bu[fn] = *(const f16x8*)((const char*)sBu + row * 128 + (gb ^ swz(row)));
      }
#pragma unroll
      for (int fm = 0; fm < 4; fm++)
#pragma unroll
        for (int fn = 0; fn < 3; fn++) {
          accG[fm][fn] = __builtin_amdgcn_mfma_f32_16x16x32_f16(af[fm], bg[fn], accG[fm][fn], 0, 0, 0);
          accU[fm][fn] = __builtin_amdgcn_mfma_f32_16x16x32_f16(af[fm], bu[fn], accU[fm][fn], 0, 0, 0);
        }
    }
  }
  // epilogue: SiLU in-wave (gate & up both local)
  const int rl4 = (lane >> 4) * 4;
  const int cl  = lane & 15;
#pragma unroll
  for (int fm = 0; fm < 4; fm++)
#pragma unroll
    for (int fn = 0; fn < 3; fn++)
#pragma unroll
      for (int j = 0; j < 4; j++) {
        int row = wm * 64 + fm * 16 + rl4 + j;
        int col = n0 + wn * 48 + fn * 16 + cl;
        float g = accG[fm][fn][j], u = accU[fm][fn][j];
        float h = g * u / (1.0f + __expf(-g));
        hbuf[(size_t)(r0 + row) * IDIM + col] = (f16)h;
      }
}

// GEMM2: y = (h @ Wd) * slot_w; 128x192 tile, 4 waves (2m x 2n)
__global__ __launch_bounds__(256, 3) void kg2(
    const f16* __restrict__ hbuf, const f16* __restrict__ wdT,
    f16* __restrict__ ybuf, const int* __restrict__ meta, const float* __restrict__ slot_w) {
  const int id = blockIdx.x;
  const int sid = (id & 7) * (NB2_A / 8) + (id >> 3);
  const int mt = sid % MAXMT_A;
  const int nb = sid / MAXMT_A;
  if (mt >= meta[M_NTILES]) return;
  const int e  = meta[M_TILE_E + mt];
  const int r0 = meta[M_TILE_R0 + mt];
  const int n0 = nb * BN2_A;

  __shared__ ushort sA[BM_A * BK];     // 16KB
  __shared__ ushort sB[BN2_A * BK];    // 24KB

  const int tid = threadIdx.x;
  const int lane = tid & 63;
  const int w = tid >> 6;
  const int wm = w >> 1, wn = w & 1;

  const char* aG[4]; int aL[4];
#pragma unroll
  for (int i = 0; i < 4; i++) {
    int seg = w * 4 + i;
    int row = seg * 8 + (lane >> 3);
    int colb = ((lane & 7) * 16) ^ swz(row);
    aG[i] = (const char*)(hbuf + (size_t)(r0 + row) * IDIM) + colb;
    aL[i] = seg * 1024;
  }
  const char* bG[6]; int bL[6];
#pragma unroll
  for (int i = 0; i < 6; i++) {
    int seg = w * 6 + i;
    int row = seg * 8 + (lane >> 3);
    int colb = ((lane & 7) * 16) ^ swz(row);
    bG[i] = (const char*)(wdT + ((size_t)e * DDIM + n0 + row) * IDIM) + colb;
    bL[i] = seg * 1024;
  }

  f32x4 acc[4][6];
#pragma unroll
  for (int i = 0; i < 4; i++)
#pragma unroll
    for (int j = 0; j < 6; j++) acc[i][j] = {0.f,0.f,0.f,0.f};

  for (int kt = 0; kt < NKT; kt++) {
    __syncthreads();
#pragma unroll
    for (int i = 0; i < 4; i++) gload_lds16(aG[i] + kt * 128, (char*)sA + aL[i]);
#pragma unroll
    for (int i = 0; i < 6; i++) gload_lds16(bG[i] + kt * 128, (char*)sB + bL[i]);
    __syncthreads();
#pragma unroll
    for (int kk = 0; kk < 2; kk++) {
      const int gb = kk * 64 + ((lane >> 4) * 16);
      f16x8 af[4], bf[6];
#pragma unroll
      for (int fm = 0; fm < 4; fm++) {
        int row = wm * 64 + fm * 16 + (lane & 15);
        af[fm] = *(const f16x8*)((const char*)sA + row * 128 + (gb ^ swz(row)));
      }
#pragma unroll
      for (int fn = 0; fn < 6; fn++) {
        int row = wn * 96 + fn * 16 + (lane & 15);
        bf[fn] = *(const f16x8*)((const char*)sB + row * 128 + (gb ^ swz(row)));
      }
#pragma unroll
      for (int fm = 0; fm < 4; fm++)
#pragma unroll
        for (int fn = 0; fn < 6; fn++)
          acc[fm][fn] = __builtin_amdgcn_mfma_f32_16x16x32_f16(af[fm], bf[fn], acc[fm][fn], 0, 0, 0);
    }
  }
  const int rl4 = (lane >> 4) * 4;
  const int cl  = lane & 15;
#pragma unroll
  for (int fm = 0; fm < 4; fm++)
#pragma unroll
    for (int j = 0; j < 4; j++) {
      int row = wm * 64 + fm * 16 + rl4 + j;
      int slot = r0 + row;
      float wv = slot_w[slot];
#pragma unroll
      for (int fn = 0; fn < 6; fn++) {
        int col = n0 + wn * 96 + fn * 16 + cl;
        ybuf[(size_t)slot * DDIM + col] = (f16)(acc[fm][fn][j] * wv);
      }
    }
}

// ---------------- combine: out[t] = y[slot0] + y[slot1] ----------------
__global__ __launch_bounds__(256) void k_combine(const f16* __restrict__ ybuf,
    const int* __restrict__ meta, float* __restrict__ out) {
  size_t idx = (size_t)blockIdx.x * 256 + threadIdx.x;
  int t = (int)(idx / (DDIM/8));
  int c = (int)(idx % (DDIM/8));
  int s0 = meta[M_SLOT_OF + 2*t];
  int s1 = meta[M_SLOT_OF + 2*t + 1];
  f16x8 a = *(const f16x8*)(ybuf + (size_t)s0 * DDIM + c*8);
  f16x8 b = *(const f16x8*)(ybuf + (size_t)s1 * DDIM + c*8);
  float4 o0, o1;
  o0.x = (float)a[0] + (float)b[0];
  o0.y = (float)a[1] + (float)b[1];
  o0.z = (float)a[2] + (float)b[2];
  o0.w = (float)a[3] + (float)b[3];
  o1.x = (float)a[4] + (float)b[4];
  o1.y = (float)a[5] + (float)b[5];
  o1.z = (float)a[6] + (float)b[6];
  o1.w = (float)a[7] + (float)b[7];
  float* op = out + (size_t)t * DDIM + c*8;
  *(float4*)op = o0;
  *(float4*)(op + 4) = o1;
}

// ================= PATH B: fallback fused GEMMs (v4, verified) =================

__global__ __launch_bounds__(512, 2) void kg1_fb(
    const f16* __restrict__ xh, const float* __restrict__ wg, const float* __restrict__ wu,
    f16* __restrict__ hbuf, const int* __restrict__ meta) {
  const int id = blockIdx.x;
  const int sid = (id & 7) * (NB1_B / 8) + (id >> 3);
  const int mt = sid % MAXMT_B;
  const int nb = sid / MAXMT_B;
  if (mt >= meta[M_NTILES]) return;
  const int e  = meta[M_TILE_E + mt];
  const int r0 = meta[M_TILE_R0 + mt];
  const int n0 = nb * BN1_B;

  __shared__ ushort sA[2][BM_B * BK];
  __shared__ ushort sB[2][2][BN1_B * BK];

  const int tid  = threadIdx.x;
  const int lane = tid & 63;
  const int w    = tid >> 6;
  const int wm   = w >> 1;
  const int gu   = w & 1;

  const char* a_gbase[4];
  int a_loff[4];
#pragma unroll
  for (int i = 0; i < 4; i++) {
    int seg = w * 4 + i;
    int row = seg * 8 + (lane >> 3);
    int colb = ((lane & 7) * 16) ^ swz(row);
    int tok = meta[M_SLOT_TOK + r0 + row];
    a_gbase[i] = (const char*)(xh + (size_t)tok * DDIM) + colb;
    a_loff[i] = seg * 1024;
  }
  const int bm_ = tid / 192;
  const int tt  = tid % 192;
  const int bn0 = (tt % 24) * 4;
  const int bk0 = (tt / 24) * 8;
  const bool bact = tid < 384;
  const float* bsrc = (bm_ ? wu : wg) + ((size_t)e * DDIM + bk0) * IDIM + n0 + bn0;

  float4 vB[8];
  f32x4 acc[4][6];
#pragma unroll
  for (int i = 0; i < 4; i++)
#pragma unroll
    for (int j = 0; j < 6; j++) acc[i][j] = {0.f,0.f,0.f,0.f};

#pragma unroll
  for (int i = 0; i < 4; i++) gload_lds16(a_gbase[i], (char*)sA[0] + a_loff[i]);
  if (bact) {
#pragma unroll
    for (int j = 0; j < 8; j++) vB[j] = *(const float4*)(bsrc + (size_t)j * IDIM);
#pragma unroll
    for (int c = 0; c < 4; c++) {
      f16x8 p;
#pragma unroll
      for (int j = 0; j < 8; j++) {
        float fc = (c==0) ? vB[j].x : (c==1) ? vB[j].y : (c==2) ? vB[j].z : vB[j].w;
        p[j] = (f16)fc;
      }
      *(f16x8*)((char*)sB[0][bm_] + (bn0 + c) * 128 + ((bk0 * 2) ^ swz(bn0 + c))) = p;
    }
  }
  __syncthreads();

  for (int kt = 0; kt < NKT; kt++) {
    const int cur = kt & 1;
    if (kt + 1 < NKT) {
#pragma unroll
      for (int i = 0; i < 4; i++)
        gload_lds16(a_gbase[i] + (kt + 1) * 128, (char*)sA[cur ^ 1] + a_loff[i]);
      if (bact) {
        const float* bs = bsrc + (size_t)(kt + 1) * BK * IDIM;
#pragma unroll
        for (int j = 0; j < 8; j++) vB[j] = *(const float4*)(bs + (size_t)j * IDIM);
      }
    }
#pragma unroll
    for (int kk = 0; kk < 2; kk++) {
      const int gb = kk * 64 + ((lane >> 4) * 16);
      f16x8 af[4], bf[6];
#pragma unroll
      for (int fm = 0; fm < 4; fm++) {
        int row = wm * 64 + fm * 16 + (lane & 15);
        af[fm] = *(const f16x8*)((const char*)sA[cur] + row * 128 + (gb ^ swz(row)));
      }
#pragma unroll
      for (int fn = 0; fn < 6; fn++) {
        int row = fn * 16 + (lane & 15);
        bf[fn] = *(const f16x8*)((const char*)sB[cur][gu] + row * 128 + (gb ^ swz(row)));
      }
#pragma unroll
      for (int fm = 0; fm < 4; fm++)
#pragma unroll
        for (int fn = 0; fn < 6; fn++)
          acc[fm][fn] = __builtin_amdgcn_mfma_f32_16x16x32_f16(af[fm], bf[fn], acc[fm][fn], 0, 0, 0);
    }
    if (kt + 1 < NKT && bact) {
#pragma unroll
      for (int c = 0; c < 4; c++) {
        f16x8 p;
#pragma unroll
        for (int j = 0; j < 8; j++) {
          float fc = (c==0) ? vB[j].x : (c==1) ? vB[j].y : (c==2) ? vB[j].z : vB[j].w;
          p[j] = (f16)fc;
        }
        *(f16x8*)((char*)sB[cur ^ 1][bm_] + (bn0 + c) * 128 + ((bk0 * 2) ^ swz(bn0 + c))) = p;
      }
    }
    __syncthreads();
  }

  float* u_lds = (float*)&sA[0][0];
  const int rl4 = (lane >> 4) * 4;
  const int cl  = lane & 15;
#pragma unroll
  for (int r = 0; r < 2; r++) {
    __syncthreads();
    if (gu == 1) {
#pragma unroll
      for (int fi = 0; fi < 2; fi++)
#pragma unroll
        for (int fn = 0; fn < 6; fn++)
#pragma unroll
          for (int j = 0; j < 4; j++)
            u_lds[wm * 3200 + (fi * 16 + rl4 + j) * 100 + fn * 16 + cl] = acc[2*r + fi][fn][j];
    }
    __syncthreads();
    if (gu == 0) {
#pragma unroll
      for (int fi = 0; fi < 2; fi++) {
        int fm = 2*r + fi;
#pragma unroll
        for (int fn = 0; fn < 6; fn++)
#pragma unroll
          for (int j = 0; j < 4; j++) {
            float u = u_lds[wm * 3200 + (fi * 16 + rl4 + j) * 100 + fn * 16 + cl];
            float g = acc[fm][fn][j];
            float h = g * u / (1.0f + __expf(-g));
            hbuf[(size_t)(r0 + wm * 64 + fm * 16 + rl4 + j) * IDIM + n0 + fn * 16 + cl] = (f16)h;
          }
      }
    }
  }
}

__global__ __launch_bounds__(512, 2) void kg2_fb(
    const f16* __restrict__ hbuf, const float* __restrict__ wd,
    f16* __restrict__ ybuf, const int* __restrict__ meta, const float* __restrict__ slot_w) {
  const int id = blockIdx.x;
  const int sid = (id & 7) * (NB2_B / 8) + (id >> 3);
  const int mt = sid % MAXMT_B;
  const int nb = sid / MAXMT_B;
  if (mt >= meta[M_NTILES]) return;
  const int e  = meta[M_TILE_E + mt];
  const int r0 = meta[M_TILE_R0 + mt];
  const int n0 = nb * BN2_B;

  __shared__ ushort sA[2][BM_B * BK];
  __shared__ ushort sB1[2][BN2_B * BK];

  const int tid  = threadIdx.x;
  const int lane = tid & 63;
  const int w    = tid >> 6;
  const int wm   = w >> 1;
  const int wn   = w & 1;

  const char* a_gbase[4];
  int a_loff[4];
#pragma unroll
  for (int i = 0; i < 4; i++) {
    int seg = w * 4 + i;
    int row = seg * 8 + (lane >> 3);
    int colb = ((lane & 7) * 16) ^ swz(row);
    a_gbase[i] = (const char*)(hbuf + (size_t)(r0 + row) * IDIM) + colb;
    a_loff[i] = seg * 1024;
  }
  const int half = tid / 192;
  const int tt   = tid % 192;
  const int bn0  = half * 96 + (tt % 24) * 4;
  const int bk0  = (tt / 24) * 8;
  const bool bact = tid < 384;
  const float* bsrc = wd + ((size_t)e * IDIM + bk0) * DDIM + n0 + bn0;

  float4 vB[8];
  f32x4 acc[4][6];
#pragma unroll
  for (int i = 0; i < 4; i++)
#pragma unroll
    for (int j = 0; j < 6; j++) acc[i][j] = {0.f,0.f,0.f,0.f};

#pragma unroll
  for (int i = 0; i < 4; i++) gload_lds16(a_gbase[i], (char*)sA[0] + a_loff[i]);
  if (bact) {
#pragma unroll
    for (int j = 0; j < 8; j++) vB[j] = *(const float4*)(bsrc + (size_t)j * DDIM);
#pragma unroll
    for (int c = 0; c < 4; c++) {
      f16x8 p;
#pragma unroll
      for (int j = 0; j < 8; j++) {
        float fc = (c==0) ? vB[j].x : (c==1) ? vB[j].y : (c==2) ? vB[j].z : vB[j].w;
        p[j] = (f16)fc;
      }
      *(f16x8*)((char*)sB1[0] + (bn0 + c) * 128 + ((bk0 * 2) ^ swz(bn0 + c))) = p;
    }
  }
  __syncthreads();

  for (int kt = 0; kt < NKT; kt++) {
    const int cur = kt & 1;
    if (kt + 1 < NKT) {
#pragma unroll
      for (int i = 0; i < 4; i++)
        gload_lds16(a_gbase[i] + (kt + 1) * 128, (char*)sA[cur ^ 1] + a_loff[i]);
      if (bact) {
        const float* bs = bsrc + (size_t)(kt + 1) * BK * DDIM;
#pragma unroll
        for (int j = 0; j < 8; j++) vB[j] = *(const float4*)(bs + (size_t)j * DDIM);
      }
    }
#pragma unroll
    for (int kk = 0; kk < 2; kk++) {
      const int gb = kk * 64 + ((lane >> 4) * 16);
      f16x8 af[4], bf[6];
#pragma unroll
      for (int fm = 0; fm < 4; fm++) {
        int row = wm * 64 + fm * 16 + (lane & 15);
        af[fm] = *(const f16x8*)((const char*)sA[cur] + row * 128 + (gb ^ swz(row)));
      }
#pragma unroll
      for (int fn = 0; fn < 6; fn++) {
        int row = wn * 96 + fn * 16 + (lane & 15);
        bf[fn] = *(const f16x8*)((const char*)sB1[cur] + row * 128 + (gb ^ swz(row)));
      }
#pragma unroll
      for (int fm = 0; fm < 4; fm++)
#pragma unroll
        for (int fn = 0; fn < 6; fn++)
          acc[fm][fn] = __builtin_amdgcn_mfma_f32_16x16x32_f16(af[fm], bf[fn], acc[fm][fn], 0, 0, 0);
    }
    if (kt + 1 < NKT && bact) {
#pragma unroll
      for (int c = 0; c < 4; c++) {
        f16x8 p;
#pragma unroll
        for (int j = 0; j < 8; j++) {
          float fc = (c==0) ? vB[j].x : (c==1) ? vB[j].y : (c==2) ? vB[j].z : vB[j].w;
          p[j] = (f16)fc;
        }
        *(f16x8*)((char*)sB1[cur ^ 1] + (bn0 + c) * 128 + ((bk0 * 2) ^ swz(bn0 + c))) = p;
      }
    }
    __syncthreads();
  }

  const int rl4 = (lane >> 4) * 4;
  const int cl  = lane & 15;
#pragma unroll
  for (int fm = 0; fm < 4; fm++)
#pragma unroll
    for (int j = 0; j < 4; j++) {
      int row = wm * 64 + fm * 16 + rl4 + j;
      int slot = r0 + row;
      float wv = slot_w[slot];
#pragma unroll
      for (int fn = 0; fn < 6; fn++) {
        int col = n0 + wn * 96 + fn * 16 + cl;
        ybuf[(size_t)slot * DDIM + col] = (f16)(acc[fm][fn][j] * wv);
      }
    }
}

extern "C" void kernel_launch(void* const* d_in, const int* in_sizes, int n_in,
                              void* d_out, int out_size, void* d_ws, size_t ws_size,
                              hipStream_t stream) {
  const float* x  = (const float*)d_in[0];
  const float* wr = (const float*)d_in[1];
  const float* wg = (const float*)d_in[2];
  const float* wu = (const float*)d_in[3];
  const float* wd = (const float*)d_in[4];
  float* out = (float*)d_out;
  char* ws = (char*)d_ws;

  if (ws_size >= A_NEED) {
    // ---- path A: preconverted f16 weights, m97-template GEMMs ----
    f16* wgT = (f16*)(ws + A_WGT);
    f16* wuT = (f16*)(ws + A_WUT);
    f16* wdT = (f16*)(ws + A_WDT);   // aliases wgT (dead after kg1)
    f16* hbuf = (f16*)(ws + A_HBUF);
    f16* ybuf = (f16*)(ws + A_YBUF);
    f16* xh   = (f16*)(ws + A_XH);
    int* meta = (int*)(ws + A_META);
    float* slot_w = (float*)(ws + A_SLOTW);
    float* tok_w  = (float*)(ws + A_TOKW);

    hipMemsetAsync(meta + M_COUNT, 0, NEXP * sizeof(int), stream);
    k_cvt_w<<<dim3(2025, NEXP), 256, 0, stream>>>(wg, wgT);
    k_cvt_w<<<dim3(2025, NEXP), 256, 0, stream>>>(wu, wuT);
    k_router<<<T_TOK/4, 256, 0, stream>>>(x, wr, meta, tok_w);
    k_xcvt<<<(T_TOK*DDIM/8)/256, 256, 0, stream>>>(x, xh);
    k_scan<<<1, 64, 0, stream>>>(meta, slot_w, BM_A);
    k_scatter<<<(T_TOK + 255)/256, 256, 0, stream>>>(meta, slot_w, tok_w);
    kg1<<<NB1_A, 256, 0, stream>>>(xh, wgT, wuT, hbuf, meta);
    k_cvt_w<<<dim3(2025, NEXP), 256, 0, stream>>>(wd, wdT);
    kg2<<<NB2_A, 256, 0, stream>>>(hbuf, wdT, ybuf, meta, slot_w);
    k_combine<<<(T_TOK*DDIM/8)/256, 256, 0, stream>>>(ybuf, meta, out);
  } else if (ws_size >= B_NEED) {
    // ---- path B: fused-conversion fallback (v4) ----
    f16* hbuf = (f16*)(ws + B_HBUF);
    f16* xh   = (f16*)(ws + B_XH);
    f16* ybuf = (f16*)(ws + B_YBUF);
    int* meta = (int*)(ws + B_META);
    float* slot_w = (float*)(ws + B_SLOTW);
    float* tok_w  = (float*)(ws + B_TOKW);

    hipMemsetAsync(meta + M_COUNT, 0, NEXP * sizeof(int), stream);
    k_router<<<T_TOK/4, 256, 0, stream>>>(x, wr, meta, tok_w);
    k_xcvt<<<(T_TOK*DDIM/8)/256, 256, 0, stream>>>(x, xh);
    k_scan<<<1, 64, 0, stream>>>(meta, slot_w, BM_B);
    k_scatter<<<(T_TOK + 255)/256, 256, 0, stream>>>(meta, slot_w, tok_w);
    kg1_fb<<<NB1_B, 512, 0, stream>>>(xh, wg, wu, hbuf, meta);
    kg2_fb<<<NB2_B, 512, 0, stream>>>(hbuf, wd, ybuf, meta, slot_w);
    k_combine<<<(T_TOK*DDIM/8)/256, 256, 0, stream>>>(ybuf, meta, out);
  }
  // else: ws too small -> output stays poisoned (fail loudly)
}

// Round 8
// 580.875 us; speedup vs baseline: 1.3533x; 1.1900x over previous
//
#include <hip/hip_runtime.h>
#include <hip/hip_fp16.h>
#include <stdint.h>
#include <math.h>

// MoE MLP block: router top-2 + 8 experts SiLU-GLU, fp16 MFMA.
// v7b: v7 with the LDS pointer-array compile error fixed (compute smem+offset
// at use instead of arrays of addrspace-cast pointers).
// P1 = cvt_wg+cvt_wu+router+xcvt fused; P3 = kg1 + cvt_wd backfill; GEMMs
// double-buffered (80KB LDS, 1 barrier/k-step). 3-tier ws fallback.

typedef _Float16 f16;
typedef _Float16 f16x8 __attribute__((ext_vector_type(8)));
typedef float f32x4 __attribute__((ext_vector_type(4)));

#define T_TOK 2048
#define DDIM 2880
#define NEXP 8
#define IDIM 2880
#define BK 64
#define NKT 45

#define BM_A 128
#define BN1_A 96
#define BN2_A 192
#define MAXMT_A 40
#define NB1_A (30*MAXMT_A)   // 1200
#define NB2_A (15*MAXMT_A)   // 600
#define NCVT 16200           // 2025*8 blocks per weight tensor

#define BM_B 256
#define BN1_B 96
#define BN2_B 192
#define MAXMT_B 24
#define NB1_B (30*MAXMT_B)
#define NB2_B (15*MAXMT_B)

#define SLOT_CAP 6144

// meta int32 indices
#define M_COUNT 0
#define M_OFFS 16
#define M_NTILES 25
#define M_TILE_E 32
#define M_TILE_R0 96
#define M_SLOT_TOK 160
#define M_SLOT_OF (160+SLOT_CAP)
#define M_TOK_E (M_SLOT_OF + 2*T_TOK)
#define META_INTS (M_TOK_E + 2*T_TOK)

#define WT_B   ((size_t)NEXP*DDIM*IDIM*2)     // 132.7MB
#define HB_B   ((size_t)5120*IDIM*2)          // 29.5MB
#define XH_B   ((size_t)T_TOK*DDIM*2)         // 11.8MB
#define TAIL_B ((size_t)META_INTS*4 + (size_t)SLOT_CAP*4 + (size_t)T_TOK*2*4)

#define A3_NEED (3*WT_B + 2*HB_B + XH_B + TAIL_B)
#define A2_NEED (2*WT_B + 2*HB_B + XH_B + TAIL_B)
#define BF_NEED ((size_t)SLOT_CAP*IDIM*2 + (size_t)SLOT_CAP*DDIM*2 + TAIL_B)

__device__ __forceinline__ int swz(int row) { return ((row ^ (row >> 3)) & 7) << 4; }

__device__ __forceinline__ void gload_lds16(const void* gp, void* lp) {
  __builtin_amdgcn_global_load_lds(
      (const __attribute__((address_space(1))) uint32_t*)gp,
      (__attribute__((address_space(3))) uint32_t*)lp,
      16, 0, 0);
}

// ================= device bodies =================

__device__ __forceinline__ void cvt_body(const float* __restrict__ src, f16* __restrict__ dst,
                                          int blk, int tid, char* smem) {
  f16 (*t)[72] = (f16 (*)[72])smem;   // 64*72*2 = 9216B
  const int e = blk / 2025;
  const int tile = blk % 2025;
  const int k0 = (tile / 45) * 64;
  const int i0 = (tile % 45) * 64;
  const float* sp = src + ((size_t)e * DDIM + k0) * IDIM + i0;
#pragma unroll
  for (int p = 0; p < 4; p++) {
    int kr = p * 16 + (tid >> 4);
    int c0 = (tid & 15) * 4;
    float4 v = *(const float4*)(sp + (size_t)kr * IDIM + c0);
    t[c0 + 0][kr] = (f16)v.x;
    t[c0 + 1][kr] = (f16)v.y;
    t[c0 + 2][kr] = (f16)v.z;
    t[c0 + 3][kr] = (f16)v.w;
  }
  __syncthreads();
#pragma unroll
  for (int p = 0; p < 2; p++) {
    int row = tid >> 2;
    int ch = (tid & 3) + p * 4;
    f16x8 o = *(const f16x8*)&t[row][ch * 8];
    *(f16x8*)(dst + ((size_t)e * IDIM + i0 + row) * DDIM + k0 + ch * 8) = o;
  }
}

__device__ __forceinline__ void router_body(const float* __restrict__ x, const float* __restrict__ wr,
                                            int* __restrict__ meta, float* __restrict__ tok_w,
                                            int blk, int tid) {
  const int lane = tid & 63;
  const int t = blk * 4 + (tid >> 6);
  double acc[NEXP];
#pragma unroll
  for (int e = 0; e < NEXP; e++) acc[e] = 0.0;
  for (int d = lane; d < DDIM; d += 64) {
    float xv = x[(size_t)t * DDIM + d];
    float4 w0 = *(const float4*)(wr + (size_t)d * NEXP);
    float4 w1 = *(const float4*)(wr + (size_t)d * NEXP + 4);
    acc[0] += (double)xv * (double)w0.x;
    acc[1] += (double)xv * (double)w0.y;
    acc[2] += (double)xv * (double)w0.z;
    acc[3] += (double)xv * (double)w0.w;
    acc[4] += (double)xv * (double)w1.x;
    acc[5] += (double)xv * (double)w1.y;
    acc[6] += (double)xv * (double)w1.z;
    acc[7] += (double)xv * (double)w1.w;
  }
#pragma unroll
  for (int m = 32; m >= 1; m >>= 1) {
#pragma unroll
    for (int e = 0; e < NEXP; e++) acc[e] += __shfl_xor(acc[e], m, 64);
  }
  if (lane == 0) {
    int e0 = 0;
#pragma unroll
    for (int e = 1; e < NEXP; e++) if (acc[e] > acc[e0]) e0 = e;
    int e1 = (e0 == 0) ? 1 : 0;
#pragma unroll
    for (int e = 0; e < NEXP; e++) if (e != e0 && acc[e] > acc[e1]) e1 = e;
    double w0 = 1.0 / (1.0 + exp(acc[e1] - acc[e0]));
    meta[M_TOK_E + 2*t]     = e0;
    meta[M_TOK_E + 2*t + 1] = e1;
    tok_w[2*t]     = (float)w0;
    tok_w[2*t + 1] = (float)(1.0 - w0);
    atomicAdd(&meta[M_COUNT + e0], 1);
    atomicAdd(&meta[M_COUNT + e1], 1);
  }
}

__device__ __forceinline__ void xcvt_body(const float* __restrict__ x, f16* __restrict__ xh,
                                          int blk, int tid) {
  size_t i = ((size_t)blk * 256 + tid) * 8;
  float4 a = *(const float4*)(x + i);
  float4 b = *(const float4*)(x + i + 4);
  f16x8 v;
  v[0]=(f16)a.x; v[1]=(f16)a.y; v[2]=(f16)a.z; v[3]=(f16)a.w;
  v[4]=(f16)b.x; v[5]=(f16)b.y; v[6]=(f16)b.z; v[7]=(f16)b.w;
  *(f16x8*)(xh + i) = v;
}

// ================= P1: cvt_wg + cvt_wu + router + xcvt =================
__global__ __launch_bounds__(256) void k_p1(
    const float* __restrict__ x, const float* __restrict__ wr,
    const float* __restrict__ wg, const float* __restrict__ wu,
    f16* __restrict__ wgT, f16* __restrict__ wuT, f16* __restrict__ xh,
    int* __restrict__ meta, float* __restrict__ tok_w) {
  __shared__ char smem[9216];
  int b = blockIdx.x;
  const int tid = threadIdx.x;
  if (b < NCVT) { cvt_body(wg, wgT, b, tid, smem); return; }
  b -= NCVT;
  if (b < NCVT) { cvt_body(wu, wuT, b, tid, smem); return; }
  b -= NCVT;
  if (b < T_TOK/4) { router_body(x, wr, meta, tok_w, b, tid); return; }
  b -= T_TOK/4;
  xcvt_body(x, xh, b, tid);
}

__global__ __launch_bounds__(256) void k_router(const float* x, const float* wr, int* meta, float* tok_w) {
  router_body(x, wr, meta, tok_w, blockIdx.x, threadIdx.x);
}
__global__ __launch_bounds__(256) void k_xcvt(const float* x, f16* xh) {
  xcvt_body(x, xh, blockIdx.x, threadIdx.x);
}
__global__ __launch_bounds__(256) void k_cvt_w(const float* src, f16* dst) {
  __shared__ char smem[9216];
  cvt_body(src, dst, blockIdx.x, threadIdx.x, smem);
}

// ================= scan + scatter (one block) =================
__global__ __launch_bounds__(256) void k_scan_scatter(
    int* __restrict__ meta, float* __restrict__ slot_w, const float* __restrict__ tok_w, int bm) {
  __shared__ int s_off[NEXP], s_cnt[NEXP], s_pc[NEXP], s_cur[NEXP];
  const int tid = threadIdx.x;
  if (tid == 0) {
    int run = 0, nt = 0;
    for (int e = 0; e < NEXP; e++) {
      int c = meta[M_COUNT + e];
      int mt = (c + bm - 1) / bm;
      meta[M_OFFS + e] = run;
      s_off[e] = run; s_cnt[e] = c; s_pc[e] = mt * bm; s_cur[e] = 0;
      for (int j = 0; j < mt; j++) { meta[M_TILE_E + nt] = e; meta[M_TILE_R0 + nt] = run + j * bm; nt++; }
      run += mt * bm;
    }
    meta[M_OFFS + NEXP] = run;
    meta[M_NTILES] = nt;
  }
  __syncthreads();
  for (int e = 0; e < NEXP; e++) {
    for (int i = s_cnt[e] + tid; i < s_pc[e]; i += 256) {
      meta[M_SLOT_TOK + s_off[e] + i] = 0;
      slot_w[s_off[e] + i] = 0.0f;
    }
  }
  for (int t = tid; t < T_TOK; t += 256) {
#pragma unroll
    for (int k = 0; k < 2; k++) {
      int e = meta[M_TOK_E + 2*t + k];
      int pos = atomicAdd(&s_cur[e], 1);
      int slot = s_off[e] + pos;
      meta[M_SLOT_TOK + slot] = t;
      slot_w[slot] = tok_w[2*t + k];
      meta[M_SLOT_OF + 2*t + k] = slot;
    }
  }
}

// ================= kg1 (dbuf) + optional cvt_wd backfill =================
// LDS layout (bytes): sA buf0 @0, buf1 @16384; sBg buf0 @32768, buf1 @45056;
//                     sBu buf0 @57344, buf1 @69632. Total 81920.
__device__ __forceinline__ void kg1_body(
    const f16* __restrict__ xh, const f16* __restrict__ wgT, const f16* __restrict__ wuT,
    f16* __restrict__ hbuf, const int* __restrict__ meta, int id, int tid, char* smem) {
  const int sid = (id & 7) * (NB1_A / 8) + (id >> 3);
  const int mt = sid % MAXMT_A;
  const int nb = sid / MAXMT_A;
  if (mt >= meta[M_NTILES]) return;
  const int e  = meta[M_TILE_E + mt];
  const int r0 = meta[M_TILE_R0 + mt];
  const int n0 = nb * BN1_A;

  const int lane = tid & 63;
  const int w = tid >> 6;
  const int wm = w >> 1, wn = w & 1;

  const char* aG[4]; int aL[4];
#pragma unroll
  for (int i = 0; i < 4; i++) {
    int seg = w * 4 + i;
    int row = seg * 8 + (lane >> 3);
    int colb = ((lane & 7) * 16) ^ swz(row);
    int tok = meta[M_SLOT_TOK + r0 + row];
    aG[i] = (const char*)(xh + (size_t)tok * DDIM) + colb;
    aL[i] = seg * 1024;
  }
  const char* gG[3]; const char* uG[3]; int bL[3];
#pragma unroll
  for (int i = 0; i < 3; i++) {
    int seg = w * 3 + i;
    int row = seg * 8 + (lane >> 3);
    int colb = ((lane & 7) * 16) ^ swz(row);
    gG[i] = (const char*)(wgT + ((size_t)e * IDIM + n0 + row) * DDIM) + colb;
    uG[i] = (const char*)(wuT + ((size_t)e * IDIM + n0 + row) * DDIM) + colb;
    bL[i] = seg * 1024;
  }

  f32x4 accG[4][3], accU[4][3];
#pragma unroll
  for (int i = 0; i < 4; i++)
#pragma unroll
    for (int j = 0; j < 3; j++) { accG[i][j] = {0.f,0.f,0.f,0.f}; accU[i][j] = {0.f,0.f,0.f,0.f}; }

  // prologue: tile 0 into buf0
#pragma unroll
  for (int i = 0; i < 4; i++) gload_lds16(aG[i], smem + aL[i]);
#pragma unroll
  for (int i = 0; i < 3; i++) gload_lds16(gG[i], smem + 32768 + bL[i]);
#pragma unroll
  for (int i = 0; i < 3; i++) gload_lds16(uG[i], smem + 57344 + bL[i]);
  __syncthreads();

  for (int kt = 0; kt < NKT; kt++) {
    const int cur = kt & 1;
    char* curA  = smem + cur * 16384;
    char* curBg = smem + 32768 + cur * 12288;
    char* curBu = smem + 57344 + cur * 12288;
    if (kt + 1 < NKT) {   // prefetch kt+1 into other buffer; flies during MFMA
      const int nx = cur ^ 1;
      char* nxA  = smem + nx * 16384;
      char* nxBg = smem + 32768 + nx * 12288;
      char* nxBu = smem + 57344 + nx * 12288;
#pragma unroll
      for (int i = 0; i < 4; i++) gload_lds16(aG[i] + (kt+1) * 128, nxA + aL[i]);
#pragma unroll
      for (int i = 0; i < 3; i++) gload_lds16(gG[i] + (kt+1) * 128, nxBg + bL[i]);
#pragma unroll
      for (int i = 0; i < 3; i++) gload_lds16(uG[i] + (kt+1) * 128, nxBu + bL[i]);
    }
#pragma unroll
    for (int kk = 0; kk < 2; kk++) {
      const int gb = kk * 64 + ((lane >> 4) * 16);
      f16x8 af[4], bg[3], bu[3];
#pragma unroll
      for (int fm = 0; fm < 4; fm++) {
        int row = wm * 64 + fm * 16 + (lane & 15);
        af[fm] = *(const f16x8*)(curA + row * 128 + (gb ^ swz(row)));
      }
#pragma unroll
      for (int fn = 0; fn < 3; fn++) {
        int row = wn * 48 + fn * 16 + (lane & 15);
        bg[fn] = *(const f16x8*)(curBg + row * 128 + (gb ^ swz(row)));
        bu[fn] = *(const f16x8*)(curBu + row * 128 + (gb ^ swz(row)));
      }
#pragma unroll
      for (int fm = 0; fm < 4; fm++)
#pragma unroll
        for (int fn = 0; fn < 3; fn++) {
          accG[fm][fn] = __builtin_amdgcn_mfma_f32_16x16x32_f16(af[fm], bg[fn], accG[fm][fn], 0, 0, 0);
          accU[fm][fn] = __builtin_amdgcn_mfma_f32_16x16x32_f16(af[fm], bu[fn], accU[fm][fn], 0, 0, 0);
        }
    }
    __syncthreads();   // vmcnt(0) drain lands after ~470cy of MFMA
  }

  const int rl4 = (lane >> 4) * 4;
  const int cl  = lane & 15;
#pragma unroll
  for (int fm = 0; fm < 4; fm++)
#pragma unroll
    for (int fn = 0; fn < 3; fn++)
#pragma unroll
      for (int j = 0; j < 4; j++) {
        int row = wm * 64 + fm * 16 + rl4 + j;
        int col = n0 + wn * 48 + fn * 16 + cl;
        float g = accG[fm][fn][j], u = accU[fm][fn][j];
        float h = g * u / (1.0f + __expf(-g));
        hbuf[(size_t)(r0 + row) * IDIM + col] = (f16)h;
      }
}

__global__ __launch_bounds__(256, 2) void k_g1cvt(
    const f16* __restrict__ xh, const f16* __restrict__ wgT, const f16* __restrict__ wuT,
    f16* __restrict__ hbuf, const int* __restrict__ meta,
    const float* __restrict__ wd, f16* __restrict__ wdT) {
  __shared__ char smem[81920];
  const int id = blockIdx.x;
  if (id < NB1_A) kg1_body(xh, wgT, wuT, hbuf, meta, id, threadIdx.x, smem);
  else            cvt_body(wd, wdT, id - NB1_A, threadIdx.x, smem);
}

// ================= kg2 (dbuf) =================
// LDS: sA buf0 @0, buf1 @16384; sB buf0 @32768, buf1 @57344. Total 81920.
__global__ __launch_bounds__(256, 2) void kg2(
    const f16* __restrict__ hbuf, const f16* __restrict__ wdT,
    f16* __restrict__ ybuf, const int* __restrict__ meta, const float* __restrict__ slot_w) {
  __shared__ char smem[81920];
  const int id = blockIdx.x;
  const int sid = (id & 7) * (NB2_A / 8) + (id >> 3);
  const int mt = sid % MAXMT_A;
  const int nb = sid / MAXMT_A;
  if (mt >= meta[M_NTILES]) return;
  const int e  = meta[M_TILE_E + mt];
  const int r0 = meta[M_TILE_R0 + mt];
  const int n0 = nb * BN2_A;

  const int tid = threadIdx.x;
  const int lane = tid & 63;
  const int w = tid >> 6;
  const int wm = w >> 1, wn = w & 1;

  const char* aG[4]; int aL[4];
#pragma unroll
  for (int i = 0; i < 4; i++) {
    int seg = w * 4 + i;
    int row = seg * 8 + (lane >> 3);
    int colb = ((lane & 7) * 16) ^ swz(row);
    aG[i] = (const char*)(hbuf + (size_t)(r0 + row) * IDIM) + colb;
    aL[i] = seg * 1024;
  }
  const char* bG[6]; int bL[6];
#pragma unroll
  for (int i = 0; i < 6; i++) {
    int seg = w * 6 + i;
    int row = seg * 8 + (lane >> 3);
    int colb = ((lane & 7) * 16) ^ swz(row);
    bG[i] = (const char*)(wdT + ((size_t)e * DDIM + n0 + row) * IDIM) + colb;
    bL[i] = seg * 1024;
  }

  f32x4 acc[4][6];
#pragma unroll
  for (int i = 0; i < 4; i++)
#pragma unroll
    for (int j = 0; j < 6; j++) acc[i][j] = {0.f,0.f,0.f,0.f};

#pragma unroll
  for (int i = 0; i < 4; i++) gload_lds16(aG[i], smem + aL[i]);
#pragma unroll
  for (int i = 0; i < 6; i++) gload_lds16(bG[i], smem + 32768 + bL[i]);
  __syncthreads();

  for (int kt = 0; kt < NKT; kt++) {
    const int cur = kt & 1;
    char* curA = smem + cur * 16384;
    char* curB = smem + 32768 + cur * 24576;
    if (kt + 1 < NKT) {
      const int nx = cur ^ 1;
      char* nxA = smem + nx * 16384;
      char* nxB = smem + 32768 + nx * 24576;
#pragma unroll
      for (int i = 0; i < 4; i++) gload_lds16(aG[i] + (kt+1) * 128, nxA + aL[i]);
#pragma unroll
      for (int i = 0; i < 6; i++) gload_lds16(bG[i] + (kt+1) * 128, nxB + bL[i]);
    }
#pragma unroll
    for (int kk = 0; kk < 2; kk++) {
      const int gb = kk * 64 + ((lane >> 4) * 16);
      f16x8 af[4], bf[6];
#pragma unroll
      for (int fm = 0; fm < 4; fm++) {
        int row = wm * 64 + fm * 16 + (lane & 15);
        af[fm] = *(const f16x8*)(curA + row * 128 + (gb ^ swz(row)));
      }
#pragma unroll
      for (int fn = 0; fn < 6; fn++) {
        int row = wn * 96 + fn * 16 + (lane & 15);
        bf[fn] = *(const f16x8*)(curB + row * 128 + (gb ^ swz(row)));
      }
#pragma unroll
      for (int fm = 0; fm < 4; fm++)
#pragma unroll
        for (int fn = 0; fn < 6; fn++)
          acc[fm][fn] = __builtin_amdgcn_mfma_f32_16x16x32_f16(af[fm], bf[fn], acc[fm][fn], 0, 0, 0);
    }
    __syncthreads();
  }
  const int rl4 = (lane >> 4) * 4;
  const int cl  = lane & 15;
#pragma unroll
  for (int fm = 0; fm < 4; fm++)
#pragma unroll
    for (int j = 0; j < 4; j++) {
      int row = wm * 64 + fm * 16 + rl4 + j;
      int slot = r0 + row;
      float wv = slot_w[slot];
#pragma unroll
      for (int fn = 0; fn < 6; fn++) {
        int col = n0 + wn * 96 + fn * 16 + cl;
        ybuf[(size_t)slot * DDIM + col] = (f16)(acc[fm][fn][j] * wv);
      }
    }
}

// ---------------- combine ----------------
__global__ __launch_bounds__(256) void k_combine(const f16* __restrict__ ybuf,
    const int* __restrict__ meta, float* __restrict__ out) {
  size_t idx = (size_t)blockIdx.x * 256 + threadIdx.x;
  int t = (int)(idx / (DDIM/8));
  int c = (int)(idx % (DDIM/8));
  int s0 = meta[M_SLOT_OF + 2*t];
  int s1 = meta[M_SLOT_OF + 2*t + 1];
  f16x8 a = *(const f16x8*)(ybuf + (size_t)s0 * DDIM + c*8);
  f16x8 b = *(const f16x8*)(ybuf + (size_t)s1 * DDIM + c*8);
  float4 o0, o1;
  o0.x = (float)a[0] + (float)b[0];
  o0.y = (float)a[1] + (float)b[1];
  o0.z = (float)a[2] + (float)b[2];
  o0.w = (float)a[3] + (float)b[3];
  o1.x = (float)a[4] + (float)b[4];
  o1.y = (float)a[5] + (float)b[5];
  o1.z = (float)a[6] + (float)b[6];
  o1.w = (float)a[7] + (float)b[7];
  float* op = out + (size_t)t * DDIM + c*8;
  *(float4*)op = o0;
  *(float4*)(op + 4) = o1;
}

// ================= PATH B: fallback fused GEMMs (v4, verified) =================

__global__ __launch_bounds__(512, 2) void kg1_fb(
    const f16* __restrict__ xh, const float* __restrict__ wg, const float* __restrict__ wu,
    f16* __restrict__ hbuf, const int* __restrict__ meta) {
  const int id = blockIdx.x;
  const int sid = (id & 7) * (NB1_B / 8) + (id >> 3);
  const int mt = sid % MAXMT_B;
  const int nb = sid / MAXMT_B;
  if (mt >= meta[M_NTILES]) return;
  const int e  = meta[M_TILE_E + mt];
  const int r0 = meta[M_TILE_R0 + mt];
  const int n0 = nb * BN1_B;

  __shared__ ushort sA[2][BM_B * BK];
  __shared__ ushort sB[2][2][BN1_B * BK];

  const int tid  = threadIdx.x;
  const int lane = tid & 63;
  const int w    = tid >> 6;
  const int wm   = w >> 1;
  const int gu   = w & 1;

  const char* a_gbase[4];
  int a_loff[4];
#pragma unroll
  for (int i = 0; i < 4; i++) {
    int seg = w * 4 + i;
    int row = seg * 8 + (lane >> 3);
    int colb = ((lane & 7) * 16) ^ swz(row);
    int tok = meta[M_SLOT_TOK + r0 + row];
    a_gbase[i] = (const char*)(xh + (size_t)tok * DDIM) + colb;
    a_loff[i] = seg * 1024;
  }
  const int bm_ = tid / 192;
  const int tt  = tid % 192;
  const int bn0 = (tt % 24) * 4;
  const int bk0 = (tt / 24) * 8;
  const bool bact = tid < 384;
  const float* bsrc = (bm_ ? wu : wg) + ((size_t)e * DDIM + bk0) * IDIM + n0 + bn0;

  float4 vB[8];
  f32x4 acc[4][6];
#pragma unroll
  for (int i = 0; i < 4; i++)
#pragma unroll
    for (int j = 0; j < 6; j++) acc[i][j] = {0.f,0.f,0.f,0.f};

#pragma unroll
  for (int i = 0; i < 4; i++) gload_lds16(a_gbase[i], (char*)sA[0] + a_loff[i]);
  if (bact) {
#pragma unroll
    for (int j = 0; j < 8; j++) vB[j] = *(const float4*)(bsrc + (size_t)j * IDIM);
#pragma unroll
    for (int c = 0; c < 4; c++) {
      f16x8 p;
#pragma unroll
      for (int j = 0; j < 8; j++) {
        float fc = (c==0) ? vB[j].x : (c==1) ? vB[j].y : (c==2) ? vB[j].z : vB[j].w;
        p[j] = (f16)fc;
      }
      *(f16x8*)((char*)sB[0][bm_] + (bn0 + c) * 128 + ((bk0 * 2) ^ swz(bn0 + c))) = p;
    }
  }
  __syncthreads();

  for (int kt = 0; kt < NKT; kt++) {
    const int cur = kt & 1;
    if (kt + 1 < NKT) {
#pragma unroll
      for (int i = 0; i < 4; i++)
        gload_lds16(a_gbase[i] + (kt + 1) * 128, (char*)sA[cur ^ 1] + a_loff[i]);
      if (bact) {
        const float* bs = bsrc + (size_t)(kt + 1) * BK * IDIM;
#pragma unroll
        for (int j = 0; j < 8; j++) vB[j] = *(const float4*)(bs + (size_t)j * IDIM);
      }
    }
#pragma unroll
    for (int kk = 0; kk < 2; kk++) {
      const int gb = kk * 64 + ((lane >> 4) * 16);
      f16x8 af[4], bf[6];
#pragma unroll
      for (int fm = 0; fm < 4; fm++) {
        int row = wm * 64 + fm * 16 + (lane & 15);
        af[fm] = *(const f16x8*)((const char*)sA[cur] + row * 128 + (gb ^ swz(row)));
      }
#pragma unroll
      for (int fn = 0; fn < 6; fn++) {
        int row = fn * 16 + (lane & 15);
        bf[fn] = *(const f16x8*)((const char*)sB[cur][gu] + row * 128 + (gb ^ swz(row)));
      }
#pragma unroll
      for (int fm = 0; fm < 4; fm++)
#pragma unroll
        for (int fn = 0; fn < 6; fn++)
          acc[fm][fn] = __builtin_amdgcn_mfma_f32_16x16x32_f16(af[fm], bf[fn], acc[fm][fn], 0, 0, 0);
    }
    if (kt + 1 < NKT && bact) {
#pragma unroll
      for (int c = 0; c < 4; c++) {
        f16x8 p;
#pragma unroll
        for (int j = 0; j < 8; j++) {
          float fc = (c==0) ? vB[j].x : (c==1) ? vB[j].y : (c==2) ? vB[j].z : vB[j].w;
          p[j] = (f16)fc;
        }
        *(f16x8*)((char*)sB[cur ^ 1][bm_] + (bn0 + c) * 128 + ((bk0 * 2) ^ swz(bn0 + c))) = p;
      }
    }
    __syncthreads();
  }

  float* u_lds = (float*)&sA[0][0];
  const int rl4 = (lane >> 4) * 4;
  const int cl  = lane & 15;
#pragma unroll
  for (int r = 0; r < 2; r++) {
    __syncthreads();
    if (gu == 1) {
#pragma unroll
      for (int fi = 0; fi < 2; fi++)
#pragma unroll
        for (int fn = 0; fn < 6; fn++)
#pragma unroll
          for (int j = 0; j < 4; j++)
            u_lds[wm * 3200 + (fi * 16 + rl4 + j) * 100 + fn * 16 + cl] = acc[2*r + fi][fn][j];
    }
    __syncthreads();
    if (gu == 0) {
#pragma unroll
      for (int fi = 0; fi < 2; fi++) {
        int fm = 2*r + fi;
#pragma unroll
        for (int fn = 0; fn < 6; fn++)
#pragma unroll
          for (int j = 0; j < 4; j++) {
            float u = u_lds[wm * 3200 + (fi * 16 + rl4 + j) * 100 + fn * 16 + cl];
            float g = acc[fm][fn][j];
            float h = g * u / (1.0f + __expf(-g));
            hbuf[(size_t)(r0 + wm * 64 + fm * 16 + rl4 + j) * IDIM + n0 + fn * 16 + cl] = (f16)h;
          }
      }
    }
  }
}

__global__ __launch_bounds__(512, 2) void kg2_fb(
    const f16* __restrict__ hbuf, const float* __restrict__ wd,
    f16* __restrict__ ybuf, const int* __restrict__ meta, const float* __restrict__ slot_w) {
  const int id = blockIdx.x;
  const int sid = (id & 7) * (NB2_B / 8) + (id >> 3);
  const int mt = sid % MAXMT_B;
  const int nb = sid / MAXMT_B;
  if (mt >= meta[M_NTILES]) return;
  const int e  = meta[M_TILE_E + mt];
  const int r0 = meta[M_TILE_R0 + mt];
  const int n0 = nb * BN2_B;

  __shared__ ushort sA[2][BM_B * BK];
  __shared__ ushort sB1[2][BN2_B * BK];

  const int tid  = threadIdx.x;
  const int lane = tid & 63;
  const int w    = tid >> 6;
  const int wm   = w >> 1;
  const int wn   = w & 1;

  const char* a_gbase[4];
  int a_loff[4];
#pragma unroll
  for (int i = 0; i < 4; i++) {
    int seg = w * 4 + i;
    int row = seg * 8 + (lane >> 3);
    int colb = ((lane & 7) * 16) ^ swz(row);
    a_gbase[i] = (const char*)(hbuf + (size_t)(r0 + row) * IDIM) + colb;
    a_loff[i] = seg * 1024;
  }
  const int half = tid / 192;
  const int tt   = tid % 192;
  const int bn0  = half * 96 + (tt % 24) * 4;
  const int bk0  = (tt / 24) * 8;
  const bool bact = tid < 384;
  const float* bsrc = wd + ((size_t)e * IDIM + bk0) * DDIM + n0 + bn0;

  float4 vB[8];
  f32x4 acc[4][6];
#pragma unroll
  for (int i = 0; i < 4; i++)
#pragma unroll
    for (int j = 0; j < 6; j++) acc[i][j] = {0.f,0.f,0.f,0.f};

#pragma unroll
  for (int i = 0; i < 4; i++) gload_lds16(a_gbase[i], (char*)sA[0] + a_loff[i]);
  if (bact) {
#pragma unroll
    for (int j = 0; j < 8; j++) vB[j] = *(const float4*)(bsrc + (size_t)j * DDIM);
#pragma unroll
    for (int c = 0; c < 4; c++) {
      f16x8 p;
#pragma unroll
      for (int j = 0; j < 8; j++) {
        float fc = (c==0) ? vB[j].x : (c==1) ? vB[j].y : (c==2) ? vB[j].z : vB[j].w;
        p[j] = (f16)fc;
      }
      *(f16x8*)((char*)sB1[0] + (bn0 + c) * 128 + ((bk0 * 2) ^ swz(bn0 + c))) = p;
    }
  }
  __syncthreads();

  for (int kt = 0; kt < NKT; kt++) {
    const int cur = kt & 1;
    if (kt + 1 < NKT) {
#pragma unroll
      for (int i = 0; i < 4; i++)
        gload_lds16(a_gbase[i] + (kt + 1) * 128, (char*)sA[cur ^ 1] + a_loff[i]);
      if (bact) {
        const float* bs = bsrc + (size_t)(kt + 1) * BK * DDIM;
#pragma unroll
        for (int j = 0; j < 8; j++) vB[j] = *(const float4*)(bs + (size_t)j * DDIM);
      }
    }
#pragma unroll
    for (int kk = 0; kk < 2; kk++) {
      const int gb = kk * 64 + ((lane >> 4) * 16);
      f16x8 af[4], bf[6];
#pragma unroll
      for (int fm = 0; fm < 4; fm++) {
        int row = wm * 64 + fm * 16 + (lane & 15);
        af[fm] = *(const f16x8*)((const char*)sA[cur] + row * 128 + (gb ^ swz(row)));
      }
#pragma unroll
      for (int fn = 0; fn < 6; fn++) {
        int row = wn * 96 + fn * 16 + (lane & 15);
        bf[fn] = *(const f16x8*)((const char*)sB1[cur] + row * 128 + (gb ^ swz(row)));
      }
#pragma unroll
      for (int fm = 0; fm < 4; fm++)
#pragma unroll
        for (int fn = 0; fn < 6; fn++)
          acc[fm][fn] = __builtin_amdgcn_mfma_f32_16x16x32_f16(af[fm], bf[fn], acc[fm][fn], 0, 0, 0);
    }
    if (kt + 1 < NKT && bact) {
#pragma unroll
      for (int c = 0; c < 4; c++) {
        f16x8 p;
#pragma unroll
        for (int j = 0; j < 8; j++) {
          float fc = (c==0) ? vB[j].x : (c==1) ? vB[j].y : (c==2) ? vB[j].z : vB[j].w;
          p[j] = (f16)fc;
        }
        *(f16x8*)((char*)sB1[cur ^ 1] + (bn0 + c) * 128 + ((bk0 * 2) ^ swz(bn0 + c))) = p;
      }
    }
    __syncthreads();
  }

  const int rl4 = (lane >> 4) * 4;
  const int cl  = lane & 15;
#pragma unroll
  for (int fm = 0; fm < 4; fm++)
#pragma unroll
    for (int j = 0; j < 4; j++) {
      int row = wm * 64 + fm * 16 + rl4 + j;
      int slot = r0 + row;
      float wv = slot_w[slot];
#pragma unroll
      for (int fn = 0; fn < 6; fn++) {
        int col = n0 + wn * 96 + fn * 16 + cl;
        ybuf[(size_t)slot * DDIM + col] = (f16)(acc[fm][fn][j] * wv);
      }
    }
}

extern "C" void kernel_launch(void* const* d_in, const int* in_sizes, int n_in,
                              void* d_out, int out_size, void* d_ws, size_t ws_size,
                              hipStream_t stream) {
  const float* x  = (const float*)d_in[0];
  const float* wr = (const float*)d_in[1];
  const float* wg = (const float*)d_in[2];
  const float* wu = (const float*)d_in[3];
  const float* wd = (const float*)d_in[4];
  float* out = (float*)d_out;
  char* ws = (char*)d_ws;

  if (ws_size >= A2_NEED) {
    const bool three = (ws_size >= A3_NEED);
    f16* wgT = (f16*)(ws);
    f16* wuT = (f16*)(ws + WT_B);
    f16* wdT = three ? (f16*)(ws + 2*WT_B) : wgT;   // alias only if sequential
    char* base = ws + (three ? 3*WT_B : 2*WT_B);
    f16* hbuf = (f16*)(base);
    f16* ybuf = (f16*)(base + HB_B);
    f16* xh   = (f16*)(base + 2*HB_B);
    int* meta = (int*)(base + 2*HB_B + XH_B);
    float* slot_w = (float*)((char*)meta + META_INTS*4);
    float* tok_w  = (float*)((char*)slot_w + SLOT_CAP*4);

    (void)hipMemsetAsync(meta + M_COUNT, 0, NEXP * sizeof(int), stream);
    k_p1<<<2*NCVT + T_TOK/4 + 2880, 256, 0, stream>>>(x, wr, wg, wu, wgT, wuT, xh, meta, tok_w);
    k_scan_scatter<<<1, 256, 0, stream>>>(meta, slot_w, tok_w, BM_A);
    if (three) {
      k_g1cvt<<<NB1_A + NCVT, 256, 0, stream>>>(xh, wgT, wuT, hbuf, meta, wd, wdT);
    } else {
      k_g1cvt<<<NB1_A, 256, 0, stream>>>(xh, wgT, wuT, hbuf, meta, wd, wdT);
      k_cvt_w<<<NCVT, 256, 0, stream>>>(wd, wdT);
    }
    kg2<<<NB2_A, 256, 0, stream>>>(hbuf, wdT, ybuf, meta, slot_w);
    k_combine<<<(T_TOK*DDIM/8)/256, 256, 0, stream>>>(ybuf, meta, out);
  } else if (ws_size >= BF_NEED) {
    f16* hbuf = (f16*)(ws);
    f16* xh   = (f16*)(ws + (size_t)SLOT_CAP*IDIM*2);
    f16* ybuf = xh;
    int* meta = (int*)(ws + (size_t)SLOT_CAP*IDIM*2 + (size_t)SLOT_CAP*DDIM*2);
    float* slot_w = (float*)((char*)meta + META_INTS*4);
    float* tok_w  = (float*)((char*)slot_w + SLOT_CAP*4);

    (void)hipMemsetAsync(meta + M_COUNT, 0, NEXP * sizeof(int), stream);
    k_router<<<T_TOK/4, 256, 0, stream>>>(x, wr, meta, tok_w);
    k_xcvt<<<(T_TOK*DDIM/8)/256, 256, 0, stream>>>(x, xh);
    k_scan_scatter<<<1, 256, 0, stream>>>(meta, slot_w, tok_w, BM_B);
    kg1_fb<<<NB1_B, 512, 0, stream>>>(xh, wg, wu, hbuf, meta);
    kg2_fb<<<NB2_B, 512, 0, stream>>>(hbuf, wd, ybuf, meta, slot_w);
    k_combine<<<(T_TOK*DDIM/8)/256, 256, 0, stream>>>(ybuf, meta, out);
  }
}

// Round 9
// 573.065 us; speedup vs baseline: 1.3717x; 1.0136x over previous
//
#include <hip/hip_runtime.h>
#include <hip/hip_fp16.h>
#include <stdint.h>
#include <math.h>

// MoE MLP block: router top-2 + 8 experts SiLU-GLU, fp16 MFMA.
// v8: v7b with LDS-clean weight transpose-convert: register 4x4 transpose,
// ds_write_b64, GEMM-style XOR swizzle on LDS rows, 128B-coalesced output.
// P1 = cvt_wg+cvt_wu+router+xcvt fused; P3 = kg1 + cvt_wd backfill; GEMMs
// double-buffered (80KB LDS, 1 barrier/k-step). 3-tier ws fallback.

typedef _Float16 f16;
typedef _Float16 f16x4 __attribute__((ext_vector_type(4)));
typedef _Float16 f16x8 __attribute__((ext_vector_type(8)));
typedef float f32x4 __attribute__((ext_vector_type(4)));

#define T_TOK 2048
#define DDIM 2880
#define NEXP 8
#define IDIM 2880
#define BK 64
#define NKT 45

#define BM_A 128
#define BN1_A 96
#define BN2_A 192
#define MAXMT_A 40
#define NB1_A (30*MAXMT_A)   // 1200
#define NB2_A (15*MAXMT_A)   // 600
#define NCVT 16200           // 2025*8 blocks per weight tensor

#define BM_B 256
#define BN1_B 96
#define BN2_B 192
#define MAXMT_B 24
#define NB1_B (30*MAXMT_B)
#define NB2_B (15*MAXMT_B)

#define SLOT_CAP 6144

// meta int32 indices
#define M_COUNT 0
#define M_OFFS 16
#define M_NTILES 25
#define M_TILE_E 32
#define M_TILE_R0 96
#define M_SLOT_TOK 160
#define M_SLOT_OF (160+SLOT_CAP)
#define M_TOK_E (M_SLOT_OF + 2*T_TOK)
#define META_INTS (M_TOK_E + 2*T_TOK)

#define WT_B   ((size_t)NEXP*DDIM*IDIM*2)     // 132.7MB
#define HB_B   ((size_t)5120*IDIM*2)          // 29.5MB
#define XH_B   ((size_t)T_TOK*DDIM*2)         // 11.8MB
#define TAIL_B ((size_t)META_INTS*4 + (size_t)SLOT_CAP*4 + (size_t)T_TOK*2*4)

#define A3_NEED (3*WT_B + 2*HB_B + XH_B + TAIL_B)
#define A2_NEED (2*WT_B + 2*HB_B + XH_B + TAIL_B)
#define BF_NEED ((size_t)SLOT_CAP*IDIM*2 + (size_t)SLOT_CAP*DDIM*2 + TAIL_B)

__device__ __forceinline__ int swz(int row) { return ((row ^ (row >> 3)) & 7) << 4; }

__device__ __forceinline__ void gload_lds16(const void* gp, void* lp) {
  __builtin_amdgcn_global_load_lds(
      (const __attribute__((address_space(1))) uint32_t*)gp,
      (__attribute__((address_space(3))) uint32_t*)lp,
      16, 0, 0);
}

// ================= device bodies =================

// weight transpose-convert tile: f32 [K,N] -> f16 [N,K], 64x64 per block.
// Register 4x4 transpose + b64 LDS writes + XOR-swizzled rows (conflict-floor)
// + 128B-contiguous global writes. Uses 8KB of smem.
__device__ __forceinline__ void cvt_body(const float* __restrict__ src, f16* __restrict__ dst,
                                          int blk, int tid, char* smem) {
  const int e = blk / 2025;
  const int tile = blk % 2025;
  const int k0 = (tile / 45) * 64;
  const int i0 = (tile % 45) * 64;
  const float* sp = src + ((size_t)e * DDIM + k0) * IDIM + i0;
  const int c0  = (tid & 15) * 4;   // N quad
  const int kr0 = (tid >> 4) * 4;   // K quad
  float4 v0 = *(const float4*)(sp + (size_t)(kr0 + 0) * IDIM + c0);
  float4 v1 = *(const float4*)(sp + (size_t)(kr0 + 1) * IDIM + c0);
  float4 v2 = *(const float4*)(sp + (size_t)(kr0 + 2) * IDIM + c0);
  float4 v3 = *(const float4*)(sp + (size_t)(kr0 + 3) * IDIM + c0);
#pragma unroll
  for (int c = 0; c < 4; c++) {
    f16x4 p;
    p[0] = (f16)((c==0) ? v0.x : (c==1) ? v0.y : (c==2) ? v0.z : v0.w);
    p[1] = (f16)((c==0) ? v1.x : (c==1) ? v1.y : (c==2) ? v1.z : v1.w);
    p[2] = (f16)((c==0) ? v2.x : (c==1) ? v2.y : (c==2) ? v2.z : v2.w);
    p[3] = (f16)((c==0) ? v3.x : (c==1) ? v3.y : (c==2) ? v3.z : v3.w);
    int row = c0 + c;
    *(f16x4*)(smem + row * 128 + ((kr0 * 2) ^ swz(row))) = p;
  }
  __syncthreads();
#pragma unroll
  for (int q = 0; q < 2; q++) {
    int row = (tid >> 3) + 32 * q;
    int o = (tid & 7) * 16;   // byte offset within row
    f16x8 r = *(const f16x8*)(smem + row * 128 + (o ^ swz(row)));
    *(f16x8*)(dst + ((size_t)e * IDIM + i0 + row) * DDIM + k0 + o / 2) = r;
  }
}

__device__ __forceinline__ void router_body(const float* __restrict__ x, const float* __restrict__ wr,
                                            int* __restrict__ meta, float* __restrict__ tok_w,
                                            int blk, int tid) {
  const int lane = tid & 63;
  const int t = blk * 4 + (tid >> 6);
  double acc[NEXP];
#pragma unroll
  for (int e = 0; e < NEXP; e++) acc[e] = 0.0;
  for (int d = lane; d < DDIM; d += 64) {
    float xv = x[(size_t)t * DDIM + d];
    float4 w0 = *(const float4*)(wr + (size_t)d * NEXP);
    float4 w1 = *(const float4*)(wr + (size_t)d * NEXP + 4);
    acc[0] += (double)xv * (double)w0.x;
    acc[1] += (double)xv * (double)w0.y;
    acc[2] += (double)xv * (double)w0.z;
    acc[3] += (double)xv * (double)w0.w;
    acc[4] += (double)xv * (double)w1.x;
    acc[5] += (double)xv * (double)w1.y;
    acc[6] += (double)xv * (double)w1.z;
    acc[7] += (double)xv * (double)w1.w;
  }
#pragma unroll
  for (int m = 32; m >= 1; m >>= 1) {
#pragma unroll
    for (int e = 0; e < NEXP; e++) acc[e] += __shfl_xor(acc[e], m, 64);
  }
  if (lane == 0) {
    int e0 = 0;
#pragma unroll
    for (int e = 1; e < NEXP; e++) if (acc[e] > acc[e0]) e0 = e;
    int e1 = (e0 == 0) ? 1 : 0;
#pragma unroll
    for (int e = 0; e < NEXP; e++) if (e != e0 && acc[e] > acc[e1]) e1 = e;
    double w0 = 1.0 / (1.0 + exp(acc[e1] - acc[e0]));
    meta[M_TOK_E + 2*t]     = e0;
    meta[M_TOK_E + 2*t + 1] = e1;
    tok_w[2*t]     = (float)w0;
    tok_w[2*t + 1] = (float)(1.0 - w0);
    atomicAdd(&meta[M_COUNT + e0], 1);
    atomicAdd(&meta[M_COUNT + e1], 1);
  }
}

__device__ __forceinline__ void xcvt_body(const float* __restrict__ x, f16* __restrict__ xh,
                                          int blk, int tid) {
  size_t i = ((size_t)blk * 256 + tid) * 8;
  float4 a = *(const float4*)(x + i);
  float4 b = *(const float4*)(x + i + 4);
  f16x8 v;
  v[0]=(f16)a.x; v[1]=(f16)a.y; v[2]=(f16)a.z; v[3]=(f16)a.w;
  v[4]=(f16)b.x; v[5]=(f16)b.y; v[6]=(f16)b.z; v[7]=(f16)b.w;
  *(f16x8*)(xh + i) = v;
}

// ================= P1: cvt_wg + cvt_wu + router + xcvt =================
__global__ __launch_bounds__(256) void k_p1(
    const float* __restrict__ x, const float* __restrict__ wr,
    const float* __restrict__ wg, const float* __restrict__ wu,
    f16* __restrict__ wgT, f16* __restrict__ wuT, f16* __restrict__ xh,
    int* __restrict__ meta, float* __restrict__ tok_w) {
  __shared__ char smem[8192];
  int b = blockIdx.x;
  const int tid = threadIdx.x;
  if (b < NCVT) { cvt_body(wg, wgT, b, tid, smem); return; }
  b -= NCVT;
  if (b < NCVT) { cvt_body(wu, wuT, b, tid, smem); return; }
  b -= NCVT;
  if (b < T_TOK/4) { router_body(x, wr, meta, tok_w, b, tid); return; }
  b -= T_TOK/4;
  xcvt_body(x, xh, b, tid);
}

__global__ __launch_bounds__(256) void k_router(const float* x, const float* wr, int* meta, float* tok_w) {
  router_body(x, wr, meta, tok_w, blockIdx.x, threadIdx.x);
}
__global__ __launch_bounds__(256) void k_xcvt(const float* x, f16* xh) {
  xcvt_body(x, xh, blockIdx.x, threadIdx.x);
}
__global__ __launch_bounds__(256) void k_cvt_w(const float* src, f16* dst) {
  __shared__ char smem[8192];
  cvt_body(src, dst, blockIdx.x, threadIdx.x, smem);
}

// ================= scan + scatter (one block) =================
__global__ __launch_bounds__(256) void k_scan_scatter(
    int* __restrict__ meta, float* __restrict__ slot_w, const float* __restrict__ tok_w, int bm) {
  __shared__ int s_off[NEXP], s_cnt[NEXP], s_pc[NEXP], s_cur[NEXP];
  const int tid = threadIdx.x;
  if (tid == 0) {
    int run = 0, nt = 0;
    for (int e = 0; e < NEXP; e++) {
      int c = meta[M_COUNT + e];
      int mt = (c + bm - 1) / bm;
      meta[M_OFFS + e] = run;
      s_off[e] = run; s_cnt[e] = c; s_pc[e] = mt * bm; s_cur[e] = 0;
      for (int j = 0; j < mt; j++) { meta[M_TILE_E + nt] = e; meta[M_TILE_R0 + nt] = run + j * bm; nt++; }
      run += mt * bm;
    }
    meta[M_OFFS + NEXP] = run;
    meta[M_NTILES] = nt;
  }
  __syncthreads();
  for (int e = 0; e < NEXP; e++) {
    for (int i = s_cnt[e] + tid; i < s_pc[e]; i += 256) {
      meta[M_SLOT_TOK + s_off[e] + i] = 0;
      slot_w[s_off[e] + i] = 0.0f;
    }
  }
  for (int t = tid; t < T_TOK; t += 256) {
#pragma unroll
    for (int k = 0; k < 2; k++) {
      int e = meta[M_TOK_E + 2*t + k];
      int pos = atomicAdd(&s_cur[e], 1);
      int slot = s_off[e] + pos;
      meta[M_SLOT_TOK + slot] = t;
      slot_w[slot] = tok_w[2*t + k];
      meta[M_SLOT_OF + 2*t + k] = slot;
    }
  }
}

// ================= kg1 (dbuf) + cvt_wd backfill =================
// LDS layout (bytes): sA buf0 @0, buf1 @16384; sBg buf0 @32768, buf1 @45056;
//                     sBu buf0 @57344, buf1 @69632. Total 81920.
__device__ __forceinline__ void kg1_body(
    const f16* __restrict__ xh, const f16* __restrict__ wgT, const f16* __restrict__ wuT,
    f16* __restrict__ hbuf, const int* __restrict__ meta, int id, int tid, char* smem) {
  const int sid = (id & 7) * (NB1_A / 8) + (id >> 3);
  const int mt = sid % MAXMT_A;
  const int nb = sid / MAXMT_A;
  if (mt >= meta[M_NTILES]) return;
  const int e  = meta[M_TILE_E + mt];
  const int r0 = meta[M_TILE_R0 + mt];
  const int n0 = nb * BN1_A;

  const int lane = tid & 63;
  const int w = tid >> 6;
  const int wm = w >> 1, wn = w & 1;

  const char* aG[4]; int aL[4];
#pragma unroll
  for (int i = 0; i < 4; i++) {
    int seg = w * 4 + i;
    int row = seg * 8 + (lane >> 3);
    int colb = ((lane & 7) * 16) ^ swz(row);
    int tok = meta[M_SLOT_TOK + r0 + row];
    aG[i] = (const char*)(xh + (size_t)tok * DDIM) + colb;
    aL[i] = seg * 1024;
  }
  const char* gG[3]; const char* uG[3]; int bL[3];
#pragma unroll
  for (int i = 0; i < 3; i++) {
    int seg = w * 3 + i;
    int row = seg * 8 + (lane >> 3);
    int colb = ((lane & 7) * 16) ^ swz(row);
    gG[i] = (const char*)(wgT + ((size_t)e * IDIM + n0 + row) * DDIM) + colb;
    uG[i] = (const char*)(wuT + ((size_t)e * IDIM + n0 + row) * DDIM) + colb;
    bL[i] = seg * 1024;
  }

  f32x4 accG[4][3], accU[4][3];
#pragma unroll
  for (int i = 0; i < 4; i++)
#pragma unroll
    for (int j = 0; j < 3; j++) { accG[i][j] = {0.f,0.f,0.f,0.f}; accU[i][j] = {0.f,0.f,0.f,0.f}; }

#pragma unroll
  for (int i = 0; i < 4; i++) gload_lds16(aG[i], smem + aL[i]);
#pragma unroll
  for (int i = 0; i < 3; i++) gload_lds16(gG[i], smem + 32768 + bL[i]);
#pragma unroll
  for (int i = 0; i < 3; i++) gload_lds16(uG[i], smem + 57344 + bL[i]);
  __syncthreads();

  for (int kt = 0; kt < NKT; kt++) {
    const int cur = kt & 1;
    char* curA  = smem + cur * 16384;
    char* curBg = smem + 32768 + cur * 12288;
    char* curBu = smem + 57344 + cur * 12288;
    if (kt + 1 < NKT) {
      const int nx = cur ^ 1;
      char* nxA  = smem + nx * 16384;
      char* nxBg = smem + 32768 + nx * 12288;
      char* nxBu = smem + 57344 + nx * 12288;
#pragma unroll
      for (int i = 0; i < 4; i++) gload_lds16(aG[i] + (kt+1) * 128, nxA + aL[i]);
#pragma unroll
      for (int i = 0; i < 3; i++) gload_lds16(gG[i] + (kt+1) * 128, nxBg + bL[i]);
#pragma unroll
      for (int i = 0; i < 3; i++) gload_lds16(uG[i] + (kt+1) * 128, nxBu + bL[i]);
    }
#pragma unroll
    for (int kk = 0; kk < 2; kk++) {
      const int gb = kk * 64 + ((lane >> 4) * 16);
      f16x8 af[4], bg[3], bu[3];
#pragma unroll
      for (int fm = 0; fm < 4; fm++) {
        int row = wm * 64 + fm * 16 + (lane & 15);
        af[fm] = *(const f16x8*)(curA + row * 128 + (gb ^ swz(row)));
      }
#pragma unroll
      for (int fn = 0; fn < 3; fn++) {
        int row = wn * 48 + fn * 16 + (lane & 15);
        bg[fn] = *(const f16x8*)(curBg + row * 128 + (gb ^ swz(row)));
        bu[fn] = *(const f16x8*)(curBu + row * 128 + (gb ^ swz(row)));
      }
#pragma unroll
      for (int fm = 0; fm < 4; fm++)
#pragma unroll
        for (int fn = 0; fn < 3; fn++) {
          accG[fm][fn] = __builtin_amdgcn_mfma_f32_16x16x32_f16(af[fm], bg[fn], accG[fm][fn], 0, 0, 0);
          accU[fm][fn] = __builtin_amdgcn_mfma_f32_16x16x32_f16(af[fm], bu[fn], accU[fm][fn], 0, 0, 0);
        }
    }
    __syncthreads();
  }

  const int rl4 = (lane >> 4) * 4;
  const int cl  = lane & 15;
#pragma unroll
  for (int fm = 0; fm < 4; fm++)
#pragma unroll
    for (int fn = 0; fn < 3; fn++)
#pragma unroll
      for (int j = 0; j < 4; j++) {
        int row = wm * 64 + fm * 16 + rl4 + j;
        int col = n0 + wn * 48 + fn * 16 + cl;
        float g = accG[fm][fn][j], u = accU[fm][fn][j];
        float h = g * u / (1.0f + __expf(-g));
        hbuf[(size_t)(r0 + row) * IDIM + col] = (f16)h;
      }
}

__global__ __launch_bounds__(256, 2) void k_g1cvt(
    const f16* __restrict__ xh, const f16* __restrict__ wgT, const f16* __restrict__ wuT,
    f16* __restrict__ hbuf, const int* __restrict__ meta,
    const float* __restrict__ wd, f16* __restrict__ wdT) {
  __shared__ char smem[81920];
  const int id = blockIdx.x;
  if (id < NB1_A) kg1_body(xh, wgT, wuT, hbuf, meta, id, threadIdx.x, smem);
  else            cvt_body(wd, wdT, id - NB1_A, threadIdx.x, smem);
}

// ================= kg2 (dbuf) =================
// LDS: sA buf0 @0, buf1 @16384; sB buf0 @32768, buf1 @57344. Total 81920.
__global__ __launch_bounds__(256, 2) void kg2(
    const f16* __restrict__ hbuf, const f16* __restrict__ wdT,
    f16* __restrict__ ybuf, const int* __restrict__ meta, const float* __restrict__ slot_w) {
  __shared__ char smem[81920];
  const int id = blockIdx.x;
  const int sid = (id & 7) * (NB2_A / 8) + (id >> 3);
  const int mt = sid % MAXMT_A;
  const int nb = sid / MAXMT_A;
  if (mt >= meta[M_NTILES]) return;
  const int e  = meta[M_TILE_E + mt];
  const int r0 = meta[M_TILE_R0 + mt];
  const int n0 = nb * BN2_A;

  const int tid = threadIdx.x;
  const int lane = tid & 63;
  const int w = tid >> 6;
  const int wm = w >> 1, wn = w & 1;

  const char* aG[4]; int aL[4];
#pragma unroll
  for (int i = 0; i < 4; i++) {
    int seg = w * 4 + i;
    int row = seg * 8 + (lane >> 3);
    int colb = ((lane & 7) * 16) ^ swz(row);
    aG[i] = (const char*)(hbuf + (size_t)(r0 + row) * IDIM) + colb;
    aL[i] = seg * 1024;
  }
  const char* bG[6]; int bL[6];
#pragma unroll
  for (int i = 0; i < 6; i++) {
    int seg = w * 6 + i;
    int row = seg * 8 + (lane >> 3);
    int colb = ((lane & 7) * 16) ^ swz(row);
    bG[i] = (const char*)(wdT + ((size_t)e * DDIM + n0 + row) * IDIM) + colb;
    bL[i] = seg * 1024;
  }

  f32x4 acc[4][6];
#pragma unroll
  for (int i = 0; i < 4; i++)
#pragma unroll
    for (int j = 0; j < 6; j++) acc[i][j] = {0.f,0.f,0.f,0.f};

#pragma unroll
  for (int i = 0; i < 4; i++) gload_lds16(aG[i], smem + aL[i]);
#pragma unroll
  for (int i = 0; i < 6; i++) gload_lds16(bG[i], smem + 32768 + bL[i]);
  __syncthreads();

  for (int kt = 0; kt < NKT; kt++) {
    const int cur = kt & 1;
    char* curA = smem + cur * 16384;
    char* curB = smem + 32768 + cur * 24576;
    if (kt + 1 < NKT) {
      const int nx = cur ^ 1;
      char* nxA = smem + nx * 16384;
      char* nxB = smem + 32768 + nx * 24576;
#pragma unroll
      for (int i = 0; i < 4; i++) gload_lds16(aG[i] + (kt+1) * 128, nxA + aL[i]);
#pragma unroll
      for (int i = 0; i < 6; i++) gload_lds16(bG[i] + (kt+1) * 128, nxB + bL[i]);
    }
#pragma unroll
    for (int kk = 0; kk < 2; kk++) {
      const int gb = kk * 64 + ((lane >> 4) * 16);
      f16x8 af[4], bf[6];
#pragma unroll
      for (int fm = 0; fm < 4; fm++) {
        int row = wm * 64 + fm * 16 + (lane & 15);
        af[fm] = *(const f16x8*)(curA + row * 128 + (gb ^ swz(row)));
      }
#pragma unroll
      for (int fn = 0; fn < 6; fn++) {
        int row = wn * 96 + fn * 16 + (lane & 15);
        bf[fn] = *(const f16x8*)(curB + row * 128 + (gb ^ swz(row)));
      }
#pragma unroll
      for (int fm = 0; fm < 4; fm++)
#pragma unroll
        for (int fn = 0; fn < 6; fn++)
          acc[fm][fn] = __builtin_amdgcn_mfma_f32_16x16x32_f16(af[fm], bf[fn], acc[fm][fn], 0, 0, 0);
    }
    __syncthreads();
  }
  const int rl4 = (lane >> 4) * 4;
  const int cl  = lane & 15;
#pragma unroll
  for (int fm = 0; fm < 4; fm++)
#pragma unroll
    for (int j = 0; j < 4; j++) {
      int row = wm * 64 + fm * 16 + rl4 + j;
      int slot = r0 + row;
      float wv = slot_w[slot];
#pragma unroll
      for (int fn = 0; fn < 6; fn++) {
        int col = n0 + wn * 96 + fn * 16 + cl;
        ybuf[(size_t)slot * DDIM + col] = (f16)(acc[fm][fn][j] * wv);
      }
    }
}

// ---------------- combine ----------------
__global__ __launch_bounds__(256) void k_combine(const f16* __restrict__ ybuf,
    const int* __restrict__ meta, float* __restrict__ out) {
  size_t idx = (size_t)blockIdx.x * 256 + threadIdx.x;
  int t = (int)(idx / (DDIM/8));
  int c = (int)(idx % (DDIM/8));
  int s0 = meta[M_SLOT_OF + 2*t];
  int s1 = meta[M_SLOT_OF + 2*t + 1];
  f16x8 a = *(const f16x8*)(ybuf + (size_t)s0 * DDIM + c*8);
  f16x8 b = *(const f16x8*)(ybuf + (size_t)s1 * DDIM + c*8);
  float4 o0, o1;
  o0.x = (float)a[0] + (float)b[0];
  o0.y = (float)a[1] + (float)b[1];
  o0.z = (float)a[2] + (float)b[2];
  o0.w = (float)a[3] + (float)b[3];
  o1.x = (float)a[4] + (float)b[4];
  o1.y = (float)a[5] + (float)b[5];
  o1.z = (float)a[6] + (float)b[6];
  o1.w = (float)a[7] + (float)b[7];
  float* op = out + (size_t)t * DDIM + c*8;
  *(float4*)op = o0;
  *(float4*)(op + 4) = o1;
}

// ================= PATH B: fallback fused GEMMs (v4, verified) =================

__global__ __launch_bounds__(512, 2) void kg1_fb(
    const f16* __restrict__ xh, const float* __restrict__ wg, const float* __restrict__ wu,
    f16* __restrict__ hbuf, const int* __restrict__ meta) {
  const int id = blockIdx.x;
  const int sid = (id & 7) * (NB1_B / 8) + (id >> 3);
  const int mt = sid % MAXMT_B;
  const int nb = sid / MAXMT_B;
  if (mt >= meta[M_NTILES]) return;
  const int e  = meta[M_TILE_E + mt];
  const int r0 = meta[M_TILE_R0 + mt];
  const int n0 = nb * BN1_B;

  __shared__ ushort sA[2][BM_B * BK];
  __shared__ ushort sB[2][2][BN1_B * BK];

  const int tid  = threadIdx.x;
  const int lane = tid & 63;
  const int w    = tid >> 6;
  const int wm   = w >> 1;
  const int gu   = w & 1;

  const char* a_gbase[4];
  int a_loff[4];
#pragma unroll
  for (int i = 0; i < 4; i++) {
    int seg = w * 4 + i;
    int row = seg * 8 + (lane >> 3);
    int colb = ((lane & 7) * 16) ^ swz(row);
    int tok = meta[M_SLOT_TOK + r0 + row];
    a_gbase[i] = (const char*)(xh + (size_t)tok * DDIM) + colb;
    a_loff[i] = seg * 1024;
  }
  const int bm_ = tid / 192;
  const int tt  = tid % 192;
  const int bn0 = (tt % 24) * 4;
  const int bk0 = (tt / 24) * 8;
  const bool bact = tid < 384;
  const float* bsrc = (bm_ ? wu : wg) + ((size_t)e * DDIM + bk0) * IDIM + n0 + bn0;

  float4 vB[8];
  f32x4 acc[4][6];
#pragma unroll
  for (int i = 0; i < 4; i++)
#pragma unroll
    for (int j = 0; j < 6; j++) acc[i][j] = {0.f,0.f,0.f,0.f};

#pragma unroll
  for (int i = 0; i < 4; i++) gload_lds16(a_gbase[i], (char*)sA[0] + a_loff[i]);
  if (bact) {
#pragma unroll
    for (int j = 0; j < 8; j++) vB[j] = *(const float4*)(bsrc + (size_t)j * IDIM);
#pragma unroll
    for (int c = 0; c < 4; c++) {
      f16x8 p;
#pragma unroll
      for (int j = 0; j < 8; j++) {
        float fc = (c==0) ? vB[j].x : (c==1) ? vB[j].y : (c==2) ? vB[j].z : vB[j].w;
        p[j] = (f16)fc;
      }
      *(f16x8*)((char*)sB[0][bm_] + (bn0 + c) * 128 + ((bk0 * 2) ^ swz(bn0 + c))) = p;
    }
  }
  __syncthreads();

  for (int kt = 0; kt < NKT; kt++) {
    const int cur = kt & 1;
    if (kt + 1 < NKT) {
#pragma unroll
      for (int i = 0; i < 4; i++)
        gload_lds16(a_gbase[i] + (kt + 1) * 128, (char*)sA[cur ^ 1] + a_loff[i]);
      if (bact) {
        const float* bs = bsrc + (size_t)(kt + 1) * BK * IDIM;
#pragma unroll
        for (int j = 0; j < 8; j++) vB[j] = *(const float4*)(bs + (size_t)j * IDIM);
      }
    }
#pragma unroll
    for (int kk = 0; kk < 2; kk++) {
      const int gb = kk * 64 + ((lane >> 4) * 16);
      f16x8 af[4], bf[6];
#pragma unroll
      for (int fm = 0; fm < 4; fm++) {
        int row = wm * 64 + fm * 16 + (lane & 15);
        af[fm] = *(const f16x8*)((const char*)sA[cur] + row * 128 + (gb ^ swz(row)));
      }
#pragma unroll
      for (int fn = 0; fn < 6; fn++) {
        int row = fn * 16 + (lane & 15);
        bf[fn] = *(const f16x8*)((const char*)sB[cur][gu] + row * 128 + (gb ^ swz(row)));
      }
#pragma unroll
      for (int fm = 0; fm < 4; fm++)
#pragma unroll
        for (int fn = 0; fn < 6; fn++)
          acc[fm][fn] = __builtin_amdgcn_mfma_f32_16x16x32_f16(af[fm], bf[fn], acc[fm][fn], 0, 0, 0);
    }
    if (kt + 1 < NKT && bact) {
#pragma unroll
      for (int c = 0; c < 4; c++) {
        f16x8 p;
#pragma unroll
        for (int j = 0; j < 8; j++) {
          float fc = (c==0) ? vB[j].x : (c==1) ? vB[j].y : (c==2) ? vB[j].z : vB[j].w;
          p[j] = (f16)fc;
        }
        *(f16x8*)((char*)sB[cur ^ 1][bm_] + (bn0 + c) * 128 + ((bk0 * 2) ^ swz(bn0 + c))) = p;
      }
    }
    __syncthreads();
  }

  float* u_lds = (float*)&sA[0][0];
  const int rl4 = (lane >> 4) * 4;
  const int cl  = lane & 15;
#pragma unroll
  for (int r = 0; r < 2; r++) {
    __syncthreads();
    if (gu == 1) {
#pragma unroll
      for (int fi = 0; fi < 2; fi++)
#pragma unroll
        for (int fn = 0; fn < 6; fn++)
#pragma unroll
          for (int j = 0; j < 4; j++)
            u_lds[wm * 3200 + (fi * 16 + rl4 + j) * 100 + fn * 16 + cl] = acc[2*r + fi][fn][j];
    }
    __syncthreads();
    if (gu == 0) {
#pragma unroll
      for (int fi = 0; fi < 2; fi++) {
        int fm = 2*r + fi;
#pragma unroll
        for (int fn = 0; fn < 6; fn++)
#pragma unroll
          for (int j = 0; j < 4; j++) {
            float u = u_lds[wm * 3200 + (fi * 16 + rl4 + j) * 100 + fn * 16 + cl];
            float g = acc[fm][fn][j];
            float h = g * u / (1.0f + __expf(-g));
            hbuf[(size_t)(r0 + wm * 64 + fm * 16 + rl4 + j) * IDIM + n0 + fn * 16 + cl] = (f16)h;
          }
      }
    }
  }
}

__global__ __launch_bounds__(512, 2) void kg2_fb(
    const f16* __restrict__ hbuf, const float* __restrict__ wd,
    f16* __restrict__ ybuf, const int* __restrict__ meta, const float* __restrict__ slot_w) {
  const int id = blockIdx.x;
  const int sid = (id & 7) * (NB2_B / 8) + (id >> 3);
  const int mt = sid % MAXMT_B;
  const int nb = sid / MAXMT_B;
  if (mt >= meta[M_NTILES]) return;
  const int e  = meta[M_TILE_E + mt];
  const int r0 = meta[M_TILE_R0 + mt];
  const int n0 = nb * BN2_B;

  __shared__ ushort sA[2][BM_B * BK];
  __shared__ ushort sB1[2][BN2_B * BK];

  const int tid  = threadIdx.x;
  const int lane = tid & 63;
  const int w    = tid >> 6;
  const int wm   = w >> 1;
  const int wn   = w & 1;

  const char* a_gbase[4];
  int a_loff[4];
#pragma unroll
  for (int i = 0; i < 4; i++) {
    int seg = w * 4 + i;
    int row = seg * 8 + (lane >> 3);
    int colb = ((lane & 7) * 16) ^ swz(row);
    a_gbase[i] = (const char*)(hbuf + (size_t)(r0 + row) * IDIM) + colb;
    a_loff[i] = seg * 1024;
  }
  const int half = tid / 192;
  const int tt   = tid % 192;
  const int bn0  = half * 96 + (tt % 24) * 4;
  const int bk0  = (tt / 24) * 8;
  const bool bact = tid < 384;
  const float* bsrc = wd + ((size_t)e * IDIM + bk0) * DDIM + n0 + bn0;

  float4 vB[8];
  f32x4 acc[4][6];
#pragma unroll
  for (int i = 0; i < 4; i++)
#pragma unroll
    for (int j = 0; j < 6; j++) acc[i][j] = {0.f,0.f,0.f,0.f};

#pragma unroll
  for (int i = 0; i < 4; i++) gload_lds16(a_gbase[i], (char*)sA[0] + a_loff[i]);
  if (bact) {
#pragma unroll
    for (int j = 0; j < 8; j++) vB[j] = *(const float4*)(bsrc + (size_t)j * DDIM);
#pragma unroll
    for (int c = 0; c < 4; c++) {
      f16x8 p;
#pragma unroll
      for (int j = 0; j < 8; j++) {
        float fc = (c==0) ? vB[j].x : (c==1) ? vB[j].y : (c==2) ? vB[j].z : vB[j].w;
        p[j] = (f16)fc;
      }
      *(f16x8*)((char*)sB1[0] + (bn0 + c) * 128 + ((bk0 * 2) ^ swz(bn0 + c))) = p;
    }
  }
  __syncthreads();

  for (int kt = 0; kt < NKT; kt++) {
    const int cur = kt & 1;
    if (kt + 1 < NKT) {
#pragma unroll
      for (int i = 0; i < 4; i++)
        gload_lds16(a_gbase[i] + (kt + 1) * 128, (char*)sA[cur ^ 1] + a_loff[i]);
      if (bact) {
        const float* bs = bsrc + (size_t)(kt + 1) * BK * DDIM;
#pragma unroll
        for (int j = 0; j < 8; j++) vB[j] = *(const float4*)(bs + (size_t)j * DDIM);
      }
    }
#pragma unroll
    for (int kk = 0; kk < 2; kk++) {
      const int gb = kk * 64 + ((lane >> 4) * 16);
      f16x8 af[4], bf[6];
#pragma unroll
      for (int fm = 0; fm < 4; fm++) {
        int row = wm * 64 + fm * 16 + (lane & 15);
        af[fm] = *(const f16x8*)((const char*)sA[cur] + row * 128 + (gb ^ swz(row)));
      }
#pragma unroll
      for (int fn = 0; fn < 6; fn++) {
        int row = wn * 96 + fn * 16 + (lane & 15);
        bf[fn] = *(const f16x8*)((const char*)sB1[cur] + row * 128 + (gb ^ swz(row)));
      }
#pragma unroll
      for (int fm = 0; fm < 4; fm++)
#pragma unroll
        for (int fn = 0; fn < 6; fn++)
          acc[fm][fn] = __builtin_amdgcn_mfma_f32_16x16x32_f16(af[fm], bf[fn], acc[fm][fn], 0, 0, 0);
    }
    if (kt + 1 < NKT && bact) {
#pragma unroll
      for (int c = 0; c < 4; c++) {
        f16x8 p;
#pragma unroll
        for (int j = 0; j < 8; j++) {
          float fc = (c==0) ? vB[j].x : (c==1) ? vB[j].y : (c==2) ? vB[j].z : vB[j].w;
          p[j] = (f16)fc;
        }
        *(f16x8*)((char*)sB1[cur ^ 1] + (bn0 + c) * 128 + ((bk0 * 2) ^ swz(bn0 + c))) = p;
      }
    }
    __syncthreads();
  }

  const int rl4 = (lane >> 4) * 4;
  const int cl  = lane & 15;
#pragma unroll
  for (int fm = 0; fm < 4; fm++)
#pragma unroll
    for (int j = 0; j < 4; j++) {
      int row = wm * 64 + fm * 16 + rl4 + j;
      int slot = r0 + row;
      float wv = slot_w[slot];
#pragma unroll
      for (int fn = 0; fn < 6; fn++) {
        int col = n0 + wn * 96 + fn * 16 + cl;
        ybuf[(size_t)slot * DDIM + col] = (f16)(acc[fm][fn][j] * wv);
      }
    }
}

extern "C" void kernel_launch(void* const* d_in, const int* in_sizes, int n_in,
                              void* d_out, int out_size, void* d_ws, size_t ws_size,
                              hipStream_t stream) {
  const float* x  = (const float*)d_in[0];
  const float* wr = (const float*)d_in[1];
  const float* wg = (const float*)d_in[2];
  const float* wu = (const float*)d_in[3];
  const float* wd = (const float*)d_in[4];
  float* out = (float*)d_out;
  char* ws = (char*)d_ws;

  if (ws_size >= A2_NEED) {
    const bool three = (ws_size >= A3_NEED);
    f16* wgT = (f16*)(ws);
    f16* wuT = (f16*)(ws + WT_B);
    f16* wdT = three ? (f16*)(ws + 2*WT_B) : wgT;   // alias only if sequential
    char* base = ws + (three ? 3*WT_B : 2*WT_B);
    f16* hbuf = (f16*)(base);
    f16* ybuf = (f16*)(base + HB_B);
    f16* xh   = (f16*)(base + 2*HB_B);
    int* meta = (int*)(base + 2*HB_B + XH_B);
    float* slot_w = (float*)((char*)meta + META_INTS*4);
    float* tok_w  = (float*)((char*)slot_w + SLOT_CAP*4);

    (void)hipMemsetAsync(meta + M_COUNT, 0, NEXP * sizeof(int), stream);
    k_p1<<<2*NCVT + T_TOK/4 + 2880, 256, 0, stream>>>(x, wr, wg, wu, wgT, wuT, xh, meta, tok_w);
    k_scan_scatter<<<1, 256, 0, stream>>>(meta, slot_w, tok_w, BM_A);
    if (three) {
      k_g1cvt<<<NB1_A + NCVT, 256, 0, stream>>>(xh, wgT, wuT, hbuf, meta, wd, wdT);
    } else {
      k_g1cvt<<<NB1_A, 256, 0, stream>>>(xh, wgT, wuT, hbuf, meta, wd, wdT);
      k_cvt_w<<<NCVT, 256, 0, stream>>>(wd, wdT);
    }
    kg2<<<NB2_A, 256, 0, stream>>>(hbuf, wdT, ybuf, meta, slot_w);
    k_combine<<<(T_TOK*DDIM/8)/256, 256, 0, stream>>>(ybuf, meta, out);
  } else if (ws_size >= BF_NEED) {
    f16* hbuf = (f16*)(ws);
    f16* xh   = (f16*)(ws + (size_t)SLOT_CAP*IDIM*2);
    f16* ybuf = xh;
    int* meta = (int*)(ws + (size_t)SLOT_CAP*IDIM*2 + (size_t)SLOT_CAP*DDIM*2);
    float* slot_w = (float*)((char*)meta + META_INTS*4);
    float* tok_w  = (float*)((char*)slot_w + SLOT_CAP*4);

    (void)hipMemsetAsync(meta + M_COUNT, 0, NEXP * sizeof(int), stream);
    k_router<<<T_TOK/4, 256, 0, stream>>>(x, wr, meta, tok_w);
    k_xcvt<<<(T_TOK*DDIM/8)/256, 256, 0, stream>>>(x, xh);
    k_scan_scatter<<<1, 256, 0, stream>>>(meta, slot_w, tok_w, BM_B);
    kg1_fb<<<NB1_B, 512, 0, stream>>>(xh, wg, wu, hbuf, meta);
    kg2_fb<<<NB2_B, 512, 0, stream>>>(hbuf, wd, ybuf, meta, slot_w);
    k_combine<<<(T_TOK*DDIM/8)/256, 256, 0, stream>>>(ybuf, meta, out);
  }
}

// Round 10
// 572.485 us; speedup vs baseline: 1.3731x; 1.0010x over previous
//
#include <hip/hip_runtime.h>
#include <hip/hip_fp16.h>
#include <stdint.h>
#include <math.h>

// MoE MLP block: router top-2 + 8 experts SiLU-GLU, fp16 MFMA.
// v8: v7b with LDS-clean weight transpose-convert: register 4x4 transpose,
// ds_write_b64, GEMM-style XOR swizzle on LDS rows, 128B-coalesced output.
// P1 = cvt_wg+cvt_wu+router+xcvt fused; P3 = kg1 + cvt_wd backfill; GEMMs
// double-buffered (80KB LDS, 1 barrier/k-step). 3-tier ws fallback.

typedef _Float16 f16;
typedef _Float16 f16x4 __attribute__((ext_vector_type(4)));
typedef _Float16 f16x8 __attribute__((ext_vector_type(8)));
typedef float f32x4 __attribute__((ext_vector_type(4)));

#define T_TOK 2048
#define DDIM 2880
#define NEXP 8
#define IDIM 2880
#define BK 64
#define NKT 45

#define BM_A 128
#define BN1_A 96
#define BN2_A 192
#define MAXMT_A 40
#define NB1_A (30*MAXMT_A)   // 1200
#define NB2_A (15*MAXMT_A)   // 600
#define NCVT 16200           // 2025*8 blocks per weight tensor

#define BM_B 256
#define BN1_B 96
#define BN2_B 192
#define MAXMT_B 24
#define NB1_B (30*MAXMT_B)
#define NB2_B (15*MAXMT_B)

#define SLOT_CAP 6144

// meta int32 indices
#define M_COUNT 0
#define M_OFFS 16
#define M_NTILES 25
#define M_TILE_E 32
#define M_TILE_R0 96
#define M_SLOT_TOK 160
#define M_SLOT_OF (160+SLOT_CAP)
#define M_TOK_E (M_SLOT_OF + 2*T_TOK)
#define META_INTS (M_TOK_E + 2*T_TOK)

#define WT_B   ((size_t)NEXP*DDIM*IDIM*2)     // 132.7MB
#define HB_B   ((size_t)5120*IDIM*2)          // 29.5MB
#define XH_B   ((size_t)T_TOK*DDIM*2)         // 11.8MB
#define TAIL_B ((size_t)META_INTS*4 + (size_t)SLOT_CAP*4 + (size_t)T_TOK*2*4)

#define A3_NEED (3*WT_B + 2*HB_B + XH_B + TAIL_B)
#define A2_NEED (2*WT_B + 2*HB_B + XH_B + TAIL_B)
#define BF_NEED ((size_t)SLOT_CAP*IDIM*2 + (size_t)SLOT_CAP*DDIM*2 + TAIL_B)

__device__ __forceinline__ int swz(int row) { return ((row ^ (row >> 3)) & 7) << 4; }

__device__ __forceinline__ void gload_lds16(const void* gp, void* lp) {
  __builtin_amdgcn_global_load_lds(
      (const __attribute__((address_space(1))) uint32_t*)gp,
      (__attribute__((address_space(3))) uint32_t*)lp,
      16, 0, 0);
}

// ================= device bodies =================

// weight transpose-convert tile: f32 [K,N] -> f16 [N,K], 64x64 per block.
// Register 4x4 transpose + b64 LDS writes + XOR-swizzled rows (conflict-floor)
// + 128B-contiguous global writes. Uses 8KB of smem.
__device__ __forceinline__ void cvt_body(const float* __restrict__ src, f16* __restrict__ dst,
                                          int blk, int tid, char* smem) {
  const int e = blk / 2025;
  const int tile = blk % 2025;
  const int k0 = (tile / 45) * 64;
  const int i0 = (tile % 45) * 64;
  const float* sp = src + ((size_t)e * DDIM + k0) * IDIM + i0;
  const int c0  = (tid & 15) * 4;   // N quad
  const int kr0 = (tid >> 4) * 4;   // K quad
  float4 v0 = *(const float4*)(sp + (size_t)(kr0 + 0) * IDIM + c0);
  float4 v1 = *(const float4*)(sp + (size_t)(kr0 + 1) * IDIM + c0);
  float4 v2 = *(const float4*)(sp + (size_t)(kr0 + 2) * IDIM + c0);
  float4 v3 = *(const float4*)(sp + (size_t)(kr0 + 3) * IDIM + c0);
#pragma unroll
  for (int c = 0; c < 4; c++) {
    f16x4 p;
    p[0] = (f16)((c==0) ? v0.x : (c==1) ? v0.y : (c==2) ? v0.z : v0.w);
    p[1] = (f16)((c==0) ? v1.x : (c==1) ? v1.y : (c==2) ? v1.z : v1.w);
    p[2] = (f16)((c==0) ? v2.x : (c==1) ? v2.y : (c==2) ? v2.z : v2.w);
    p[3] = (f16)((c==0) ? v3.x : (c==1) ? v3.y : (c==2) ? v3.z : v3.w);
    int row = c0 + c;
    *(f16x4*)(smem + row * 128 + ((kr0 * 2) ^ swz(row))) = p;
  }
  __syncthreads();
#pragma unroll
  for (int q = 0; q < 2; q++) {
    int row = (tid >> 3) + 32 * q;
    int o = (tid & 7) * 16;   // byte offset within row
    f16x8 r = *(const f16x8*)(smem + row * 128 + (o ^ swz(row)));
    *(f16x8*)(dst + ((size_t)e * IDIM + i0 + row) * DDIM + k0 + o / 2) = r;
  }
}

__device__ __forceinline__ void router_body(const float* __restrict__ x, const float* __restrict__ wr,
                                            int* __restrict__ meta, float* __restrict__ tok_w,
                                            int blk, int tid) {
  const int lane = tid & 63;
  const int t = blk * 4 + (tid >> 6);
  double acc[NEXP];
#pragma unroll
  for (int e = 0; e < NEXP; e++) acc[e] = 0.0;
  for (int d = lane; d < DDIM; d += 64) {
    float xv = x[(size_t)t * DDIM + d];
    float4 w0 = *(const float4*)(wr + (size_t)d * NEXP);
    float4 w1 = *(const float4*)(wr + (size_t)d * NEXP + 4);
    acc[0] += (double)xv * (double)w0.x;
    acc[1] += (double)xv * (double)w0.y;
    acc[2] += (double)xv * (double)w0.z;
    acc[3] += (double)xv * (double)w0.w;
    acc[4] += (double)xv * (double)w1.x;
    acc[5] += (double)xv * (double)w1.y;
    acc[6] += (double)xv * (double)w1.z;
    acc[7] += (double)xv * (double)w1.w;
  }
#pragma unroll
  for (int m = 32; m >= 1; m >>= 1) {
#pragma unroll
    for (int e = 0; e < NEXP; e++) acc[e] += __shfl_xor(acc[e], m, 64);
  }
  if (lane == 0) {
    int e0 = 0;
#pragma unroll
    for (int e = 1; e < NEXP; e++) if (acc[e] > acc[e0]) e0 = e;
    int e1 = (e0 == 0) ? 1 : 0;
#pragma unroll
    for (int e = 0; e < NEXP; e++) if (e != e0 && acc[e] > acc[e1]) e1 = e;
    double w0 = 1.0 / (1.0 + exp(acc[e1] - acc[e0]));
    meta[M_TOK_E + 2*t]     = e0;
    meta[M_TOK_E + 2*t + 1] = e1;
    tok_w[2*t]     = (float)w0;
    tok_w[2*t + 1] = (float)(1.0 - w0);
    atomicAdd(&meta[M_COUNT + e0], 1);
    atomicAdd(&meta[M_COUNT + e1], 1);
  }
}

__device__ __forceinline__ void xcvt_body(const float* __restrict__ x, f16* __restrict__ xh,
                                          int blk, int tid) {
  size_t i = ((size_t)blk * 256 + tid) * 8;
  float4 a = *(const float4*)(x + i);
  float4 b = *(const float4*)(x + i + 4);
  f16x8 v;
  v[0]=(f16)a.x; v[1]=(f16)a.y; v[2]=(f16)a.z; v[3]=(f16)a.w;
  v[4]=(f16)b.x; v[5]=(f16)b.y; v[6]=(f16)b.z; v[7]=(f16)b.w;
  *(f16x8*)(xh + i) = v;
}

// ================= P1: cvt_wg + cvt_wu + router + xcvt =================
__global__ __launch_bounds__(256) void k_p1(
    const float* __restrict__ x, const float* __restrict__ wr,
    const float* __restrict__ wg, const float* __restrict__ wu,
    f16* __restrict__ wgT, f16* __restrict__ wuT, f16* __restrict__ xh,
    int* __restrict__ meta, float* __restrict__ tok_w) {
  __shared__ char smem[8192];
  int b = blockIdx.x;
  const int tid = threadIdx.x;
  if (b < NCVT) { cvt_body(wg, wgT, b, tid, smem); return; }
  b -= NCVT;
  if (b < NCVT) { cvt_body(wu, wuT, b, tid, smem); return; }
  b -= NCVT;
  if (b < T_TOK/4) { router_body(x, wr, meta, tok_w, b, tid); return; }
  b -= T_TOK/4;
  xcvt_body(x, xh, b, tid);
}

__global__ __launch_bounds__(256) void k_router(const float* x, const float* wr, int* meta, float* tok_w) {
  router_body(x, wr, meta, tok_w, blockIdx.x, threadIdx.x);
}
__global__ __launch_bounds__(256) void k_xcvt(const float* x, f16* xh) {
  xcvt_body(x, xh, blockIdx.x, threadIdx.x);
}
__global__ __launch_bounds__(256) void k_cvt_w(const float* src, f16* dst) {
  __shared__ char smem[8192];
  cvt_body(src, dst, blockIdx.x, threadIdx.x, smem);
}

// ================= scan + scatter (one block) =================
__global__ __launch_bounds__(256) void k_scan_scatter(
    int* __restrict__ meta, float* __restrict__ slot_w, const float* __restrict__ tok_w, int bm) {
  __shared__ int s_off[NEXP], s_cnt[NEXP], s_pc[NEXP], s_cur[NEXP];
  const int tid = threadIdx.x;
  if (tid == 0) {
    int run = 0, nt = 0;
    for (int e = 0; e < NEXP; e++) {
      int c = meta[M_COUNT + e];
      int mt = (c + bm - 1) / bm;
      meta[M_OFFS + e] = run;
      s_off[e] = run; s_cnt[e] = c; s_pc[e] = mt * bm; s_cur[e] = 0;
      for (int j = 0; j < mt; j++) { meta[M_TILE_E + nt] = e; meta[M_TILE_R0 + nt] = run + j * bm; nt++; }
      run += mt * bm;
    }
    meta[M_OFFS + NEXP] = run;
    meta[M_NTILES] = nt;
  }
  __syncthreads();
  for (int e = 0; e < NEXP; e++) {
    for (int i = s_cnt[e] + tid; i < s_pc[e]; i += 256) {
      meta[M_SLOT_TOK + s_off[e] + i] = 0;
      slot_w[s_off[e] + i] = 0.0f;
    }
  }
  for (int t = tid; t < T_TOK; t += 256) {
#pragma unroll
    for (int k = 0; k < 2; k++) {
      int e = meta[M_TOK_E + 2*t + k];
      int pos = atomicAdd(&s_cur[e], 1);
      int slot = s_off[e] + pos;
      meta[M_SLOT_TOK + slot] = t;
      slot_w[slot] = tok_w[2*t + k];
      meta[M_SLOT_OF + 2*t + k] = slot;
    }
  }
}

// ================= kg1 (dbuf) + cvt_wd backfill =================
// LDS layout (bytes): sA buf0 @0, buf1 @16384; sBg buf0 @32768, buf1 @45056;
//                     sBu buf0 @57344, buf1 @69632. Total 81920.
__device__ __forceinline__ void kg1_body(
    const f16* __restrict__ xh, const f16* __restrict__ wgT, const f16* __restrict__ wuT,
    f16* __restrict__ hbuf, const int* __restrict__ meta, int id, int tid, char* smem) {
  const int sid = (id & 7) * (NB1_A / 8) + (id >> 3);
  const int mt = sid % MAXMT_A;
  const int nb = sid / MAXMT_A;
  if (mt >= meta[M_NTILES]) return;
  const int e  = meta[M_TILE_E + mt];
  const int r0 = meta[M_TILE_R0 + mt];
  const int n0 = nb * BN1_A;

  const int lane = tid & 63;
  const int w = tid >> 6;
  const int wm = w >> 1, wn = w & 1;

  const char* aG[4]; int aL[4];
#pragma unroll
  for (int i = 0; i < 4; i++) {
    int seg = w * 4 + i;
    int row = seg * 8 + (lane >> 3);
    int colb = ((lane & 7) * 16) ^ swz(row);
    int tok = meta[M_SLOT_TOK + r0 + row];
    aG[i] = (const char*)(xh + (size_t)tok * DDIM) + colb;
    aL[i] = seg * 1024;
  }
  const char* gG[3]; const char* uG[3]; int bL[3];
#pragma unroll
  for (int i = 0; i < 3; i++) {
    int seg = w * 3 + i;
    int row = seg * 8 + (lane >> 3);
    int colb = ((lane & 7) * 16) ^ swz(row);
    gG[i] = (const char*)(wgT + ((size_t)e * IDIM + n0 + row) * DDIM) + colb;
    uG[i] = (const char*)(wuT + ((size_t)e * IDIM + n0 + row) * DDIM) + colb;
    bL[i] = seg * 1024;
  }

  f32x4 accG[4][3], accU[4][3];
#pragma unroll
  for (int i = 0; i < 4; i++)
#pragma unroll
    for (int j = 0; j < 3; j++) { accG[i][j] = {0.f,0.f,0.f,0.f}; accU[i][j] = {0.f,0.f,0.f,0.f}; }

#pragma unroll
  for (int i = 0; i < 4; i++) gload_lds16(aG[i], smem + aL[i]);
#pragma unroll
  for (int i = 0; i < 3; i++) gload_lds16(gG[i], smem + 32768 + bL[i]);
#pragma unroll
  for (int i = 0; i < 3; i++) gload_lds16(uG[i], smem + 57344 + bL[i]);
  __syncthreads();

  for (int kt = 0; kt < NKT; kt++) {
    const int cur = kt & 1;
    char* curA  = smem + cur * 16384;
    char* curBg = smem + 32768 + cur * 12288;
    char* curBu = smem + 57344 + cur * 12288;
    if (kt + 1 < NKT) {
      const int nx = cur ^ 1;
      char* nxA  = smem + nx * 16384;
      char* nxBg = smem + 32768 + nx * 12288;
      char* nxBu = smem + 57344 + nx * 12288;
#pragma unroll
      for (int i = 0; i < 4; i++) gload_lds16(aG[i] + (kt+1) * 128, nxA + aL[i]);
#pragma unroll
      for (int i = 0; i < 3; i++) gload_lds16(gG[i] + (kt+1) * 128, nxBg + bL[i]);
#pragma unroll
      for (int i = 0; i < 3; i++) gload_lds16(uG[i] + (kt+1) * 128, nxBu + bL[i]);
    }
#pragma unroll
    for (int kk = 0; kk < 2; kk++) {
      const int gb = kk * 64 + ((lane >> 4) * 16);
      f16x8 af[4], bg[3], bu[3];
#pragma unroll
      for (int fm = 0; fm < 4; fm++) {
        int row = wm * 64 + fm * 16 + (lane & 15);
        af[fm] = *(const f16x8*)(curA + row * 128 + (gb ^ swz(row)));
      }
#pragma unroll
      for (int fn = 0; fn < 3; fn++) {
        int row = wn * 48 + fn * 16 + (lane & 15);
        bg[fn] = *(const f16x8*)(curBg + row * 128 + (gb ^ swz(row)));
        bu[fn] = *(const f16x8*)(curBu + row * 128 + (gb ^ swz(row)));
      }
#pragma unroll
      for (int fm = 0; fm < 4; fm++)
#pragma unroll
        for (int fn = 0; fn < 3; fn++) {
          accG[fm][fn] = __builtin_amdgcn_mfma_f32_16x16x32_f16(af[fm], bg[fn], accG[fm][fn], 0, 0, 0);
          accU[fm][fn] = __builtin_amdgcn_mfma_f32_16x16x32_f16(af[fm], bu[fn], accU[fm][fn], 0, 0, 0);
        }
    }
    __syncthreads();
  }

  const int rl4 = (lane >> 4) * 4;
  const int cl  = lane & 15;
#pragma unroll
  for (int fm = 0; fm < 4; fm++)
#pragma unroll
    for (int fn = 0; fn < 3; fn++)
#pragma unroll
      for (int j = 0; j < 4; j++) {
        int row = wm * 64 + fm * 16 + rl4 + j;
        int col = n0 + wn * 48 + fn * 16 + cl;
        float g = accG[fm][fn][j], u = accU[fm][fn][j];
        float h = g * u / (1.0f + __expf(-g));
        hbuf[(size_t)(r0 + row) * IDIM + col] = (f16)h;
      }
}

__global__ __launch_bounds__(256, 2) void k_g1cvt(
    const f16* __restrict__ xh, const f16* __restrict__ wgT, const f16* __restrict__ wuT,
    f16* __restrict__ hbuf, const int* __restrict__ meta,
    const float* __restrict__ wd, f16* __restrict__ wdT) {
  __shared__ char smem[81920];
  const int id = blockIdx.x;
  if (id < NB1_A) kg1_body(xh, wgT, wuT, hbuf, meta, id, threadIdx.x, smem);
  else            cvt_body(wd, wdT, id - NB1_A, threadIdx.x, smem);
}

// ================= kg2 (dbuf) =================
// LDS: sA buf0 @0, buf1 @16384; sB buf0 @32768, buf1 @57344. Total 81920.
__global__ __launch_bounds__(256, 2) void kg2(
    const f16* __restrict__ hbuf, const f16* __restrict__ wdT,
    f16* __restrict__ ybuf, const int* __restrict__ meta, const float* __restrict__ slot_w) {
  __shared__ char smem[81920];
  const int id = blockIdx.x;
  const int sid = (id & 7) * (NB2_A / 8) + (id >> 3);
  const int mt = sid % MAXMT_A;
  const int nb = sid / MAXMT_A;
  if (mt >= meta[M_NTILES]) return;
  const int e  = meta[M_TILE_E + mt];
  const int r0 = meta[M_TILE_R0 + mt];
  const int n0 = nb * BN2_A;

  const int tid = threadIdx.x;
  const int lane = tid & 63;
  const int w = tid >> 6;
  const int wm = w >> 1, wn = w & 1;

  const char* aG[4]; int aL[4];
#pragma unroll
  for (int i = 0; i < 4; i++) {
    int seg = w * 4 + i;
    int row = seg * 8 + (lane >> 3);
    int colb = ((lane & 7) * 16) ^ swz(row);
    aG[i] = (const char*)(hbuf + (size_t)(r0 + row) * IDIM) + colb;
    aL[i] = seg * 1024;
  }
  const char* bG[6]; int bL[6];
#pragma unroll
  for (int i = 0; i < 6; i++) {
    int seg = w * 6 + i;
    int row = seg * 8 + (lane >> 3);
    int colb = ((lane & 7) * 16) ^ swz(row);
    bG[i] = (const char*)(wdT + ((size_t)e * DDIM + n0 + row) * IDIM) + colb;
    bL[i] = seg * 1024;
  }

  f32x4 acc[4][6];
#pragma unroll
  for (int i = 0; i < 4; i++)
#pragma unroll
    for (int j = 0; j < 6; j++) acc[i][j] = {0.f,0.f,0.f,0.f};

#pragma unroll
  for (int i = 0; i < 4; i++) gload_lds16(aG[i], smem + aL[i]);
#pragma unroll
  for (int i = 0; i < 6; i++) gload_lds16(bG[i], smem + 32768 + bL[i]);
  __syncthreads();

  for (int kt = 0; kt < NKT; kt++) {
    const int cur = kt & 1;
    char* curA = smem + cur * 16384;
    char* curB = smem + 32768 + cur * 24576;
    if (kt + 1 < NKT) {
      const int nx = cur ^ 1;
      char* nxA = smem + nx * 16384;
      char* nxB = smem + 32768 + nx * 24576;
#pragma unroll
      for (int i = 0; i < 4; i++) gload_lds16(aG[i] + (kt+1) * 128, nxA + aL[i]);
#pragma unroll
      for (int i = 0; i < 6; i++) gload_lds16(bG[i] + (kt+1) * 128, nxB + bL[i]);
    }
#pragma unroll
    for (int kk = 0; kk < 2; kk++) {
      const int gb = kk * 64 + ((lane >> 4) * 16);
      f16x8 af[4], bf[6];
#pragma unroll
      for (int fm = 0; fm < 4; fm++) {
        int row = wm * 64 + fm * 16 + (lane & 15);
        af[fm] = *(const f16x8*)(curA + row * 128 + (gb ^ swz(row)));
      }
#pragma unroll
      for (int fn = 0; fn < 6; fn++) {
        int row = wn * 96 + fn * 16 + (lane & 15);
        bf[fn] = *(const f16x8*)(curB + row * 128 + (gb ^ swz(row)));
      }
#pragma unroll
      for (int fm = 0; fm < 4; fm++)
#pragma unroll
        for (int fn = 0; fn < 6; fn++)
          acc[fm][fn] = __builtin_amdgcn_mfma_f32_16x16x32_f16(af[fm], bf[fn], acc[fm][fn], 0, 0, 0);
    }
    __syncthreads();
  }
  const int rl4 = (lane >> 4) * 4;
  const int cl  = lane & 15;
#pragma unroll
  for (int fm = 0; fm < 4; fm++)
#pragma unroll
    for (int j = 0; j < 4; j++) {
      int row = wm * 64 + fm * 16 + rl4 + j;
      int slot = r0 + row;
      float wv = slot_w[slot];
#pragma unroll
      for (int fn = 0; fn < 6; fn++) {
        int col = n0 + wn * 96 + fn * 16 + cl;
        ybuf[(size_t)slot * DDIM + col] = (f16)(acc[fm][fn][j] * wv);
      }
    }
}

// ---------------- combine ----------------
__global__ __launch_bounds__(256) void k_combine(const f16* __restrict__ ybuf,
    const int* __restrict__ meta, float* __restrict__ out) {
  size_t idx = (size_t)blockIdx.x * 256 + threadIdx.x;
  int t = (int)(idx / (DDIM/8));
  int c = (int)(idx % (DDIM/8));
  int s0 = meta[M_SLOT_OF + 2*t];
  int s1 = meta[M_SLOT_OF + 2*t + 1];
  f16x8 a = *(const f16x8*)(ybuf + (size_t)s0 * DDIM + c*8);
  f16x8 b = *(const f16x8*)(ybuf + (size_t)s1 * DDIM + c*8);
  float4 o0, o1;
  o0.x = (float)a[0] + (float)b[0];
  o0.y = (float)a[1] + (float)b[1];
  o0.z = (float)a[2] + (float)b[2];
  o0.w = (float)a[3] + (float)b[3];
  o1.x = (float)a[4] + (float)b[4];
  o1.y = (float)a[5] + (float)b[5];
  o1.z = (float)a[6] + (float)b[6];
  o1.w = (float)a[7] + (float)b[7];
  float* op = out + (size_t)t * DDIM + c*8;
  *(float4*)op = o0;
  *(float4*)(op + 4) = o1;
}

// ================= PATH B: fallback fused GEMMs (v4, verified) =================

__global__ __launch_bounds__(512, 2) void kg1_fb(
    const f16* __restrict__ xh, const float* __restrict__ wg, const float* __restrict__ wu,
    f16* __restrict__ hbuf, const int* __restrict__ meta) {
  const int id = blockIdx.x;
  const int sid = (id & 7) * (NB1_B / 8) + (id >> 3);
  const int mt = sid % MAXMT_B;
  const int nb = sid / MAXMT_B;
  if (mt >= meta[M_NTILES]) return;
  const int e  = meta[M_TILE_E + mt];
  const int r0 = meta[M_TILE_R0 + mt];
  const int n0 = nb * BN1_B;

  __shared__ ushort sA[2][BM_B * BK];
  __shared__ ushort sB[2][2][BN1_B * BK];

  const int tid  = threadIdx.x;
  const int lane = tid & 63;
  const int w    = tid >> 6;
  const int wm   = w >> 1;
  const int gu   = w & 1;

  const char* a_gbase[4];
  int a_loff[4];
#pragma unroll
  for (int i = 0; i < 4; i++) {
    int seg = w * 4 + i;
    int row = seg * 8 + (lane >> 3);
    int colb = ((lane & 7) * 16) ^ swz(row);
    int tok = meta[M_SLOT_TOK + r0 + row];
    a_gbase[i] = (const char*)(xh + (size_t)tok * DDIM) + colb;
    a_loff[i] = seg * 1024;
  }
  const int bm_ = tid / 192;
  const int tt  = tid % 192;
  const int bn0 = (tt % 24) * 4;
  const int bk0 = (tt / 24) * 8;
  const bool bact = tid < 384;
  const float* bsrc = (bm_ ? wu : wg) + ((size_t)e * DDIM + bk0) * IDIM + n0 + bn0;

  float4 vB[8];
  f32x4 acc[4][6];
#pragma unroll
  for (int i = 0; i < 4; i++)
#pragma unroll
    for (int j = 0; j < 6; j++) acc[i][j] = {0.f,0.f,0.f,0.f};

#pragma unroll
  for (int i = 0; i < 4; i++) gload_lds16(a_gbase[i], (char*)sA[0] + a_loff[i]);
  if (bact) {
#pragma unroll
    for (int j = 0; j < 8; j++) vB[j] = *(const float4*)(bsrc + (size_t)j * IDIM);
#pragma unroll
    for (int c = 0; c < 4; c++) {
      f16x8 p;
#pragma unroll
      for (int j = 0; j < 8; j++) {
        float fc = (c==0) ? vB[j].x : (c==1) ? vB[j].y : (c==2) ? vB[j].z : vB[j].w;
        p[j] = (f16)fc;
      }
      *(f16x8*)((char*)sB[0][bm_] + (bn0 + c) * 128 + ((bk0 * 2) ^ swz(bn0 + c))) = p;
    }
  }
  __syncthreads();

  for (int kt = 0; kt < NKT; kt++) {
    const int cur = kt & 1;
    if (kt + 1 < NKT) {
#pragma unroll
      for (int i = 0; i < 4; i++)
        gload_lds16(a_gbase[i] + (kt + 1) * 128, (char*)sA[cur ^ 1] + a_loff[i]);
      if (bact) {
        const float* bs = bsrc + (size_t)(kt + 1) * BK * IDIM;
#pragma unroll
        for (int j = 0; j < 8; j++) vB[j] = *(const float4*)(bs + (size_t)j * IDIM);
      }
    }
#pragma unroll
    for (int kk = 0; kk < 2; kk++) {
      const int gb = kk * 64 + ((lane >> 4) * 16);
      f16x8 af[4], bf[6];
#pragma unroll
      for (int fm = 0; fm < 4; fm++) {
        int row = wm * 64 + fm * 16 + (lane & 15);
        af[fm] = *(const f16x8*)((const char*)sA[cur] + row * 128 + (gb ^ swz(row)));
      }
#pragma unroll
      for (int fn = 0; fn < 6; fn++) {
        int row = fn * 16 + (lane & 15);
        bf[fn] = *(const f16x8*)((const char*)sB[cur][gu] + row * 128 + (gb ^ swz(row)));
      }
#pragma unroll
      for (int fm = 0; fm < 4; fm++)
#pragma unroll
        for (int fn = 0; fn < 6; fn++)
          acc[fm][fn] = __builtin_amdgcn_mfma_f32_16x16x32_f16(af[fm], bf[fn], acc[fm][fn], 0, 0, 0);
    }
    if (kt + 1 < NKT && bact) {
#pragma unroll
      for (int c = 0; c < 4; c++) {
        f16x8 p;
#pragma unroll
        for (int j = 0; j < 8; j++) {
          float fc = (c==0) ? vB[j].x : (c==1) ? vB[j].y : (c==2) ? vB[j].z : vB[j].w;
          p[j] = (f16)fc;
        }
        *(f16x8*)((char*)sB[cur ^ 1][bm_] + (bn0 + c) * 128 + ((bk0 * 2) ^ swz(bn0 + c))) = p;
      }
    }
    __syncthreads();
  }

  float* u_lds = (float*)&sA[0][0];
  const int rl4 = (lane >> 4) * 4;
  const int cl  = lane & 15;
#pragma unroll
  for (int r = 0; r < 2; r++) {
    __syncthreads();
    if (gu == 1) {
#pragma unroll
      for (int fi = 0; fi < 2; fi++)
#pragma unroll
        for (int fn = 0; fn < 6; fn++)
#pragma unroll
          for (int j = 0; j < 4; j++)
            u_lds[wm * 3200 + (fi * 16 + rl4 + j) * 100 + fn * 16 + cl] = acc[2*r + fi][fn][j];
    }
    __syncthreads();
    if (gu == 0) {
#pragma unroll
      for (int fi = 0; fi < 2; fi++) {
        int fm = 2*r + fi;
#pragma unroll
        for (int fn = 0; fn < 6; fn++)
#pragma unroll
          for (int j = 0; j < 4; j++) {
            float u = u_lds[wm * 3200 + (fi * 16 + rl4 + j) * 100 + fn * 16 + cl];
            float g = acc[fm][fn][j];
            float h = g * u / (1.0f + __expf(-g));
            hbuf[(size_t)(r0 + wm * 64 + fm * 16 + rl4 + j) * IDIM + n0 + fn * 16 + cl] = (f16)h;
          }
      }
    }
  }
}

__global__ __launch_bounds__(512, 2) void kg2_fb(
    const f16* __restrict__ hbuf, const float* __restrict__ wd,
    f16* __restrict__ ybuf, const int* __restrict__ meta, const float* __restrict__ slot_w) {
  const int id = blockIdx.x;
  const int sid = (id & 7) * (NB2_B / 8) + (id >> 3);
  const int mt = sid % MAXMT_B;
  const int nb = sid / MAXMT_B;
  if (mt >= meta[M_NTILES]) return;
  const int e  = meta[M_TILE_E + mt];
  const int r0 = meta[M_TILE_R0 + mt];
  const int n0 = nb * BN2_B;

  __shared__ ushort sA[2][BM_B * BK];
  __shared__ ushort sB1[2][BN2_B * BK];

  const int tid  = threadIdx.x;
  const int lane = tid & 63;
  const int w    = tid >> 6;
  const int wm   = w >> 1;
  const int wn   = w & 1;

  const char* a_gbase[4];
  int a_loff[4];
#pragma unroll
  for (int i = 0; i < 4; i++) {
    int seg = w * 4 + i;
    int row = seg * 8 + (lane >> 3);
    int colb = ((lane & 7) * 16) ^ swz(row);
    a_gbase[i] = (const char*)(hbuf + (size_t)(r0 + row) * IDIM) + colb;
    a_loff[i] = seg * 1024;
  }
  const int half = tid / 192;
  const int tt   = tid % 192;
  const int bn0  = half * 96 + (tt % 24) * 4;
  const int bk0  = (tt / 24) * 8;
  const bool bact = tid < 384;
  const float* bsrc = wd + ((size_t)e * IDIM + bk0) * DDIM + n0 + bn0;

  float4 vB[8];
  f32x4 acc[4][6];
#pragma unroll
  for (int i = 0; i < 4; i++)
#pragma unroll
    for (int j = 0; j < 6; j++) acc[i][j] = {0.f,0.f,0.f,0.f};

#pragma unroll
  for (int i = 0; i < 4; i++) gload_lds16(a_gbase[i], (char*)sA[0] + a_loff[i]);
  if (bact) {
#pragma unroll
    for (int j = 0; j < 8; j++) vB[j] = *(const float4*)(bsrc + (size_t)j * DDIM);
#pragma unroll
    for (int c = 0; c < 4; c++) {
      f16x8 p;
#pragma unroll
      for (int j = 0; j < 8; j++) {
        float fc = (c==0) ? vB[j].x : (c==1) ? vB[j].y : (c==2) ? vB[j].z : vB[j].w;
        p[j] = (f16)fc;
      }
      *(f16x8*)((char*)sB1[0] + (bn0 + c) * 128 + ((bk0 * 2) ^ swz(bn0 + c))) = p;
    }
  }
  __syncthreads();

  for (int kt = 0; kt < NKT; kt++) {
    const int cur = kt & 1;
    if (kt + 1 < NKT) {
#pragma unroll
      for (int i = 0; i < 4; i++)
        gload_lds16(a_gbase[i] + (kt + 1) * 128, (char*)sA[cur ^ 1] + a_loff[i]);
      if (bact) {
        const float* bs = bsrc + (size_t)(kt + 1) * BK * DDIM;
#pragma unroll
        for (int j = 0; j < 8; j++) vB[j] = *(const float4*)(bs + (size_t)j * DDIM);
      }
    }
#pragma unroll
    for (int kk = 0; kk < 2; kk++) {
      const int gb = kk * 64 + ((lane >> 4) * 16);
      f16x8 af[4], bf[6];
#pragma unroll
      for (int fm = 0; fm < 4; fm++) {
        int row = wm * 64 + fm * 16 + (lane & 15);
        af[fm] = *(const f16x8*)((const char*)sA[cur] + row * 128 + (gb ^ swz(row)));
      }
#pragma unroll
      for (int fn = 0; fn < 6; fn++) {
        int row = wn * 96 + fn * 16 + (lane & 15);
        bf[fn] = *(const f16x8*)((const char*)sB1[cur] + row * 128 + (gb ^ swz(row)));
      }
#pragma unroll
      for (int fm = 0; fm < 4; fm++)
#pragma unroll
        for (int fn = 0; fn < 6; fn++)
          acc[fm][fn] = __builtin_amdgcn_mfma_f32_16x16x32_f16(af[fm], bf[fn], acc[fm][fn], 0, 0, 0);
    }
    if (kt + 1 < NKT && bact) {
#pragma unroll
      for (int c = 0; c < 4; c++) {
        f16x8 p;
#pragma unroll
        for (int j = 0; j < 8; j++) {
          float fc = (c==0) ? vB[j].x : (c==1) ? vB[j].y : (c==2) ? vB[j].z : vB[j].w;
          p[j] = (f16)fc;
        }
        *(f16x8*)((char*)sB1[cur ^ 1] + (bn0 + c) * 128 + ((bk0 * 2) ^ swz(bn0 + c))) = p;
      }
    }
    __syncthreads();
  }

  const int rl4 = (lane >> 4) * 4;
  const int cl  = lane & 15;
#pragma unroll
  for (int fm = 0; fm < 4; fm++)
#pragma unroll
    for (int j = 0; j < 4; j++) {
      int row = wm * 64 + fm * 16 + rl4 + j;
      int slot = r0 + row;
      float wv = slot_w[slot];
#pragma unroll
      for (int fn = 0; fn < 6; fn++) {
        int col = n0 + wn * 96 + fn * 16 + cl;
        ybuf[(size_t)slot * DDIM + col] = (f16)(acc[fm][fn][j] * wv);
      }
    }
}

extern "C" void kernel_launch(void* const* d_in, const int* in_sizes, int n_in,
                              void* d_out, int out_size, void* d_ws, size_t ws_size,
                              hipStream_t stream) {
  const float* x  = (const float*)d_in[0];
  const float* wr = (const float*)d_in[1];
  const float* wg = (const float*)d_in[2];
  const float* wu = (const float*)d_in[3];
  const float* wd = (const float*)d_in[4];
  float* out = (float*)d_out;
  char* ws = (char*)d_ws;

  if (ws_size >= A2_NEED) {
    const bool three = (ws_size >= A3_NEED);
    f16* wgT = (f16*)(ws);
    f16* wuT = (f16*)(ws + WT_B);
    f16* wdT = three ? (f16*)(ws + 2*WT_B) : wgT;   // alias only if sequential
    char* base = ws + (three ? 3*WT_B : 2*WT_B);
    f16* hbuf = (f16*)(base);
    f16* ybuf = (f16*)(base + HB_B);
    f16* xh   = (f16*)(base + 2*HB_B);
    int* meta = (int*)(base + 2*HB_B + XH_B);
    float* slot_w = (float*)((char*)meta + META_INTS*4);
    float* tok_w  = (float*)((char*)slot_w + SLOT_CAP*4);

    (void)hipMemsetAsync(meta + M_COUNT, 0, NEXP * sizeof(int), stream);
    k_p1<<<2*NCVT + T_TOK/4 + 2880, 256, 0, stream>>>(x, wr, wg, wu, wgT, wuT, xh, meta, tok_w);
    k_scan_scatter<<<1, 256, 0, stream>>>(meta, slot_w, tok_w, BM_A);
    if (three) {
      k_g1cvt<<<NB1_A + NCVT, 256, 0, stream>>>(xh, wgT, wuT, hbuf, meta, wd, wdT);
    } else {
      k_g1cvt<<<NB1_A, 256, 0, stream>>>(xh, wgT, wuT, hbuf, meta, wd, wdT);
      k_cvt_w<<<NCVT, 256, 0, stream>>>(wd, wdT);
    }
    kg2<<<NB2_A, 256, 0, stream>>>(hbuf, wdT, ybuf, meta, slot_w);
    k_combine<<<(T_TOK*DDIM/8)/256, 256, 0, stream>>>(ybuf, meta, out);
  } else if (ws_size >= BF_NEED) {
    f16* hbuf = (f16*)(ws);
    f16* xh   = (f16*)(ws + (size_t)SLOT_CAP*IDIM*2);
    f16* ybuf = xh;
    int* meta = (int*)(ws + (size_t)SLOT_CAP*IDIM*2 + (size_t)SLOT_CAP*DDIM*2);
    float* slot_w = (float*)((char*)meta + META_INTS*4);
    float* tok_w  = (float*)((char*)slot_w + SLOT_CAP*4);

    (void)hipMemsetAsync(meta + M_COUNT, 0, NEXP * sizeof(int), stream);
    k_router<<<T_TOK/4, 256, 0, stream>>>(x, wr, meta, tok_w);
    k_xcvt<<<(T_TOK*DDIM/8)/256, 256, 0, stream>>>(x, xh);
    k_scan_scatter<<<1, 256, 0, stream>>>(meta, slot_w, tok_w, BM_B);
    kg1_fb<<<NB1_B, 512, 0, stream>>>(xh, wg, wu, hbuf, meta);
    kg2_fb<<<NB2_B, 512, 0, stream>>>(hbuf, wd, ybuf, meta, slot_w);
    k_combine<<<(T_TOK*DDIM/8)/256, 256, 0, stream>>>(ybuf, meta, out);
  }
}

// Round 11
// 572.304 us; speedup vs baseline: 1.3736x; 1.0003x over previous
//
#include <hip/hip_runtime.h>
#include <hip/hip_fp16.h>
#include <stdint.h>
#include <math.h>

// MoE MLP block: router top-2 + 8 experts SiLU-GLU, fp16 MFMA.
// v8: v7b with LDS-clean weight transpose-convert: register 4x4 transpose,
// ds_write_b64, GEMM-style XOR swizzle on LDS rows, 128B-coalesced output.
// P1 = cvt_wg+cvt_wu+router+xcvt fused; P3 = kg1 + cvt_wd backfill; GEMMs
// double-buffered (80KB LDS, 1 barrier/k-step). 3-tier ws fallback.

typedef _Float16 f16;
typedef _Float16 f16x4 __attribute__((ext_vector_type(4)));
typedef _Float16 f16x8 __attribute__((ext_vector_type(8)));
typedef float f32x4 __attribute__((ext_vector_type(4)));

#define T_TOK 2048
#define DDIM 2880
#define NEXP 8
#define IDIM 2880
#define BK 64
#define NKT 45

#define BM_A 128
#define BN1_A 96
#define BN2_A 192
#define MAXMT_A 40
#define NB1_A (30*MAXMT_A)   // 1200
#define NB2_A (15*MAXMT_A)   // 600
#define NCVT 16200           // 2025*8 blocks per weight tensor

#define BM_B 256
#define BN1_B 96
#define BN2_B 192
#define MAXMT_B 24
#define NB1_B (30*MAXMT_B)
#define NB2_B (15*MAXMT_B)

#define SLOT_CAP 6144

// meta int32 indices
#define M_COUNT 0
#define M_OFFS 16
#define M_NTILES 25
#define M_TILE_E 32
#define M_TILE_R0 96
#define M_SLOT_TOK 160
#define M_SLOT_OF (160+SLOT_CAP)
#define M_TOK_E (M_SLOT_OF + 2*T_TOK)
#define META_INTS (M_TOK_E + 2*T_TOK)

#define WT_B   ((size_t)NEXP*DDIM*IDIM*2)     // 132.7MB
#define HB_B   ((size_t)5120*IDIM*2)          // 29.5MB
#define XH_B   ((size_t)T_TOK*DDIM*2)         // 11.8MB
#define TAIL_B ((size_t)META_INTS*4 + (size_t)SLOT_CAP*4 + (size_t)T_TOK*2*4)

#define A3_NEED (3*WT_B + 2*HB_B + XH_B + TAIL_B)
#define A2_NEED (2*WT_B + 2*HB_B + XH_B + TAIL_B)
#define BF_NEED ((size_t)SLOT_CAP*IDIM*2 + (size_t)SLOT_CAP*DDIM*2 + TAIL_B)

__device__ __forceinline__ int swz(int row) { return ((row ^ (row >> 3)) & 7) << 4; }

__device__ __forceinline__ void gload_lds16(const void* gp, void* lp) {
  __builtin_amdgcn_global_load_lds(
      (const __attribute__((address_space(1))) uint32_t*)gp,
      (__attribute__((address_space(3))) uint32_t*)lp,
      16, 0, 0);
}

// ================= device bodies =================

// weight transpose-convert tile: f32 [K,N] -> f16 [N,K], 64x64 per block.
// Register 4x4 transpose + b64 LDS writes + XOR-swizzled rows (conflict-floor)
// + 128B-contiguous global writes. Uses 8KB of smem.
__device__ __forceinline__ void cvt_body(const float* __restrict__ src, f16* __restrict__ dst,
                                          int blk, int tid, char* smem) {
  const int e = blk / 2025;
  const int tile = blk % 2025;
  const int k0 = (tile / 45) * 64;
  const int i0 = (tile % 45) * 64;
  const float* sp = src + ((size_t)e * DDIM + k0) * IDIM + i0;
  const int c0  = (tid & 15) * 4;   // N quad
  const int kr0 = (tid >> 4) * 4;   // K quad
  float4 v0 = *(const float4*)(sp + (size_t)(kr0 + 0) * IDIM + c0);
  float4 v1 = *(const float4*)(sp + (size_t)(kr0 + 1) * IDIM + c0);
  float4 v2 = *(const float4*)(sp + (size_t)(kr0 + 2) * IDIM + c0);
  float4 v3 = *(const float4*)(sp + (size_t)(kr0 + 3) * IDIM + c0);
#pragma unroll
  for (int c = 0; c < 4; c++) {
    f16x4 p;
    p[0] = (f16)((c==0) ? v0.x : (c==1) ? v0.y : (c==2) ? v0.z : v0.w);
    p[1] = (f16)((c==0) ? v1.x : (c==1) ? v1.y : (c==2) ? v1.z : v1.w);
    p[2] = (f16)((c==0) ? v2.x : (c==1) ? v2.y : (c==2) ? v2.z : v2.w);
    p[3] = (f16)((c==0) ? v3.x : (c==1) ? v3.y : (c==2) ? v3.z : v3.w);
    int row = c0 + c;
    *(f16x4*)(smem + row * 128 + ((kr0 * 2) ^ swz(row))) = p;
  }
  __syncthreads();
#pragma unroll
  for (int q = 0; q < 2; q++) {
    int row = (tid >> 3) + 32 * q;
    int o = (tid & 7) * 16;   // byte offset within row
    f16x8 r = *(const f16x8*)(smem + row * 128 + (o ^ swz(row)));
    *(f16x8*)(dst + ((size_t)e * IDIM + i0 + row) * DDIM + k0 + o / 2) = r;
  }
}

__device__ __forceinline__ void router_body(const float* __restrict__ x, const float* __restrict__ wr,
                                            int* __restrict__ meta, float* __restrict__ tok_w,
                                            int blk, int tid) {
  const int lane = tid & 63;
  const int t = blk * 4 + (tid >> 6);
  double acc[NEXP];
#pragma unroll
  for (int e = 0; e < NEXP; e++) acc[e] = 0.0;
  for (int d = lane; d < DDIM; d += 64) {
    float xv = x[(size_t)t * DDIM + d];
    float4 w0 = *(const float4*)(wr + (size_t)d * NEXP);
    float4 w1 = *(const float4*)(wr + (size_t)d * NEXP + 4);
    acc[0] += (double)xv * (double)w0.x;
    acc[1] += (double)xv * (double)w0.y;
    acc[2] += (double)xv * (double)w0.z;
    acc[3] += (double)xv * (double)w0.w;
    acc[4] += (double)xv * (double)w1.x;
    acc[5] += (double)xv * (double)w1.y;
    acc[6] += (double)xv * (double)w1.z;
    acc[7] += (double)xv * (double)w1.w;
  }
#pragma unroll
  for (int m = 32; m >= 1; m >>= 1) {
#pragma unroll
    for (int e = 0; e < NEXP; e++) acc[e] += __shfl_xor(acc[e], m, 64);
  }
  if (lane == 0) {
    int e0 = 0;
#pragma unroll
    for (int e = 1; e < NEXP; e++) if (acc[e] > acc[e0]) e0 = e;
    int e1 = (e0 == 0) ? 1 : 0;
#pragma unroll
    for (int e = 0; e < NEXP; e++) if (e != e0 && acc[e] > acc[e1]) e1 = e;
    double w0 = 1.0 / (1.0 + exp(acc[e1] - acc[e0]));
    meta[M_TOK_E + 2*t]     = e0;
    meta[M_TOK_E + 2*t + 1] = e1;
    tok_w[2*t]     = (float)w0;
    tok_w[2*t + 1] = (float)(1.0 - w0);
    atomicAdd(&meta[M_COUNT + e0], 1);
    atomicAdd(&meta[M_COUNT + e1], 1);
  }
}

__device__ __forceinline__ void xcvt_body(const float* __restrict__ x, f16* __restrict__ xh,
                                          int blk, int tid) {
  size_t i = ((size_t)blk * 256 + tid) * 8;
  float4 a = *(const float4*)(x + i);
  float4 b = *(const float4*)(x + i + 4);
  f16x8 v;
  v[0]=(f16)a.x; v[1]=(f16)a.y; v[2]=(f16)a.z; v[3]=(f16)a.w;
  v[4]=(f16)b.x; v[5]=(f16)b.y; v[6]=(f16)b.z; v[7]=(f16)b.w;
  *(f16x8*)(xh + i) = v;
}

// ================= P1: cvt_wg + cvt_wu + router + xcvt =================
__global__ __launch_bounds__(256) void k_p1(
    const float* __restrict__ x, const float* __restrict__ wr,
    const float* __restrict__ wg, const float* __restrict__ wu,
    f16* __restrict__ wgT, f16* __restrict__ wuT, f16* __restrict__ xh,
    int* __restrict__ meta, float* __restrict__ tok_w) {
  __shared__ char smem[8192];
  int b = blockIdx.x;
  const int tid = threadIdx.x;
  if (b < NCVT) { cvt_body(wg, wgT, b, tid, smem); return; }
  b -= NCVT;
  if (b < NCVT) { cvt_body(wu, wuT, b, tid, smem); return; }
  b -= NCVT;
  if (b < T_TOK/4) { router_body(x, wr, meta, tok_w, b, tid); return; }
  b -= T_TOK/4;
  xcvt_body(x, xh, b, tid);
}

__global__ __launch_bounds__(256) void k_router(const float* x, const float* wr, int* meta, float* tok_w) {
  router_body(x, wr, meta, tok_w, blockIdx.x, threadIdx.x);
}
__global__ __launch_bounds__(256) void k_xcvt(const float* x, f16* xh) {
  xcvt_body(x, xh, blockIdx.x, threadIdx.x);
}
__global__ __launch_bounds__(256) void k_cvt_w(const float* src, f16* dst) {
  __shared__ char smem[8192];
  cvt_body(src, dst, blockIdx.x, threadIdx.x, smem);
}

// ================= scan + scatter (one block) =================
__global__ __launch_bounds__(256) void k_scan_scatter(
    int* __restrict__ meta, float* __restrict__ slot_w, const float* __restrict__ tok_w, int bm) {
  __shared__ int s_off[NEXP], s_cnt[NEXP], s_pc[NEXP], s_cur[NEXP];
  const int tid = threadIdx.x;
  if (tid == 0) {
    int run = 0, nt = 0;
    for (int e = 0; e < NEXP; e++) {
      int c = meta[M_COUNT + e];
      int mt = (c + bm - 1) / bm;
      meta[M_OFFS + e] = run;
      s_off[e] = run; s_cnt[e] = c; s_pc[e] = mt * bm; s_cur[e] = 0;
      for (int j = 0; j < mt; j++) { meta[M_TILE_E + nt] = e; meta[M_TILE_R0 + nt] = run + j * bm; nt++; }
      run += mt * bm;
    }
    meta[M_OFFS + NEXP] = run;
    meta[M_NTILES] = nt;
  }
  __syncthreads();
  for (int e = 0; e < NEXP; e++) {
    for (int i = s_cnt[e] + tid; i < s_pc[e]; i += 256) {
      meta[M_SLOT_TOK + s_off[e] + i] = 0;
      slot_w[s_off[e] + i] = 0.0f;
    }
  }
  for (int t = tid; t < T_TOK; t += 256) {
#pragma unroll
    for (int k = 0; k < 2; k++) {
      int e = meta[M_TOK_E + 2*t + k];
      int pos = atomicAdd(&s_cur[e], 1);
      int slot = s_off[e] + pos;
      meta[M_SLOT_TOK + slot] = t;
      slot_w[slot] = tok_w[2*t + k];
      meta[M_SLOT_OF + 2*t + k] = slot;
    }
  }
}

// ================= kg1 (dbuf) + cvt_wd backfill =================
// LDS layout (bytes): sA buf0 @0, buf1 @16384; sBg buf0 @32768, buf1 @45056;
//                     sBu buf0 @57344, buf1 @69632. Total 81920.
__device__ __forceinline__ void kg1_body(
    const f16* __restrict__ xh, const f16* __restrict__ wgT, const f16* __restrict__ wuT,
    f16* __restrict__ hbuf, const int* __restrict__ meta, int id, int tid, char* smem) {
  const int sid = (id & 7) * (NB1_A / 8) + (id >> 3);
  const int mt = sid % MAXMT_A;
  const int nb = sid / MAXMT_A;
  if (mt >= meta[M_NTILES]) return;
  const int e  = meta[M_TILE_E + mt];
  const int r0 = meta[M_TILE_R0 + mt];
  const int n0 = nb * BN1_A;

  const int lane = tid & 63;
  const int w = tid >> 6;
  const int wm = w >> 1, wn = w & 1;

  const char* aG[4]; int aL[4];
#pragma unroll
  for (int i = 0; i < 4; i++) {
    int seg = w * 4 + i;
    int row = seg * 8 + (lane >> 3);
    int colb = ((lane & 7) * 16) ^ swz(row);
    int tok = meta[M_SLOT_TOK + r0 + row];
    aG[i] = (const char*)(xh + (size_t)tok * DDIM) + colb;
    aL[i] = seg * 1024;
  }
  const char* gG[3]; const char* uG[3]; int bL[3];
#pragma unroll
  for (int i = 0; i < 3; i++) {
    int seg = w * 3 + i;
    int row = seg * 8 + (lane >> 3);
    int colb = ((lane & 7) * 16) ^ swz(row);
    gG[i] = (const char*)(wgT + ((size_t)e * IDIM + n0 + row) * DDIM) + colb;
    uG[i] = (const char*)(wuT + ((size_t)e * IDIM + n0 + row) * DDIM) + colb;
    bL[i] = seg * 1024;
  }

  f32x4 accG[4][3], accU[4][3];
#pragma unroll
  for (int i = 0; i < 4; i++)
#pragma unroll
    for (int j = 0; j < 3; j++) { accG[i][j] = {0.f,0.f,0.f,0.f}; accU[i][j] = {0.f,0.f,0.f,0.f}; }

#pragma unroll
  for (int i = 0; i < 4; i++) gload_lds16(aG[i], smem + aL[i]);
#pragma unroll
  for (int i = 0; i < 3; i++) gload_lds16(gG[i], smem + 32768 + bL[i]);
#pragma unroll
  for (int i = 0; i < 3; i++) gload_lds16(uG[i], smem + 57344 + bL[i]);
  __syncthreads();

  for (int kt = 0; kt < NKT; kt++) {
    const int cur = kt & 1;
    char* curA  = smem + cur * 16384;
    char* curBg = smem + 32768 + cur * 12288;
    char* curBu = smem + 57344 + cur * 12288;
    if (kt + 1 < NKT) {
      const int nx = cur ^ 1;
      char* nxA  = smem + nx * 16384;
      char* nxBg = smem + 32768 + nx * 12288;
      char* nxBu = smem + 57344 + nx * 12288;
#pragma unroll
      for (int i = 0; i < 4; i++) gload_lds16(aG[i] + (kt+1) * 128, nxA + aL[i]);
#pragma unroll
      for (int i = 0; i < 3; i++) gload_lds16(gG[i] + (kt+1) * 128, nxBg + bL[i]);
#pragma unroll
      for (int i = 0; i < 3; i++) gload_lds16(uG[i] + (kt+1) * 128, nxBu + bL[i]);
    }
#pragma unroll
    for (int kk = 0; kk < 2; kk++) {
      const int gb = kk * 64 + ((lane >> 4) * 16);
      f16x8 af[4], bg[3], bu[3];
#pragma unroll
      for (int fm = 0; fm < 4; fm++) {
        int row = wm * 64 + fm * 16 + (lane & 15);
        af[fm] = *(const f16x8*)(curA + row * 128 + (gb ^ swz(row)));
      }
#pragma unroll
      for (int fn = 0; fn < 3; fn++) {
        int row = wn * 48 + fn * 16 + (lane & 15);
        bg[fn] = *(const f16x8*)(curBg + row * 128 + (gb ^ swz(row)));
        bu[fn] = *(const f16x8*)(curBu + row * 128 + (gb ^ swz(row)));
      }
#pragma unroll
      for (int fm = 0; fm < 4; fm++)
#pragma unroll
        for (int fn = 0; fn < 3; fn++) {
          accG[fm][fn] = __builtin_amdgcn_mfma_f32_16x16x32_f16(af[fm], bg[fn], accG[fm][fn], 0, 0, 0);
          accU[fm][fn] = __builtin_amdgcn_mfma_f32_16x16x32_f16(af[fm], bu[fn], accU[fm][fn], 0, 0, 0);
        }
    }
    __syncthreads();
  }

  const int rl4 = (lane >> 4) * 4;
  const int cl  = lane & 15;
#pragma unroll
  for (int fm = 0; fm < 4; fm++)
#pragma unroll
    for (int fn = 0; fn < 3; fn++)
#pragma unroll
      for (int j = 0; j < 4; j++) {
        int row = wm * 64 + fm * 16 + rl4 + j;
        int col = n0 + wn * 48 + fn * 16 + cl;
        float g = accG[fm][fn][j], u = accU[fm][fn][j];
        float h = g * u / (1.0f + __expf(-g));
        hbuf[(size_t)(r0 + row) * IDIM + col] = (f16)h;
      }
}

__global__ __launch_bounds__(256, 2) void k_g1cvt(
    const f16* __restrict__ xh, const f16* __restrict__ wgT, const f16* __restrict__ wuT,
    f16* __restrict__ hbuf, const int* __restrict__ meta,
    const float* __restrict__ wd, f16* __restrict__ wdT) {
  __shared__ char smem[81920];
  const int id = blockIdx.x;
  if (id < NB1_A) kg1_body(xh, wgT, wuT, hbuf, meta, id, threadIdx.x, smem);
  else            cvt_body(wd, wdT, id - NB1_A, threadIdx.x, smem);
}

// ================= kg2 (dbuf) =================
// LDS: sA buf0 @0, buf1 @16384; sB buf0 @32768, buf1 @57344. Total 81920.
__global__ __launch_bounds__(256, 2) void kg2(
    const f16* __restrict__ hbuf, const f16* __restrict__ wdT,
    f16* __restrict__ ybuf, const int* __restrict__ meta, const float* __restrict__ slot_w) {
  __shared__ char smem[81920];
  const int id = blockIdx.x;
  const int sid = (id & 7) * (NB2_A / 8) + (id >> 3);
  const int mt = sid % MAXMT_A;
  const int nb = sid / MAXMT_A;
  if (mt >= meta[M_NTILES]) return;
  const int e  = meta[M_TILE_E + mt];
  const int r0 = meta[M_TILE_R0 + mt];
  const int n0 = nb * BN2_A;

  const int tid = threadIdx.x;
  const int lane = tid & 63;
  const int w = tid >> 6;
  const int wm = w >> 1, wn = w & 1;

  const char* aG[4]; int aL[4];
#pragma unroll
  for (int i = 0; i < 4; i++) {
    int seg = w * 4 + i;
    int row = seg * 8 + (lane >> 3);
    int colb = ((lane & 7) * 16) ^ swz(row);
    aG[i] = (const char*)(hbuf + (size_t)(r0 + row) * IDIM) + colb;
    aL[i] = seg * 1024;
  }
  const char* bG[6]; int bL[6];
#pragma unroll
  for (int i = 0; i < 6; i++) {
    int seg = w * 6 + i;
    int row = seg * 8 + (lane >> 3);
    int colb = ((lane & 7) * 16) ^ swz(row);
    bG[i] = (const char*)(wdT + ((size_t)e * DDIM + n0 + row) * IDIM) + colb;
    bL[i] = seg * 1024;
  }

  f32x4 acc[4][6];
#pragma unroll
  for (int i = 0; i < 4; i++)
#pragma unroll
    for (int j = 0; j < 6; j++) acc[i][j] = {0.f,0.f,0.f,0.f};

#pragma unroll
  for (int i = 0; i < 4; i++) gload_lds16(aG[i], smem + aL[i]);
#pragma unroll
  for (int i = 0; i < 6; i++) gload_lds16(bG[i], smem + 32768 + bL[i]);
  __syncthreads();

  for (int kt = 0; kt < NKT; kt++) {
    const int cur = kt & 1;
    char* curA = smem + cur * 16384;
    char* curB = smem + 32768 + cur * 24576;
    if (kt + 1 < NKT) {
      const int nx = cur ^ 1;
      char* nxA = smem + nx * 16384;
      char* nxB = smem + 32768 + nx * 24576;
#pragma unroll
      for (int i = 0; i < 4; i++) gload_lds16(aG[i] + (kt+1) * 128, nxA + aL[i]);
#pragma unroll
      for (int i = 0; i < 6; i++) gload_lds16(bG[i] + (kt+1) * 128, nxB + bL[i]);
    }
#pragma unroll
    for (int kk = 0; kk < 2; kk++) {
      const int gb = kk * 64 + ((lane >> 4) * 16);
      f16x8 af[4], bf[6];
#pragma unroll
      for (int fm = 0; fm < 4; fm++) {
        int row = wm * 64 + fm * 16 + (lane & 15);
        af[fm] = *(const f16x8*)(curA + row * 128 + (gb ^ swz(row)));
      }
#pragma unroll
      for (int fn = 0; fn < 6; fn++) {
        int row = wn * 96 + fn * 16 + (lane & 15);
        bf[fn] = *(const f16x8*)(curB + row * 128 + (gb ^ swz(row)));
      }
#pragma unroll
      for (int fm = 0; fm < 4; fm++)
#pragma unroll
        for (int fn = 0; fn < 6; fn++)
          acc[fm][fn] = __builtin_amdgcn_mfma_f32_16x16x32_f16(af[fm], bf[fn], acc[fm][fn], 0, 0, 0);
    }
    __syncthreads();
  }
  const int rl4 = (lane >> 4) * 4;
  const int cl  = lane & 15;
#pragma unroll
  for (int fm = 0; fm < 4; fm++)
#pragma unroll
    for (int j = 0; j < 4; j++) {
      int row = wm * 64 + fm * 16 + rl4 + j;
      int slot = r0 + row;
      float wv = slot_w[slot];
#pragma unroll
      for (int fn = 0; fn < 6; fn++) {
        int col = n0 + wn * 96 + fn * 16 + cl;
        ybuf[(size_t)slot * DDIM + col] = (f16)(acc[fm][fn][j] * wv);
      }
    }
}

// ---------------- combine ----------------
__global__ __launch_bounds__(256) void k_combine(const f16* __restrict__ ybuf,
    const int* __restrict__ meta, float* __restrict__ out) {
  size_t idx = (size_t)blockIdx.x * 256 + threadIdx.x;
  int t = (int)(idx / (DDIM/8));
  int c = (int)(idx % (DDIM/8));
  int s0 = meta[M_SLOT_OF + 2*t];
  int s1 = meta[M_SLOT_OF + 2*t + 1];
  f16x8 a = *(const f16x8*)(ybuf + (size_t)s0 * DDIM + c*8);
  f16x8 b = *(const f16x8*)(ybuf + (size_t)s1 * DDIM + c*8);
  float4 o0, o1;
  o0.x = (float)a[0] + (float)b[0];
  o0.y = (float)a[1] + (float)b[1];
  o0.z = (float)a[2] + (float)b[2];
  o0.w = (float)a[3] + (float)b[3];
  o1.x = (float)a[4] + (float)b[4];
  o1.y = (float)a[5] + (float)b[5];
  o1.z = (float)a[6] + (float)b[6];
  o1.w = (float)a[7] + (float)b[7];
  float* op = out + (size_t)t * DDIM + c*8;
  *(float4*)op = o0;
  *(float4*)(op + 4) = o1;
}

// ================= PATH B: fallback fused GEMMs (v4, verified) =================

__global__ __launch_bounds__(512, 2) void kg1_fb(
    const f16* __restrict__ xh, const float* __restrict__ wg, const float* __restrict__ wu,
    f16* __restrict__ hbuf, const int* __restrict__ meta) {
  const int id = blockIdx.x;
  const int sid = (id & 7) * (NB1_B / 8) + (id >> 3);
  const int mt = sid % MAXMT_B;
  const int nb = sid / MAXMT_B;
  if (mt >= meta[M_NTILES]) return;
  const int e  = meta[M_TILE_E + mt];
  const int r0 = meta[M_TILE_R0 + mt];
  const int n0 = nb * BN1_B;

  __shared__ ushort sA[2][BM_B * BK];
  __shared__ ushort sB[2][2][BN1_B * BK];

  const int tid  = threadIdx.x;
  const int lane = tid & 63;
  const int w    = tid >> 6;
  const int wm   = w >> 1;
  const int gu   = w & 1;

  const char* a_gbase[4];
  int a_loff[4];
#pragma unroll
  for (int i = 0; i < 4; i++) {
    int seg = w * 4 + i;
    int row = seg * 8 + (lane >> 3);
    int colb = ((lane & 7) * 16) ^ swz(row);
    int tok = meta[M_SLOT_TOK + r0 + row];
    a_gbase[i] = (const char*)(xh + (size_t)tok * DDIM) + colb;
    a_loff[i] = seg * 1024;
  }
  const int bm_ = tid / 192;
  const int tt  = tid % 192;
  const int bn0 = (tt % 24) * 4;
  const int bk0 = (tt / 24) * 8;
  const bool bact = tid < 384;
  const float* bsrc = (bm_ ? wu : wg) + ((size_t)e * DDIM + bk0) * IDIM + n0 + bn0;

  float4 vB[8];
  f32x4 acc[4][6];
#pragma unroll
  for (int i = 0; i < 4; i++)
#pragma unroll
    for (int j = 0; j < 6; j++) acc[i][j] = {0.f,0.f,0.f,0.f};

#pragma unroll
  for (int i = 0; i < 4; i++) gload_lds16(a_gbase[i], (char*)sA[0] + a_loff[i]);
  if (bact) {
#pragma unroll
    for (int j = 0; j < 8; j++) vB[j] = *(const float4*)(bsrc + (size_t)j * IDIM);
#pragma unroll
    for (int c = 0; c < 4; c++) {
      f16x8 p;
#pragma unroll
      for (int j = 0; j < 8; j++) {
        float fc = (c==0) ? vB[j].x : (c==1) ? vB[j].y : (c==2) ? vB[j].z : vB[j].w;
        p[j] = (f16)fc;
      }
      *(f16x8*)((char*)sB[0][bm_] + (bn0 + c) * 128 + ((bk0 * 2) ^ swz(bn0 + c))) = p;
    }
  }
  __syncthreads();

  for (int kt = 0; kt < NKT; kt++) {
    const int cur = kt & 1;
    if (kt + 1 < NKT) {
#pragma unroll
      for (int i = 0; i < 4; i++)
        gload_lds16(a_gbase[i] + (kt + 1) * 128, (char*)sA[cur ^ 1] + a_loff[i]);
      if (bact) {
        const float* bs = bsrc + (size_t)(kt + 1) * BK * IDIM;
#pragma unroll
        for (int j = 0; j < 8; j++) vB[j] = *(const float4*)(bs + (size_t)j * IDIM);
      }
    }
#pragma unroll
    for (int kk = 0; kk < 2; kk++) {
      const int gb = kk * 64 + ((lane >> 4) * 16);
      f16x8 af[4], bf[6];
#pragma unroll
      for (int fm = 0; fm < 4; fm++) {
        int row = wm * 64 + fm * 16 + (lane & 15);
        af[fm] = *(const f16x8*)((const char*)sA[cur] + row * 128 + (gb ^ swz(row)));
      }
#pragma unroll
      for (int fn = 0; fn < 6; fn++) {
        int row = fn * 16 + (lane & 15);
        bf[fn] = *(const f16x8*)((const char*)sB[cur][gu] + row * 128 + (gb ^ swz(row)));
      }
#pragma unroll
      for (int fm = 0; fm < 4; fm++)
#pragma unroll
        for (int fn = 0; fn < 6; fn++)
          acc[fm][fn] = __builtin_amdgcn_mfma_f32_16x16x32_f16(af[fm], bf[fn], acc[fm][fn], 0, 0, 0);
    }
    if (kt + 1 < NKT && bact) {
#pragma unroll
      for (int c = 0; c < 4; c++) {
        f16x8 p;
#pragma unroll
        for (int j = 0; j < 8; j++) {
          float fc = (c==0) ? vB[j].x : (c==1) ? vB[j].y : (c==2) ? vB[j].z : vB[j].w;
          p[j] = (f16)fc;
        }
        *(f16x8*)((char*)sB[cur ^ 1][bm_] + (bn0 + c) * 128 + ((bk0 * 2) ^ swz(bn0 + c))) = p;
      }
    }
    __syncthreads();
  }

  float* u_lds = (float*)&sA[0][0];
  const int rl4 = (lane >> 4) * 4;
  const int cl  = lane & 15;
#pragma unroll
  for (int r = 0; r < 2; r++) {
    __syncthreads();
    if (gu == 1) {
#pragma unroll
      for (int fi = 0; fi < 2; fi++)
#pragma unroll
        for (int fn = 0; fn < 6; fn++)
#pragma unroll
          for (int j = 0; j < 4; j++)
            u_lds[wm * 3200 + (fi * 16 + rl4 + j) * 100 + fn * 16 + cl] = acc[2*r + fi][fn][j];
    }
    __syncthreads();
    if (gu == 0) {
#pragma unroll
      for (int fi = 0; fi < 2; fi++) {
        int fm = 2*r + fi;
#pragma unroll
        for (int fn = 0; fn < 6; fn++)
#pragma unroll
          for (int j = 0; j < 4; j++) {
            float u = u_lds[wm * 3200 + (fi * 16 + rl4 + j) * 100 + fn * 16 + cl];
            float g = acc[fm][fn][j];
            float h = g * u / (1.0f + __expf(-g));
            hbuf[(size_t)(r0 + wm * 64 + fm * 16 + rl4 + j) * IDIM + n0 + fn * 16 + cl] = (f16)h;
          }
      }
    }
  }
}

__global__ __launch_bounds__(512, 2) void kg2_fb(
    const f16* __restrict__ hbuf, const float* __restrict__ wd,
    f16* __restrict__ ybuf, const int* __restrict__ meta, const float* __restrict__ slot_w) {
  const int id = blockIdx.x;
  const int sid = (id & 7) * (NB2_B / 8) + (id >> 3);
  const int mt = sid % MAXMT_B;
  const int nb = sid / MAXMT_B;
  if (mt >= meta[M_NTILES]) return;
  const int e  = meta[M_TILE_E + mt];
  const int r0 = meta[M_TILE_R0 + mt];
  const int n0 = nb * BN2_B;

  __shared__ ushort sA[2][BM_B * BK];
  __shared__ ushort sB1[2][BN2_B * BK];

  const int tid  = threadIdx.x;
  const int lane = tid & 63;
  const int w    = tid >> 6;
  const int wm   = w >> 1;
  const int wn   = w & 1;

  const char* a_gbase[4];
  int a_loff[4];
#pragma unroll
  for (int i = 0; i < 4; i++) {
    int seg = w * 4 + i;
    int row = seg * 8 + (lane >> 3);
    int colb = ((lane & 7) * 16) ^ swz(row);
    a_gbase[i] = (const char*)(hbuf + (size_t)(r0 + row) * IDIM) + colb;
    a_loff[i] = seg * 1024;
  }
  const int half = tid / 192;
  const int tt   = tid % 192;
  const int bn0  = half * 96 + (tt % 24) * 4;
  const int bk0  = (tt / 24) * 8;
  const bool bact = tid < 384;
  const float* bsrc = wd + ((size_t)e * IDIM + bk0) * DDIM + n0 + bn0;

  float4 vB[8];
  f32x4 acc[4][6];
#pragma unroll
  for (int i = 0; i < 4; i++)
#pragma unroll
    for (int j = 0; j < 6; j++) acc[i][j] = {0.f,0.f,0.f,0.f};

#pragma unroll
  for (int i = 0; i < 4; i++) gload_lds16(a_gbase[i], (char*)sA[0] + a_loff[i]);
  if (bact) {
#pragma unroll
    for (int j = 0; j < 8; j++) vB[j] = *(const float4*)(bsrc + (size_t)j * DDIM);
#pragma unroll
    for (int c = 0; c < 4; c++) {
      f16x8 p;
#pragma unroll
      for (int j = 0; j < 8; j++) {
        float fc = (c==0) ? vB[j].x : (c==1) ? vB[j].y : (c==2) ? vB[j].z : vB[j].w;
        p[j] = (f16)fc;
      }
      *(f16x8*)((char*)sB1[0] + (bn0 + c) * 128 + ((bk0 * 2) ^ swz(bn0 + c))) = p;
    }
  }
  __syncthreads();

  for (int kt = 0; kt < NKT; kt++) {
    const int cur = kt & 1;
    if (kt + 1 < NKT) {
#pragma unroll
      for (int i = 0; i < 4; i++)
        gload_lds16(a_gbase[i] + (kt + 1) * 128, (char*)sA[cur ^ 1] + a_loff[i]);
      if (bact) {
        const float* bs = bsrc + (size_t)(kt + 1) * BK * DDIM;
#pragma unroll
        for (int j = 0; j < 8; j++) vB[j] = *(const float4*)(bs + (size_t)j * DDIM);
      }
    }
#pragma unroll
    for (int kk = 0; kk < 2; kk++) {
      const int gb = kk * 64 + ((lane >> 4) * 16);
      f16x8 af[4], bf[6];
#pragma unroll
      for (int fm = 0; fm < 4; fm++) {
        int row = wm * 64 + fm * 16 + (lane & 15);
        af[fm] = *(const f16x8*)((const char*)sA[cur] + row * 128 + (gb ^ swz(row)));
      }
#pragma unroll
      for (int fn = 0; fn < 6; fn++) {
        int row = wn * 96 + fn * 16 + (lane & 15);
        bf[fn] = *(const f16x8*)((const char*)sB1[cur] + row * 128 + (gb ^ swz(row)));
      }
#pragma unroll
      for (int fm = 0; fm < 4; fm++)
#pragma unroll
        for (int fn = 0; fn < 6; fn++)
          acc[fm][fn] = __builtin_amdgcn_mfma_f32_16x16x32_f16(af[fm], bf[fn], acc[fm][fn], 0, 0, 0);
    }
    if (kt + 1 < NKT && bact) {
#pragma unroll
      for (int c = 0; c < 4; c++) {
        f16x8 p;
#pragma unroll
        for (int j = 0; j < 8; j++) {
          float fc = (c==0) ? vB[j].x : (c==1) ? vB[j].y : (c==2) ? vB[j].z : vB[j].w;
          p[j] = (f16)fc;
        }
        *(f16x8*)((char*)sB1[cur ^ 1] + (bn0 + c) * 128 + ((bk0 * 2) ^ swz(bn0 + c))) = p;
      }
    }
    __syncthreads();
  }

  const int rl4 = (lane >> 4) * 4;
  const int cl  = lane & 15;
#pragma unroll
  for (int fm = 0; fm < 4; fm++)
#pragma unroll
    for (int j = 0; j < 4; j++) {
      int row = wm * 64 + fm * 16 + rl4 + j;
      int slot = r0 + row;
      float wv = slot_w[slot];
#pragma unroll
      for (int fn = 0; fn < 6; fn++) {
        int col = n0 + wn * 96 + fn * 16 + cl;
        ybuf[(size_t)slot * DDIM + col] = (f16)(acc[fm][fn][j] * wv);
      }
    }
}

extern "C" void kernel_launch(void* const* d_in, const int* in_sizes, int n_in,
                              void* d_out, int out_size, void* d_ws, size_t ws_size,
                              hipStream_t stream) {
  const float* x  = (const float*)d_in[0];
  const float* wr = (const float*)d_in[1];
  const float* wg = (const float*)d_in[2];
  const float* wu = (const float*)d_in[3];
  const float* wd = (const float*)d_in[4];
  float* out = (float*)d_out;
  char* ws = (char*)d_ws;

  if (ws_size >= A2_NEED) {
    const bool three = (ws_size >= A3_NEED);
    f16* wgT = (f16*)(ws);
    f16* wuT = (f16*)(ws + WT_B);
    f16* wdT = three ? (f16*)(ws + 2*WT_B) : wgT;   // alias only if sequential
    char* base = ws + (three ? 3*WT_B : 2*WT_B);
    f16* hbuf = (f16*)(base);
    f16* ybuf = (f16*)(base + HB_B);
    f16* xh   = (f16*)(base + 2*HB_B);
    int* meta = (int*)(base + 2*HB_B + XH_B);
    float* slot_w = (float*)((char*)meta + META_INTS*4);
    float* tok_w  = (float*)((char*)slot_w + SLOT_CAP*4);

    (void)hipMemsetAsync(meta + M_COUNT, 0, NEXP * sizeof(int), stream);
    k_p1<<<2*NCVT + T_TOK/4 + 2880, 256, 0, stream>>>(x, wr, wg, wu, wgT, wuT, xh, meta, tok_w);
    k_scan_scatter<<<1, 256, 0, stream>>>(meta, slot_w, tok_w, BM_A);
    if (three) {
      k_g1cvt<<<NB1_A + NCVT, 256, 0, stream>>>(xh, wgT, wuT, hbuf, meta, wd, wdT);
    } else {
      k_g1cvt<<<NB1_A, 256, 0, stream>>>(xh, wgT, wuT, hbuf, meta, wd, wdT);
      k_cvt_w<<<NCVT, 256, 0, stream>>>(wd, wdT);
    }
    kg2<<<NB2_A, 256, 0, stream>>>(hbuf, wdT, ybuf, meta, slot_w);
    k_combine<<<(T_TOK*DDIM/8)/256, 256, 0, stream>>>(ybuf, meta, out);
  } else if (ws_size >= BF_NEED) {
    f16* hbuf = (f16*)(ws);
    f16* xh   = (f16*)(ws + (size_t)SLOT_CAP*IDIM*2);
    f16* ybuf = xh;
    int* meta = (int*)(ws + (size_t)SLOT_CAP*IDIM*2 + (size_t)SLOT_CAP*DDIM*2);
    float* slot_w = (float*)((char*)meta + META_INTS*4);
    float* tok_w  = (float*)((char*)slot_w + SLOT_CAP*4);

    (void)hipMemsetAsync(meta + M_COUNT, 0, NEXP * sizeof(int), stream);
    k_router<<<T_TOK/4, 256, 0, stream>>>(x, wr, meta, tok_w);
    k_xcvt<<<(T_TOK*DDIM/8)/256, 256, 0, stream>>>(x, xh);
    k_scan_scatter<<<1, 256, 0, stream>>>(meta, slot_w, tok_w, BM_B);
    kg1_fb<<<NB1_B, 512, 0, stream>>>(xh, wg, wu, hbuf, meta);
    kg2_fb<<<NB2_B, 512, 0, stream>>>(hbuf, wd, ybuf, meta, slot_w);
    k_combine<<<(T_TOK*DDIM/8)/256, 256, 0, stream>>>(ybuf, meta, out);
  }
}